// Round 7
// baseline (685.226 us; speedup 1.0000x reference)
//
#include <hip/hip_runtime.h>
#include <hip/hip_bf16.h>

// Problem constants
#define BB 8
#define SS 512
#define DD 512
#define HH 8
#define DQKv 64
#define DFFv 2048
#define LL 2

typedef __attribute__((ext_vector_type(8))) __bf16 bf16x8;
typedef __attribute__((ext_vector_type(4))) float f32x4;

// fp32 -> bf16 (RNE), bf16 -> fp32 helpers on raw ushort bits
static __device__ __forceinline__ ushort f2b(float x) {
    unsigned int u = __float_as_uint(x);
    unsigned int r = (u + 0x7FFFu + ((u >> 16) & 1u)) >> 16;
    return (ushort)r;
}
static __device__ __forceinline__ float b2f(ushort u) {
    return __uint_as_float(((unsigned int)u) << 16);
}

typedef __attribute__((address_space(1))) const unsigned int gas_u32;
typedef __attribute__((address_space(3))) unsigned int las_u32;
static __device__ __forceinline__ void gload16(const void* g, void* l) {
    __builtin_amdgcn_global_load_lds((gas_u32*)g, (las_u32*)l, 16, 0, 0);
}

// ---------------------------------------------------------------------------
// x = in + PE (PE trig computed inline); src->x and trg->y in one grid.
// ---------------------------------------------------------------------------
__global__ __launch_bounds__(256) void add_pe2_k(const float* __restrict__ src,
                                                 const float* __restrict__ trg,
                                                 float* __restrict__ xf,
                                                 ushort* __restrict__ xb,
                                                 float* __restrict__ yf,
                                                 ushort* __restrict__ yb) {
    const int NQ = BB * SS * DD / 4;
    int i = blockIdx.x * 256 + threadIdx.x;       // 0 .. 2*NQ-1
    const bool second = i >= NQ;
    const int ii = second ? i - NQ : i;
    const int rem = ii & (SS * DD / 4 - 1);
    const int d4 = rem & (DD / 4 - 1);            // 0..127
    const int s = rem >> 7;

    float4 a = ((const float4*)(second ? trg : src))[ii];
    const float c = -9.210340371976184f / 512.0f; // -ln(1e4)/D
    const float div0 = __expf((float)(4 * d4) * c);
    const float div1 = __expf((float)(4 * d4 + 2) * c);
    const float a0 = (float)s * div0, a1 = (float)s * div1;
    a.x += sinf(a0); a.y += cosf(a0);
    a.z += sinf(a1); a.w += cosf(a1);

    float* of = second ? yf : xf;
    ushort* ob = second ? yb : xb;
    ((float4*)of)[ii] = a;
    ushort4 ub;
    ub.x = f2b(a.x); ub.y = f2b(a.y); ub.z = f2b(a.z); ub.w = f2b(a.w);
    ((ushort4*)ob)[ii] = ub;
}

// ---------------------------------------------------------------------------
// Per-op weight transpose+cast (fallback when ws is small)
// ---------------------------------------------------------------------------
__global__ __launch_bounds__(256) void tcast_k(const float* __restrict__ s0,
                                               const float* __restrict__ s1,
                                               const float* __restrict__ s2,
                                               const float* __restrict__ s3,
                                               ushort* __restrict__ dst,
                                               int K, int N) {
    __shared__ ushort st[64][72];
    const float* src = (blockIdx.z == 0) ? s0 : (blockIdx.z == 1) ? s1
                     : (blockIdx.z == 2) ? s2 : s3;
    ushort* d = dst + (size_t)blockIdx.z * K * N;
    const int k0 = blockIdx.y * 64, n0 = blockIdx.x * 64;
    const int t = threadIdx.x;
    const int r = t >> 2, c4 = (t & 3) * 16;
#pragma unroll
    for (int i = 0; i < 16; i += 4) {
        float4 v = *(const float4*)&src[(size_t)(k0 + r) * N + n0 + c4 + i];
        st[c4 + i + 0][r] = f2b(v.x);
        st[c4 + i + 1][r] = f2b(v.y);
        st[c4 + i + 2][r] = f2b(v.z);
        st[c4 + i + 3][r] = f2b(v.w);
    }
    __syncthreads();
    const int n = t >> 2, seg = (t & 3) * 16;
    *(uint4*)&d[(size_t)(n0 + n) * K + k0 + seg]     = *(const uint4*)&st[n][seg];
    *(uint4*)&d[(size_t)(n0 + n) * K + k0 + seg + 8] = *(const uint4*)&st[n][seg + 8];
}

// ---------------------------------------------------------------------------
// All-weights transpose+cast in ONE launch.
// ---------------------------------------------------------------------------
#define NW 32
struct WTab {
    const float* src[NW];
    unsigned off[NW];   // dst offset in ushort elems
    int Kd[NW];         // K/64
    int Nd[NW];         // N/64
    int cum[NW + 1];    // tile prefix sums
};

__global__ __launch_bounds__(256) void tcast_all_k(WTab tab, ushort* __restrict__ dst) {
    __shared__ ushort st[64][72];
    const int t = blockIdx.x;
    int m = 0;
    while (t >= tab.cum[m + 1]) ++m;
    const int local = t - tab.cum[m];
    const int ntx = tab.Nd[m];
    const int bx = local % ntx, by = local / ntx;
    const float* src = tab.src[m];
    ushort* d = dst + tab.off[m];
    const int N = ntx * 64, K = tab.Kd[m] * 64;
    const int k0 = by * 64, n0 = bx * 64;

    const int tt = threadIdx.x;
    const int r = tt >> 2, c4 = (tt & 3) * 16;
#pragma unroll
    for (int i = 0; i < 16; i += 4) {
        float4 v = *(const float4*)&src[(size_t)(k0 + r) * N + n0 + c4 + i];
        st[c4 + i + 0][r] = f2b(v.x);
        st[c4 + i + 1][r] = f2b(v.y);
        st[c4 + i + 2][r] = f2b(v.z);
        st[c4 + i + 3][r] = f2b(v.w);
    }
    __syncthreads();
    const int n = tt >> 2, seg = (tt & 3) * 16;
    *(uint4*)&d[(size_t)(n0 + n) * K + k0 + seg]     = *(const uint4*)&st[n][seg];
    *(uint4*)&d[(size_t)(n0 + n) * K + k0 + seg + 8] = *(const uint4*)&st[n][seg + 8];
}

// ---------------------------------------------------------------------------
// bf16 MFMA GEMM, BM=128 BN=64 BK=64 (for N=512 shapes; grid fills 256 CUs).
// ---------------------------------------------------------------------------
template <bool BIAS, bool RES, bool RELU, bool OUTBF>
__global__ __launch_bounds__(256) void gemm2_k(const ushort* __restrict__ A,
                                               const ushort* __restrict__ Bt,
                                               const float* __restrict__ bias,
                                               const float* __restrict__ res,
                                               void* __restrict__ Cout,
                                               int M, int N, int K, int nbx) {
    __shared__ ushort sA[128 * 64];
    __shared__ ushort sB[64 * 64];

    const int tid = threadIdx.x;
    const int nwg = gridDim.x;
    const int wg = blockIdx.x;
    const int swz = (wg & 7) * (nwg >> 3) + (wg >> 3);   // XCD-contiguous chunks
    const int bx = swz % nbx, by = swz / nbx;

    const int lane = tid & 63, w = tid >> 6;
    const int wm = w >> 1, wn = w & 1;
    const int llo = lane & 15, lhi = lane >> 4;

    const int srow = tid >> 3;           // 0..31
    const int scol = (tid & 7) * 8;      // element offset in row (8 elems=16B)
    const ushort* Ab = A + (size_t)(by * 128 + srow) * K + scol;
    const ushort* Bb = Bt + (size_t)(bx * 64 + srow) * K + scol;
    char* sAd = (char*)sA + srow * 128 + (tid & 7) * 16;
    char* sBd = (char*)sB + srow * 128 + (tid & 7) * 16;

    f32x4 acc[4][2] = {};

    for (int k0 = 0; k0 < K; k0 += 64) {
#pragma unroll
        for (int i = 0; i < 4; ++i)
            gload16(Ab + (size_t)i * 32 * K + k0, sAd + i * 32 * 128);
#pragma unroll
        for (int i = 0; i < 2; ++i)
            gload16(Bb + (size_t)i * 32 * K + k0, sBd + i * 32 * 128);
        __syncthreads();   // drains vmcnt before barrier

#pragma unroll
        for (int ks = 0; ks < 2; ++ks) {
            bf16x8 af[4];
#pragma unroll
            for (int fa = 0; fa < 4; ++fa)
                af[fa] = *(const bf16x8*)&sA[(wm * 64 + fa * 16 + llo) * 64 + ks * 32 + lhi * 8];
            bf16x8 bfrag[2];
#pragma unroll
            for (int fb = 0; fb < 2; ++fb)
                bfrag[fb] = *(const bf16x8*)&sB[(wn * 32 + fb * 16 + llo) * 64 + ks * 32 + lhi * 8];
#pragma unroll
            for (int fa = 0; fa < 4; ++fa)
#pragma unroll
                for (int fb = 0; fb < 2; ++fb)
                    acc[fa][fb] = __builtin_amdgcn_mfma_f32_16x16x32_bf16(
                        af[fa], bfrag[fb], acc[fa][fb], 0, 0, 0);
        }
        __syncthreads();
    }

#pragma unroll
    for (int fa = 0; fa < 4; ++fa) {
#pragma unroll
        for (int fb = 0; fb < 2; ++fb) {
            const int col = bx * 64 + wn * 32 + fb * 16 + llo;
            const float bv = BIAS ? bias[col] : 0.f;
#pragma unroll
            for (int j = 0; j < 4; ++j) {
                const int row = by * 128 + wm * 64 + fa * 16 + lhi * 4 + j;
                float v = acc[fa][fb][j] + bv;
                if (RES) v += res[(size_t)row * N + col];
                if (RELU) v = fmaxf(v, 0.f);
                if (OUTBF) ((ushort*)Cout)[(size_t)row * N + col] = f2b(v);
                else       ((float*)Cout)[(size_t)row * N + col] = v;
            }
        }
    }
}

// ---------------------------------------------------------------------------
// bf16 MFMA GEMM, m97 configuration: BM=128 BN=128 BK=64, 4 waves (2x2),
// each wave 64x64 via 4x4 16x16x32 frags. 32 MFMA + 16 ds_read + 8 gload
// per K-step. For N>=1024 shapes (grid still >= 256 blocks).
// ---------------------------------------------------------------------------
template <bool BIAS, bool RES, bool RELU, bool OUTBF>
__global__ __launch_bounds__(256) void gemm3_k(const ushort* __restrict__ A,
                                               const ushort* __restrict__ Bt,
                                               const float* __restrict__ bias,
                                               const float* __restrict__ res,
                                               void* __restrict__ Cout,
                                               int M, int N, int K, int nbx) {
    __shared__ ushort sA[128 * 64];
    __shared__ ushort sB[128 * 64];

    const int tid = threadIdx.x;
    const int nwg = gridDim.x;
    const int wg = blockIdx.x;
    const int swz = (wg & 7) * (nwg >> 3) + (wg >> 3);
    const int bx = swz % nbx, by = swz / nbx;

    const int lane = tid & 63, w = tid >> 6;
    const int wm = w >> 1, wn = w & 1;
    const int llo = lane & 15, lhi = lane >> 4;

    const int srow = tid >> 3;           // 0..31
    const ushort* Ab = A + (size_t)(by * 128 + srow) * K + (tid & 7) * 8;
    const ushort* Bb = Bt + (size_t)(bx * 128 + srow) * K + (tid & 7) * 8;
    char* sAd = (char*)sA + srow * 128 + (tid & 7) * 16;
    char* sBd = (char*)sB + srow * 128 + (tid & 7) * 16;

    f32x4 acc[4][4] = {};

    for (int k0 = 0; k0 < K; k0 += 64) {
#pragma unroll
        for (int i = 0; i < 4; ++i)
            gload16(Ab + (size_t)i * 32 * K + k0, sAd + i * 32 * 128);
#pragma unroll
        for (int i = 0; i < 4; ++i)
            gload16(Bb + (size_t)i * 32 * K + k0, sBd + i * 32 * 128);
        __syncthreads();

#pragma unroll
        for (int ks = 0; ks < 2; ++ks) {
            bf16x8 af[4];
#pragma unroll
            for (int fa = 0; fa < 4; ++fa)
                af[fa] = *(const bf16x8*)&sA[(wm * 64 + fa * 16 + llo) * 64 + ks * 32 + lhi * 8];
            bf16x8 bfrag[4];
#pragma unroll
            for (int fb = 0; fb < 4; ++fb)
                bfrag[fb] = *(const bf16x8*)&sB[(wn * 64 + fb * 16 + llo) * 64 + ks * 32 + lhi * 8];
#pragma unroll
            for (int fa = 0; fa < 4; ++fa)
#pragma unroll
                for (int fb = 0; fb < 4; ++fb)
                    acc[fa][fb] = __builtin_amdgcn_mfma_f32_16x16x32_bf16(
                        af[fa], bfrag[fb], acc[fa][fb], 0, 0, 0);
        }
        __syncthreads();
    }

#pragma unroll
    for (int fa = 0; fa < 4; ++fa) {
#pragma unroll
        for (int fb = 0; fb < 4; ++fb) {
            const int col = bx * 128 + wn * 64 + fb * 16 + llo;
            const float bv = BIAS ? bias[col] : 0.f;
#pragma unroll
            for (int j = 0; j < 4; ++j) {
                const int row = by * 128 + wm * 64 + fa * 16 + lhi * 4 + j;
                float v = acc[fa][fb][j] + bv;
                if (RES) v += res[(size_t)row * N + col];
                if (RELU) v = fmaxf(v, 0.f);
                if (OUTBF) ((ushort*)Cout)[(size_t)row * N + col] = f2b(v);
                else       ((float*)Cout)[(size_t)row * N + col] = v;
            }
        }
    }
}

// ---------------------------------------------------------------------------
// MFMA flash attention on packed QKV [M][1536]. Semantics verified R2-R6.
// ---------------------------------------------------------------------------
__global__ __launch_bounds__(256) void attn_k(const ushort* __restrict__ QKV,
                                              ushort* __restrict__ O,
                                              const int* __restrict__ pad) {
    __shared__ ushort sQ[64][72];
    __shared__ ushort sK[64][72];
    __shared__ ushort sVt[64][72];   // V transposed: [d][key]
    __shared__ ushort sP[64][72];    // P: [q][key-local]

    const int tid = threadIdx.x;
    const int b = blockIdx.z, h = blockIdx.y, q0 = blockIdx.x << 6;
    const int klim = SS - pad[b];
    const int lane = tid & 63, w = tid >> 6;
    const int qw0 = w << 4;
    const int lhi = lane >> 4, llo = lane & 15;
    const int ST = 3 * DD;           // 1536 row stride

    {
        const int r = tid >> 2, seg = (tid & 3) << 4;
        const ushort* src = &QKV[(size_t)(b * SS + q0 + r) * ST + h * DQKv + seg];
        *(uint4*)&sQ[r][seg]     = *(const uint4*)src;
        *(uint4*)&sQ[r][seg + 8] = *(const uint4*)(src + 8);
    }

    auto window = [&](int i, int& wlo, int& whi) {
        if (h < 6) {
            const int step = 4 << (h >> 1);
            const int s2 = step >> 1;
            const int a1 = (i < s2) ? i : s2;
            const int a2 = ((SS - 1 - i) < s2) ? (SS - 1 - i) : s2;
            const int left = (i < SS / 2) ? a1 : (step - a2);
            wlo = i - left;
            whi = wlo + step;
        } else {
            wlo = 0;
            whi = SS - 1;
        }
    };

    int lo[4], hi[4];
#pragma unroll
    for (int j = 0; j < 4; ++j) window(q0 + qw0 + lhi * 4 + j, lo[j], hi[j]);

    int kt0 = 0, kt1 = SS;
    if (h < 6) {
        int lo0, hi0, lo63, hi63;
        window(q0, lo0, hi0);
        window(q0 + 63, lo63, hi63);
        if (lo63 >= klim) {
            kt0 = 0; kt1 = SS;
        } else {
            kt0 = (lo0 >> 6) << 6;
            kt1 = ((hi63 >> 6) + 1) << 6;
            if (kt1 > SS) kt1 = SS;
        }
    }

    float mr[4] = {-1e30f, -1e30f, -1e30f, -1e30f};
    float lr[4] = {0.f, 0.f, 0.f, 0.f};
    f32x4 oacc[4] = {};

    for (int kt = kt0; kt < kt1; kt += 64) {
        __syncthreads();
        {
            const int r = tid >> 2, seg = (tid & 3) << 4;
            const ushort* ksrc = &QKV[(size_t)(b * SS + kt + r) * ST + DD + h * DQKv + seg];
            *(uint4*)&sK[r][seg]     = *(const uint4*)ksrc;
            *(uint4*)&sK[r][seg + 8] = *(const uint4*)(ksrc + 8);
            const ushort* vsrc = &QKV[(size_t)(b * SS + kt + r) * ST + 2 * DD + h * DQKv + seg];
            uint4 u0 = *(const uint4*)vsrc;
            uint4 u1 = *(const uint4*)(vsrc + 8);
            const ushort* v0 = (const ushort*)&u0;
            const ushort* v1 = (const ushort*)&u1;
#pragma unroll
            for (int i = 0; i < 8; ++i) sVt[seg + i][r] = v0[i];
#pragma unroll
            for (int i = 0; i < 8; ++i) sVt[seg + 8 + i][r] = v1[i];
        }
        __syncthreads();

        // ---- QK^T ----
        f32x4 sacc[4] = {};
#pragma unroll
        for (int ks = 0; ks < 2; ++ks) {
            bf16x8 aq = *(const bf16x8*)&sQ[qw0 + llo][ks * 32 + lhi * 8];
#pragma unroll
            for (int n = 0; n < 4; ++n) {
                bf16x8 bk = *(const bf16x8*)&sK[n * 16 + llo][ks * 32 + lhi * 8];
                sacc[n] = __builtin_amdgcn_mfma_f32_16x16x32_bf16(aq, bk, sacc[n], 0, 0, 0);
            }
        }

        // ---- mask + scale + online softmax ----
#pragma unroll
        for (int j = 0; j < 4; ++j) {
            float s[4];
#pragma unroll
            for (int n = 0; n < 4; ++n) {
                const int kidx = kt + n * 16 + llo;
                const bool ok = (kidx < klim) && (kidx >= lo[j]) && (kidx <= hi[j]);
                s[n] = ok ? (sacc[n][j] * 0.125f) : -1e9f;
            }
            float tm = fmaxf(fmaxf(s[0], s[1]), fmaxf(s[2], s[3]));
#pragma unroll
            for (int off = 8; off; off >>= 1) tm = fmaxf(tm, __shfl_xor(tm, off));
            const float mn = fmaxf(mr[j], tm);
            const float alpha = __expf(mr[j] - mn);
            mr[j] = mn;
            float ps = 0.f;
            const int prow = qw0 + lhi * 4 + j;
#pragma unroll
            for (int n = 0; n < 4; ++n) {
                const ushort pb = f2b(__expf(s[n] - mn));
                sP[prow][n * 16 + llo] = pb;
                ps += b2f(pb);
            }
#pragma unroll
            for (int off = 8; off; off >>= 1) ps += __shfl_xor(ps, off);
            lr[j] = lr[j] * alpha + ps;
            oacc[0][j] *= alpha; oacc[1][j] *= alpha;
            oacc[2][j] *= alpha; oacc[3][j] *= alpha;
        }

        // ---- PV ----
#pragma unroll
        for (int ks = 0; ks < 2; ++ks) {
            bf16x8 ap = *(const bf16x8*)&sP[qw0 + llo][ks * 32 + lhi * 8];
#pragma unroll
            for (int n = 0; n < 4; ++n) {
                bf16x8 bv = *(const bf16x8*)&sVt[n * 16 + llo][ks * 32 + lhi * 8];
                oacc[n] = __builtin_amdgcn_mfma_f32_16x16x32_bf16(ap, bv, oacc[n], 0, 0, 0);
            }
        }
    }

#pragma unroll
    for (int j = 0; j < 4; ++j) {
        const float inv = 1.f / lr[j];
        const int q = q0 + qw0 + lhi * 4 + j;
#pragma unroll
        for (int n = 0; n < 4; ++n) {
            O[(size_t)(b * SS + q) * (HH * DQKv) + h * DQKv + n * 16 + llo] =
                f2b(oacc[n][j] * inv);
        }
    }
}

// ---------------------------------------------------------------------------
// LayerNorm over rows of 512; writes fp32 state + bf16 state copy
// ---------------------------------------------------------------------------
__global__ __launch_bounds__(256) void ln_k(const float* __restrict__ in,
                                            const float* __restrict__ g,
                                            const float* __restrict__ bvec,
                                            float* __restrict__ outf,
                                            ushort* __restrict__ outb) {
    const int row = blockIdx.x;
    const int tid = threadIdx.x;
    const float2 xv = *(const float2*)&in[(size_t)row * DD + tid * 2];

    __shared__ float red[4];
    __shared__ float red2[4];
    const int wid = tid >> 6, lane = tid & 63;

    float s = xv.x + xv.y;
#pragma unroll
    for (int off = 32; off; off >>= 1) s += __shfl_xor(s, off);
    if (lane == 0) red[wid] = s;
    __syncthreads();
    const float mu = (red[0] + red[1] + red[2] + red[3]) * (1.f / 512.f);

    const float dx = xv.x - mu, dy = xv.y - mu;
    float q = dx * dx + dy * dy;
#pragma unroll
    for (int off = 32; off; off >>= 1) q += __shfl_xor(q, off);
    if (lane == 0) red2[wid] = q;
    __syncthreads();
    const float var = (red2[0] + red2[1] + red2[2] + red2[3]) * (1.f / 512.f);
    const float rs = rsqrtf(var + 1e-6f);

    float2 o;
    o.x = dx * rs * g[tid * 2] + bvec[tid * 2];
    o.y = dy * rs * g[tid * 2 + 1] + bvec[tid * 2 + 1];
    *(float2*)&outf[(size_t)row * DD + tid * 2] = o;
    ushort2 ub; ub.x = f2b(o.x); ub.y = f2b(o.y);
    *(ushort2*)&outb[(size_t)row * DD + tid * 2] = ub;
}

// ---------------------------------------------------------------------------
// Host orchestration
// ---------------------------------------------------------------------------
extern "C" void kernel_launch(void* const* d_in, const int* in_sizes, int n_in,
                              void* d_out, int out_size, void* d_ws, size_t ws_size,
                              hipStream_t stream) {
    const float* src_seq = (const float*)d_in[0];
    const float* trg_seq = (const float*)d_in[1];
    const int* enc_pad = (const int*)d_in[2];
    const int* dec_pad = (const int*)d_in[3];
    const float* e_wq = (const float*)d_in[4];
    const float* e_wk = (const float*)d_in[5];
    const float* e_wv = (const float*)d_in[6];
    const float* e_wo = (const float*)d_in[7];
    const float* e_g1 = (const float*)d_in[8];
    const float* e_b1 = (const float*)d_in[9];
    const float* e_w1 = (const float*)d_in[10];
    const float* e_bb1 = (const float*)d_in[11];
    const float* e_w2 = (const float*)d_in[12];
    const float* e_bb2 = (const float*)d_in[13];
    const float* e_g2 = (const float*)d_in[14];
    const float* e_b2 = (const float*)d_in[15];
    const float* d_swq = (const float*)d_in[16];
    const float* d_swk = (const float*)d_in[17];
    const float* d_swv = (const float*)d_in[18];
    const float* d_swo = (const float*)d_in[19];
    const float* d_g1 = (const float*)d_in[20];
    const float* d_b1 = (const float*)d_in[21];
    const float* d_cwq = (const float*)d_in[22];
    const float* d_cwk = (const float*)d_in[23];
    const float* d_cwv = (const float*)d_in[24];
    const float* d_cwo = (const float*)d_in[25];
    const float* d_g2 = (const float*)d_in[26];
    const float* d_b2 = (const float*)d_in[27];
    const float* d_w1 = (const float*)d_in[28];
    const float* d_bb1 = (const float*)d_in[29];
    const float* d_w2 = (const float*)d_in[30];
    const float* d_bb2 = (const float*)d_in[31];
    const float* d_g3 = (const float*)d_in[32];
    const float* d_b3 = (const float*)d_in[33];
    (void)in_sizes; (void)n_in; (void)out_size;

    const int M = BB * SS;          // 4096
    const int NTOK = BB * SS * DD;  // 2097152
    const size_t WSZ = (size_t)DD * 512;  // 262144 elems (one 512x512 weight)

    float* ws = (float*)d_ws;
    float* x  = ws;
    float* y  = x + NTOK;
    float* t0 = y + NTOK;
    ushort* xbf  = (ushort*)(t0 + NTOK);
    ushort* ybf  = xbf + NTOK;
    ushort* qkvb = ybf + NTOK;              // M x 1536 packed QKV
    ushort* ob   = qkvb + (size_t)M * 1536;
    ushort* hbf  = qkvb;                    // FFN hidden 4096x2048 aliases qkvb+ob
    ushort* warena = ob + NTOK;

    // ---- weight table ----
    const float* wsrc[NW]; int wK[NW], wN[NW]; size_t woff[NW];
    int wcnt = 0; size_t acc = 0;
    auto push = [&](const float* p, int K, int N) {
        wsrc[wcnt] = p; wK[wcnt] = K; wN[wcnt] = N; woff[wcnt] = acc;
        acc += (size_t)K * N; ++wcnt;
    };
    for (int l = 0; l < LL; ++l) {
        push(e_wq + (size_t)l * WSZ, 512, 512);
        push(e_wk + (size_t)l * WSZ, 512, 512);
        push(e_wv + (size_t)l * WSZ, 512, 512);
        push(e_wo + (size_t)l * WSZ, 512, 512);
        push(e_w1 + (size_t)l * DD * DFFv, 512, DFFv);
        push(e_w2 + (size_t)l * DFFv * DD, DFFv, 512);
    }
    for (int l = 0; l < LL; ++l) {
        push(d_swq + (size_t)l * WSZ, 512, 512);
        push(d_swk + (size_t)l * WSZ, 512, 512);
        push(d_swv + (size_t)l * WSZ, 512, 512);
        push(d_swo + (size_t)l * WSZ, 512, 512);
        push(d_cwq + (size_t)l * WSZ, 512, 512);
        push(d_cwk + (size_t)l * WSZ, 512, 512);
        push(d_cwv + (size_t)l * WSZ, 512, 512);
        push(d_cwo + (size_t)l * WSZ, 512, 512);
        push(d_w1 + (size_t)l * DD * DFFv, 512, DFFv);
        push(d_w2 + (size_t)l * DFFv * DD, DFFv, 512);
    }

    const size_t base_bytes = (size_t)(warena - (ushort*)d_ws) * 2;
    const bool big = ws_size >= base_bytes + acc * 2;

    if (big) {
        WTab tab;
        int tiles = 0;
        for (int i = 0; i < NW; ++i) {
            tab.src[i] = wsrc[i];
            tab.off[i] = (unsigned)woff[i];
            tab.Kd[i] = wK[i] / 64;
            tab.Nd[i] = wN[i] / 64;
            tab.cum[i] = tiles;
            tiles += (wK[i] / 64) * (wN[i] / 64);
        }
        tab.cum[NW] = tiles;
        tcast_all_k<<<tiles, 256, 0, stream>>>(tab, warena);
    }

    add_pe2_k<<<2 * NTOK / 4 / 256, 256, 0, stream>>>(src_seq, trg_seq, x, xbf, y, ybf);

    auto do_mha = [&](float* statef, ushort* statebf, const ushort* kvbf, int widx,
                      const float* g, const float* bb, const int* pad) {
        const ushort* bt;
        if (big) {
            bt = warena + woff[widx];
        } else {
            tcast_k<<<dim3(8, 8, 4), 256, 0, stream>>>(
                wsrc[widx], wsrc[widx + 1], wsrc[widx + 2], wsrc[widx + 3],
                warena, 512, 512);
            bt = warena;
        }
        if (kvbf == statebf) {
            // packed QKV: 128x128 tiles, nbx = 1536/128 = 12, grid 384
            gemm3_k<false, false, false, true><<<32 * 12, 256, 0, stream>>>(
                statebf, bt, nullptr, nullptr, qkvb, M, 1536, 512, 12);
        } else {
            // cross-attn: Q (512 cols) 128x64; K/V (1024 cols) 128x128
            gemm2_k<false, false, false, true><<<32 * 8, 256, 0, stream>>>(
                statebf, bt + 0 * WSZ, nullptr, nullptr, qkvb, M, 1536, 512, 8);
            gemm3_k<false, false, false, true><<<32 * 8, 256, 0, stream>>>(
                kvbf, bt + 1 * WSZ, nullptr, nullptr, qkvb + DD, M, 1536, 512, 8);
        }
        attn_k<<<dim3(SS / 64, HH, BB), 256, 0, stream>>>(qkvb, ob, pad);
        gemm2_k<false, true, false, false><<<32 * 8, 256, 0, stream>>>(
            ob, bt + 3 * WSZ, nullptr, statef, t0, M, 512, 512, 8);
        ln_k<<<M, 256, 0, stream>>>(t0, g, bb, statef, statebf);
    };
    auto do_ffn = [&](float* statef, ushort* statebf, int widx,
                      const float* b1, const float* b2,
                      const float* g, const float* bb, float* lnoutf) {
        const ushort* bt1;
        const ushort* bt2;
        if (big) {
            bt1 = warena + woff[widx];
            bt2 = warena + woff[widx + 1];
        } else {
            tcast_k<<<dim3(32, 8, 1), 256, 0, stream>>>(
                wsrc[widx], wsrc[widx], wsrc[widx], wsrc[widx], warena, 512, DFFv);
            bt1 = warena;
            bt2 = warena;
        }
        // FFN1: N=2048, 128x128 tiles, nbx=16, grid 512
        gemm3_k<true, false, true, true><<<32 * 16, 256, 0, stream>>>(
            statebf, bt1, b1, nullptr, hbf, M, DFFv, 512, 16);
        if (!big) {
            tcast_k<<<dim3(8, 32, 1), 256, 0, stream>>>(
                wsrc[widx + 1], wsrc[widx + 1], wsrc[widx + 1], wsrc[widx + 1],
                warena, DFFv, 512);
        }
        gemm2_k<true, true, false, false><<<32 * 8, 256, 0, stream>>>(
            hbf, bt2, b2, statef, t0, M, 512, DFFv, 8);
        ln_k<<<M, 256, 0, stream>>>(t0, g, bb, lnoutf, statebf);
    };

    for (int l = 0; l < LL; ++l) {
        do_mha(x, xbf, xbf, l * 6, e_g1 + l * DD, e_b1 + l * DD, enc_pad);
        do_ffn(x, xbf, l * 6 + 4, e_bb1 + l * DFFv, e_bb2 + l * DD,
               e_g2 + l * DD, e_b2 + l * DD, x);
    }
    for (int l = 0; l < LL; ++l) {
        do_mha(y, ybf, ybf, 12 + l * 10, d_g1 + l * DD, d_b1 + l * DD, dec_pad);
        do_mha(y, ybf, xbf, 12 + l * 10 + 4, d_g2 + l * DD, d_b2 + l * DD, enc_pad);
        const bool last = (l == LL - 1);
        do_ffn(y, ybf, 12 + l * 10 + 8, d_bb1 + l * DFFv, d_bb2 + l * DD,
               d_g3 + l * DD, d_b3 + l * DD, last ? (float*)d_out : y);
    }
}

// Round 8
// 680.083 us; speedup vs baseline: 1.0076x; 1.0076x over previous
//
#include <hip/hip_runtime.h>
#include <hip/hip_bf16.h>

// Problem constants
#define BB 8
#define SS 512
#define DD 512
#define HH 8
#define DQKv 64
#define DFFv 2048
#define LL 2

typedef __attribute__((ext_vector_type(8))) __bf16 bf16x8;
typedef __attribute__((ext_vector_type(4))) float f32x4;

// fp32 -> bf16 (RNE), bf16 -> fp32 helpers on raw ushort bits
static __device__ __forceinline__ ushort f2b(float x) {
    unsigned int u = __float_as_uint(x);
    unsigned int r = (u + 0x7FFFu + ((u >> 16) & 1u)) >> 16;
    return (ushort)r;
}
static __device__ __forceinline__ float b2f(ushort u) {
    return __uint_as_float(((unsigned int)u) << 16);
}

typedef __attribute__((address_space(1))) const unsigned int gas_u32;
typedef __attribute__((address_space(3))) unsigned int las_u32;
static __device__ __forceinline__ void gload16(const void* g, void* l) {
    __builtin_amdgcn_global_load_lds((gas_u32*)g, (las_u32*)l, 16, 0, 0);
}

// ---------------------------------------------------------------------------
// x = in + PE (PE trig computed inline); src->x and trg->y in one grid.
// ---------------------------------------------------------------------------
__global__ __launch_bounds__(256) void add_pe2_k(const float* __restrict__ src,
                                                 const float* __restrict__ trg,
                                                 float* __restrict__ xf,
                                                 ushort* __restrict__ xb,
                                                 float* __restrict__ yf,
                                                 ushort* __restrict__ yb) {
    const int NQ = BB * SS * DD / 4;
    int i = blockIdx.x * 256 + threadIdx.x;       // 0 .. 2*NQ-1
    const bool second = i >= NQ;
    const int ii = second ? i - NQ : i;
    const int rem = ii & (SS * DD / 4 - 1);
    const int d4 = rem & (DD / 4 - 1);            // 0..127
    const int s = rem >> 7;

    float4 a = ((const float4*)(second ? trg : src))[ii];
    const float c = -9.210340371976184f / 512.0f; // -ln(1e4)/D
    const float div0 = __expf((float)(4 * d4) * c);
    const float div1 = __expf((float)(4 * d4 + 2) * c);
    const float a0 = (float)s * div0, a1 = (float)s * div1;
    a.x += sinf(a0); a.y += cosf(a0);
    a.z += sinf(a1); a.w += cosf(a1);

    float* of = second ? yf : xf;
    ushort* ob = second ? yb : xb;
    ((float4*)of)[ii] = a;
    ushort4 ub;
    ub.x = f2b(a.x); ub.y = f2b(a.y); ub.z = f2b(a.z); ub.w = f2b(a.w);
    ((ushort4*)ob)[ii] = ub;
}

// ---------------------------------------------------------------------------
// Per-op weight transpose+cast (fallback when ws is small)
// ---------------------------------------------------------------------------
__global__ __launch_bounds__(256) void tcast_k(const float* __restrict__ s0,
                                               const float* __restrict__ s1,
                                               const float* __restrict__ s2,
                                               const float* __restrict__ s3,
                                               ushort* __restrict__ dst,
                                               int K, int N) {
    __shared__ ushort st[64][72];
    const float* src = (blockIdx.z == 0) ? s0 : (blockIdx.z == 1) ? s1
                     : (blockIdx.z == 2) ? s2 : s3;
    ushort* d = dst + (size_t)blockIdx.z * K * N;
    const int k0 = blockIdx.y * 64, n0 = blockIdx.x * 64;
    const int t = threadIdx.x;
    const int r = t >> 2, c4 = (t & 3) * 16;
#pragma unroll
    for (int i = 0; i < 16; i += 4) {
        float4 v = *(const float4*)&src[(size_t)(k0 + r) * N + n0 + c4 + i];
        st[c4 + i + 0][r] = f2b(v.x);
        st[c4 + i + 1][r] = f2b(v.y);
        st[c4 + i + 2][r] = f2b(v.z);
        st[c4 + i + 3][r] = f2b(v.w);
    }
    __syncthreads();
    const int n = t >> 2, seg = (t & 3) * 16;
    *(uint4*)&d[(size_t)(n0 + n) * K + k0 + seg]     = *(const uint4*)&st[n][seg];
    *(uint4*)&d[(size_t)(n0 + n) * K + k0 + seg + 8] = *(const uint4*)&st[n][seg + 8];
}

// ---------------------------------------------------------------------------
// All-weights transpose+cast in ONE launch.
// ---------------------------------------------------------------------------
#define NW 32
struct WTab {
    const float* src[NW];
    unsigned off[NW];   // dst offset in ushort elems
    int Kd[NW];         // K/64
    int Nd[NW];         // N/64
    int cum[NW + 1];    // tile prefix sums
};

__global__ __launch_bounds__(256) void tcast_all_k(WTab tab, ushort* __restrict__ dst) {
    __shared__ ushort st[64][72];
    const int t = blockIdx.x;
    int m = 0;
    while (t >= tab.cum[m + 1]) ++m;
    const int local = t - tab.cum[m];
    const int ntx = tab.Nd[m];
    const int bx = local % ntx, by = local / ntx;
    const float* src = tab.src[m];
    ushort* d = dst + tab.off[m];
    const int N = ntx * 64, K = tab.Kd[m] * 64;
    const int k0 = by * 64, n0 = bx * 64;

    const int tt = threadIdx.x;
    const int r = tt >> 2, c4 = (tt & 3) * 16;
#pragma unroll
    for (int i = 0; i < 16; i += 4) {
        float4 v = *(const float4*)&src[(size_t)(k0 + r) * N + n0 + c4 + i];
        st[c4 + i + 0][r] = f2b(v.x);
        st[c4 + i + 1][r] = f2b(v.y);
        st[c4 + i + 2][r] = f2b(v.z);
        st[c4 + i + 3][r] = f2b(v.w);
    }
    __syncthreads();
    const int n = tt >> 2, seg = (tt & 3) * 16;
    *(uint4*)&d[(size_t)(n0 + n) * K + k0 + seg]     = *(const uint4*)&st[n][seg];
    *(uint4*)&d[(size_t)(n0 + n) * K + k0 + seg + 8] = *(const uint4*)&st[n][seg + 8];
}

// ---------------------------------------------------------------------------
// bf16 MFMA GEMM, BM=128 BN=64 BK=64, 2-phase double-buffered LDS pipeline:
// issue global_load_lds for tile t+1 into buf^1, MFMA from buf[cur], ONE
// __syncthreads per K-step (drains prefetch vmcnt + protects buffer reuse).
// For N=512 shapes (grid = 256 = 1 block/CU -> pipeline is the only ILP).
// ---------------------------------------------------------------------------
template <bool BIAS, bool RES, bool RELU, bool OUTBF>
__global__ __launch_bounds__(256) void gemm2_k(const ushort* __restrict__ A,
                                               const ushort* __restrict__ Bt,
                                               const float* __restrict__ bias,
                                               const float* __restrict__ res,
                                               void* __restrict__ Cout,
                                               int M, int N, int K, int nbx) {
    __shared__ ushort sA[2][128 * 64];
    __shared__ ushort sB[2][64 * 64];

    const int tid = threadIdx.x;
    const int nwg = gridDim.x;
    const int wg = blockIdx.x;
    const int swz = (wg & 7) * (nwg >> 3) + (wg >> 3);   // XCD-contiguous chunks
    const int bx = swz % nbx, by = swz / nbx;

    const int lane = tid & 63, w = tid >> 6;
    const int wm = w >> 1, wn = w & 1;
    const int llo = lane & 15, lhi = lane >> 4;

    const int srow = tid >> 3;           // 0..31
    const int scol = (tid & 7) * 8;      // element offset in row (8 elems=16B)
    const ushort* Ab = A + (size_t)(by * 128 + srow) * K + scol;
    const ushort* Bb = Bt + (size_t)(bx * 64 + srow) * K + scol;
    const int sOff = srow * 128 + (tid & 7) * 16;   // byte offset in buffer

    f32x4 acc[4][2] = {};
    const int nt = K >> 6;

    // prologue: stage tile 0 into buf 0
#pragma unroll
    for (int i = 0; i < 4; ++i)
        gload16(Ab + (size_t)i * 32 * K, (char*)sA[0] + sOff + i * 32 * 128);
#pragma unroll
    for (int i = 0; i < 2; ++i)
        gload16(Bb + (size_t)i * 32 * K, (char*)sB[0] + sOff + i * 32 * 128);
    __syncthreads();

    int cur = 0;
    for (int t = 0; t < nt; ++t) {
        if (t + 1 < nt) {
            const int k0 = (t + 1) << 6;
#pragma unroll
            for (int i = 0; i < 4; ++i)
                gload16(Ab + (size_t)i * 32 * K + k0, (char*)sA[cur ^ 1] + sOff + i * 32 * 128);
#pragma unroll
            for (int i = 0; i < 2; ++i)
                gload16(Bb + (size_t)i * 32 * K + k0, (char*)sB[cur ^ 1] + sOff + i * 32 * 128);
        }
#pragma unroll
        for (int ks = 0; ks < 2; ++ks) {
            bf16x8 af[4];
#pragma unroll
            for (int fa = 0; fa < 4; ++fa)
                af[fa] = *(const bf16x8*)&sA[cur][(wm * 64 + fa * 16 + llo) * 64 + ks * 32 + lhi * 8];
            bf16x8 bfrag[2];
#pragma unroll
            for (int fb = 0; fb < 2; ++fb)
                bfrag[fb] = *(const bf16x8*)&sB[cur][(wn * 32 + fb * 16 + llo) * 64 + ks * 32 + lhi * 8];
#pragma unroll
            for (int fa = 0; fa < 4; ++fa)
#pragma unroll
                for (int fb = 0; fb < 2; ++fb)
                    acc[fa][fb] = __builtin_amdgcn_mfma_f32_16x16x32_bf16(
                        af[fa], bfrag[fb], acc[fa][fb], 0, 0, 0);
        }
        __syncthreads();   // prefetch done (vmcnt) + all reads of buf[cur] done
        cur ^= 1;
    }

#pragma unroll
    for (int fa = 0; fa < 4; ++fa) {
#pragma unroll
        for (int fb = 0; fb < 2; ++fb) {
            const int col = bx * 64 + wn * 32 + fb * 16 + llo;
            const float bv = BIAS ? bias[col] : 0.f;
#pragma unroll
            for (int j = 0; j < 4; ++j) {
                const int row = by * 128 + wm * 64 + fa * 16 + lhi * 4 + j;
                float v = acc[fa][fb][j] + bv;
                if (RES) v += res[(size_t)row * N + col];
                if (RELU) v = fmaxf(v, 0.f);
                if (OUTBF) ((ushort*)Cout)[(size_t)row * N + col] = f2b(v);
                else       ((float*)Cout)[(size_t)row * N + col] = v;
            }
        }
    }
}

// ---------------------------------------------------------------------------
// bf16 MFMA GEMM, BM=128 BN=128 BK=64, same 2-phase dbuf pipeline, 4 waves
// (2x2), each wave 64x64 via 4x4 frags. For N>=1024 shapes.
// ---------------------------------------------------------------------------
template <bool BIAS, bool RES, bool RELU, bool OUTBF>
__global__ __launch_bounds__(256) void gemm3_k(const ushort* __restrict__ A,
                                               const ushort* __restrict__ Bt,
                                               const float* __restrict__ bias,
                                               const float* __restrict__ res,
                                               void* __restrict__ Cout,
                                               int M, int N, int K, int nbx) {
    __shared__ ushort sA[2][128 * 64];
    __shared__ ushort sB[2][128 * 64];

    const int tid = threadIdx.x;
    const int nwg = gridDim.x;
    const int wg = blockIdx.x;
    const int swz = (wg & 7) * (nwg >> 3) + (wg >> 3);
    const int bx = swz % nbx, by = swz / nbx;

    const int lane = tid & 63, w = tid >> 6;
    const int wm = w >> 1, wn = w & 1;
    const int llo = lane & 15, lhi = lane >> 4;

    const int srow = tid >> 3;           // 0..31
    const ushort* Ab = A + (size_t)(by * 128 + srow) * K + (tid & 7) * 8;
    const ushort* Bb = Bt + (size_t)(bx * 128 + srow) * K + (tid & 7) * 8;
    const int sOff = srow * 128 + (tid & 7) * 16;

    f32x4 acc[4][4] = {};
    const int nt = K >> 6;

#pragma unroll
    for (int i = 0; i < 4; ++i)
        gload16(Ab + (size_t)i * 32 * K, (char*)sA[0] + sOff + i * 32 * 128);
#pragma unroll
    for (int i = 0; i < 4; ++i)
        gload16(Bb + (size_t)i * 32 * K, (char*)sB[0] + sOff + i * 32 * 128);
    __syncthreads();

    int cur = 0;
    for (int t = 0; t < nt; ++t) {
        if (t + 1 < nt) {
            const int k0 = (t + 1) << 6;
#pragma unroll
            for (int i = 0; i < 4; ++i)
                gload16(Ab + (size_t)i * 32 * K + k0, (char*)sA[cur ^ 1] + sOff + i * 32 * 128);
#pragma unroll
            for (int i = 0; i < 4; ++i)
                gload16(Bb + (size_t)i * 32 * K + k0, (char*)sB[cur ^ 1] + sOff + i * 32 * 128);
        }
#pragma unroll
        for (int ks = 0; ks < 2; ++ks) {
            bf16x8 af[4];
#pragma unroll
            for (int fa = 0; fa < 4; ++fa)
                af[fa] = *(const bf16x8*)&sA[cur][(wm * 64 + fa * 16 + llo) * 64 + ks * 32 + lhi * 8];
            bf16x8 bfrag[4];
#pragma unroll
            for (int fb = 0; fb < 4; ++fb)
                bfrag[fb] = *(const bf16x8*)&sB[cur][(wn * 64 + fb * 16 + llo) * 64 + ks * 32 + lhi * 8];
#pragma unroll
            for (int fa = 0; fa < 4; ++fa)
#pragma unroll
                for (int fb = 0; fb < 4; ++fb)
                    acc[fa][fb] = __builtin_amdgcn_mfma_f32_16x16x32_bf16(
                        af[fa], bfrag[fb], acc[fa][fb], 0, 0, 0);
        }
        __syncthreads();
        cur ^= 1;
    }

#pragma unroll
    for (int fa = 0; fa < 4; ++fa) {
#pragma unroll
        for (int fb = 0; fb < 4; ++fb) {
            const int col = bx * 128 + wn * 64 + fb * 16 + llo;
            const float bv = BIAS ? bias[col] : 0.f;
#pragma unroll
            for (int j = 0; j < 4; ++j) {
                const int row = by * 128 + wm * 64 + fa * 16 + lhi * 4 + j;
                float v = acc[fa][fb][j] + bv;
                if (RES) v += res[(size_t)row * N + col];
                if (RELU) v = fmaxf(v, 0.f);
                if (OUTBF) ((ushort*)Cout)[(size_t)row * N + col] = f2b(v);
                else       ((float*)Cout)[(size_t)row * N + col] = v;
            }
        }
    }
}

// ---------------------------------------------------------------------------
// MFMA flash attention on packed QKV [M][1536]. Semantics verified R2-R7.
// ---------------------------------------------------------------------------
__global__ __launch_bounds__(256) void attn_k(const ushort* __restrict__ QKV,
                                              ushort* __restrict__ O,
                                              const int* __restrict__ pad) {
    __shared__ ushort sQ[64][72];
    __shared__ ushort sK[64][72];
    __shared__ ushort sVt[64][72];   // V transposed: [d][key]
    __shared__ ushort sP[64][72];    // P: [q][key-local]

    const int tid = threadIdx.x;
    const int b = blockIdx.z, h = blockIdx.y, q0 = blockIdx.x << 6;
    const int klim = SS - pad[b];
    const int lane = tid & 63, w = tid >> 6;
    const int qw0 = w << 4;
    const int lhi = lane >> 4, llo = lane & 15;
    const int ST = 3 * DD;           // 1536 row stride

    {
        const int r = tid >> 2, seg = (tid & 3) << 4;
        const ushort* src = &QKV[(size_t)(b * SS + q0 + r) * ST + h * DQKv + seg];
        *(uint4*)&sQ[r][seg]     = *(const uint4*)src;
        *(uint4*)&sQ[r][seg + 8] = *(const uint4*)(src + 8);
    }

    auto window = [&](int i, int& wlo, int& whi) {
        if (h < 6) {
            const int step = 4 << (h >> 1);
            const int s2 = step >> 1;
            const int a1 = (i < s2) ? i : s2;
            const int a2 = ((SS - 1 - i) < s2) ? (SS - 1 - i) : s2;
            const int left = (i < SS / 2) ? a1 : (step - a2);
            wlo = i - left;
            whi = wlo + step;
        } else {
            wlo = 0;
            whi = SS - 1;
        }
    };

    int lo[4], hi[4];
#pragma unroll
    for (int j = 0; j < 4; ++j) window(q0 + qw0 + lhi * 4 + j, lo[j], hi[j]);

    int kt0 = 0, kt1 = SS;
    if (h < 6) {
        int lo0, hi0, lo63, hi63;
        window(q0, lo0, hi0);
        window(q0 + 63, lo63, hi63);
        if (lo63 >= klim) {
            kt0 = 0; kt1 = SS;
        } else {
            kt0 = (lo0 >> 6) << 6;
            kt1 = ((hi63 >> 6) + 1) << 6;
            if (kt1 > SS) kt1 = SS;
        }
    }

    float mr[4] = {-1e30f, -1e30f, -1e30f, -1e30f};
    float lr[4] = {0.f, 0.f, 0.f, 0.f};
    f32x4 oacc[4] = {};

    for (int kt = kt0; kt < kt1; kt += 64) {
        __syncthreads();
        {
            const int r = tid >> 2, seg = (tid & 3) << 4;
            const ushort* ksrc = &QKV[(size_t)(b * SS + kt + r) * ST + DD + h * DQKv + seg];
            *(uint4*)&sK[r][seg]     = *(const uint4*)ksrc;
            *(uint4*)&sK[r][seg + 8] = *(const uint4*)(ksrc + 8);
            const ushort* vsrc = &QKV[(size_t)(b * SS + kt + r) * ST + 2 * DD + h * DQKv + seg];
            uint4 u0 = *(const uint4*)vsrc;
            uint4 u1 = *(const uint4*)(vsrc + 8);
            const ushort* v0 = (const ushort*)&u0;
            const ushort* v1 = (const ushort*)&u1;
#pragma unroll
            for (int i = 0; i < 8; ++i) sVt[seg + i][r] = v0[i];
#pragma unroll
            for (int i = 0; i < 8; ++i) sVt[seg + 8 + i][r] = v1[i];
        }
        __syncthreads();

        // ---- QK^T ----
        f32x4 sacc[4] = {};
#pragma unroll
        for (int ks = 0; ks < 2; ++ks) {
            bf16x8 aq = *(const bf16x8*)&sQ[qw0 + llo][ks * 32 + lhi * 8];
#pragma unroll
            for (int n = 0; n < 4; ++n) {
                bf16x8 bk = *(const bf16x8*)&sK[n * 16 + llo][ks * 32 + lhi * 8];
                sacc[n] = __builtin_amdgcn_mfma_f32_16x16x32_bf16(aq, bk, sacc[n], 0, 0, 0);
            }
        }

        // ---- mask + scale + online softmax ----
#pragma unroll
        for (int j = 0; j < 4; ++j) {
            float s[4];
#pragma unroll
            for (int n = 0; n < 4; ++n) {
                const int kidx = kt + n * 16 + llo;
                const bool ok = (kidx < klim) && (kidx >= lo[j]) && (kidx <= hi[j]);
                s[n] = ok ? (sacc[n][j] * 0.125f) : -1e9f;
            }
            float tm = fmaxf(fmaxf(s[0], s[1]), fmaxf(s[2], s[3]));
#pragma unroll
            for (int off = 8; off; off >>= 1) tm = fmaxf(tm, __shfl_xor(tm, off));
            const float mn = fmaxf(mr[j], tm);
            const float alpha = __expf(mr[j] - mn);
            mr[j] = mn;
            float ps = 0.f;
            const int prow = qw0 + lhi * 4 + j;
#pragma unroll
            for (int n = 0; n < 4; ++n) {
                const ushort pb = f2b(__expf(s[n] - mn));
                sP[prow][n * 16 + llo] = pb;
                ps += b2f(pb);
            }
#pragma unroll
            for (int off = 8; off; off >>= 1) ps += __shfl_xor(ps, off);
            lr[j] = lr[j] * alpha + ps;
            oacc[0][j] *= alpha; oacc[1][j] *= alpha;
            oacc[2][j] *= alpha; oacc[3][j] *= alpha;
        }

        // ---- PV ----
#pragma unroll
        for (int ks = 0; ks < 2; ++ks) {
            bf16x8 ap = *(const bf16x8*)&sP[qw0 + llo][ks * 32 + lhi * 8];
#pragma unroll
            for (int n = 0; n < 4; ++n) {
                bf16x8 bv = *(const bf16x8*)&sVt[n * 16 + llo][ks * 32 + lhi * 8];
                oacc[n] = __builtin_amdgcn_mfma_f32_16x16x32_bf16(ap, bv, oacc[n], 0, 0, 0);
            }
        }
    }

#pragma unroll
    for (int j = 0; j < 4; ++j) {
        const float inv = 1.f / lr[j];
        const int q = q0 + qw0 + lhi * 4 + j;
#pragma unroll
        for (int n = 0; n < 4; ++n) {
            O[(size_t)(b * SS + q) * (HH * DQKv) + h * DQKv + n * 16 + llo] =
                f2b(oacc[n][j] * inv);
        }
    }
}

// ---------------------------------------------------------------------------
// LayerNorm over rows of 512; writes fp32 state + bf16 state copy
// ---------------------------------------------------------------------------
__global__ __launch_bounds__(256) void ln_k(const float* __restrict__ in,
                                            const float* __restrict__ g,
                                            const float* __restrict__ bvec,
                                            float* __restrict__ outf,
                                            ushort* __restrict__ outb) {
    const int row = blockIdx.x;
    const int tid = threadIdx.x;
    const float2 xv = *(const float2*)&in[(size_t)row * DD + tid * 2];

    __shared__ float red[4];
    __shared__ float red2[4];
    const int wid = tid >> 6, lane = tid & 63;

    float s = xv.x + xv.y;
#pragma unroll
    for (int off = 32; off; off >>= 1) s += __shfl_xor(s, off);
    if (lane == 0) red[wid] = s;
    __syncthreads();
    const float mu = (red[0] + red[1] + red[2] + red[3]) * (1.f / 512.f);

    const float dx = xv.x - mu, dy = xv.y - mu;
    float q = dx * dx + dy * dy;
#pragma unroll
    for (int off = 32; off; off >>= 1) q += __shfl_xor(q, off);
    if (lane == 0) red2[wid] = q;
    __syncthreads();
    const float var = (red2[0] + red2[1] + red2[2] + red2[3]) * (1.f / 512.f);
    const float rs = rsqrtf(var + 1e-6f);

    float2 o;
    o.x = dx * rs * g[tid * 2] + bvec[tid * 2];
    o.y = dy * rs * g[tid * 2 + 1] + bvec[tid * 2 + 1];
    *(float2*)&outf[(size_t)row * DD + tid * 2] = o;
    ushort2 ub; ub.x = f2b(o.x); ub.y = f2b(o.y);
    *(ushort2*)&outb[(size_t)row * DD + tid * 2] = ub;
}

// ---------------------------------------------------------------------------
// Host orchestration
// ---------------------------------------------------------------------------
extern "C" void kernel_launch(void* const* d_in, const int* in_sizes, int n_in,
                              void* d_out, int out_size, void* d_ws, size_t ws_size,
                              hipStream_t stream) {
    const float* src_seq = (const float*)d_in[0];
    const float* trg_seq = (const float*)d_in[1];
    const int* enc_pad = (const int*)d_in[2];
    const int* dec_pad = (const int*)d_in[3];
    const float* e_wq = (const float*)d_in[4];
    const float* e_wk = (const float*)d_in[5];
    const float* e_wv = (const float*)d_in[6];
    const float* e_wo = (const float*)d_in[7];
    const float* e_g1 = (const float*)d_in[8];
    const float* e_b1 = (const float*)d_in[9];
    const float* e_w1 = (const float*)d_in[10];
    const float* e_bb1 = (const float*)d_in[11];
    const float* e_w2 = (const float*)d_in[12];
    const float* e_bb2 = (const float*)d_in[13];
    const float* e_g2 = (const float*)d_in[14];
    const float* e_b2 = (const float*)d_in[15];
    const float* d_swq = (const float*)d_in[16];
    const float* d_swk = (const float*)d_in[17];
    const float* d_swv = (const float*)d_in[18];
    const float* d_swo = (const float*)d_in[19];
    const float* d_g1 = (const float*)d_in[20];
    const float* d_b1 = (const float*)d_in[21];
    const float* d_cwq = (const float*)d_in[22];
    const float* d_cwk = (const float*)d_in[23];
    const float* d_cwv = (const float*)d_in[24];
    const float* d_cwo = (const float*)d_in[25];
    const float* d_g2 = (const float*)d_in[26];
    const float* d_b2 = (const float*)d_in[27];
    const float* d_w1 = (const float*)d_in[28];
    const float* d_bb1 = (const float*)d_in[29];
    const float* d_w2 = (const float*)d_in[30];
    const float* d_bb2 = (const float*)d_in[31];
    const float* d_g3 = (const float*)d_in[32];
    const float* d_b3 = (const float*)d_in[33];
    (void)in_sizes; (void)n_in; (void)out_size;

    const int M = BB * SS;          // 4096
    const int NTOK = BB * SS * DD;  // 2097152
    const size_t WSZ = (size_t)DD * 512;  // 262144 elems (one 512x512 weight)

    float* ws = (float*)d_ws;
    float* x  = ws;
    float* y  = x + NTOK;
    float* t0 = y + NTOK;
    ushort* xbf  = (ushort*)(t0 + NTOK);
    ushort* ybf  = xbf + NTOK;
    ushort* qkvb = ybf + NTOK;              // M x 1536 packed QKV
    ushort* ob   = qkvb + (size_t)M * 1536;
    ushort* hbf  = qkvb;                    // FFN hidden 4096x2048 aliases qkvb+ob
    ushort* warena = ob + NTOK;

    // ---- weight table ----
    const float* wsrc[NW]; int wK[NW], wN[NW]; size_t woff[NW];
    int wcnt = 0; size_t acc = 0;
    auto push = [&](const float* p, int K, int N) {
        wsrc[wcnt] = p; wK[wcnt] = K; wN[wcnt] = N; woff[wcnt] = acc;
        acc += (size_t)K * N; ++wcnt;
    };
    for (int l = 0; l < LL; ++l) {
        push(e_wq + (size_t)l * WSZ, 512, 512);
        push(e_wk + (size_t)l * WSZ, 512, 512);
        push(e_wv + (size_t)l * WSZ, 512, 512);
        push(e_wo + (size_t)l * WSZ, 512, 512);
        push(e_w1 + (size_t)l * DD * DFFv, 512, DFFv);
        push(e_w2 + (size_t)l * DFFv * DD, DFFv, 512);
    }
    for (int l = 0; l < LL; ++l) {
        push(d_swq + (size_t)l * WSZ, 512, 512);
        push(d_swk + (size_t)l * WSZ, 512, 512);
        push(d_swv + (size_t)l * WSZ, 512, 512);
        push(d_swo + (size_t)l * WSZ, 512, 512);
        push(d_cwq + (size_t)l * WSZ, 512, 512);
        push(d_cwk + (size_t)l * WSZ, 512, 512);
        push(d_cwv + (size_t)l * WSZ, 512, 512);
        push(d_cwo + (size_t)l * WSZ, 512, 512);
        push(d_w1 + (size_t)l * DD * DFFv, 512, DFFv);
        push(d_w2 + (size_t)l * DFFv * DD, DFFv, 512);
    }

    const size_t base_bytes = (size_t)(warena - (ushort*)d_ws) * 2;
    const bool big = ws_size >= base_bytes + acc * 2;

    if (big) {
        WTab tab;
        int tiles = 0;
        for (int i = 0; i < NW; ++i) {
            tab.src[i] = wsrc[i];
            tab.off[i] = (unsigned)woff[i];
            tab.Kd[i] = wK[i] / 64;
            tab.Nd[i] = wN[i] / 64;
            tab.cum[i] = tiles;
            tiles += (wK[i] / 64) * (wN[i] / 64);
        }
        tab.cum[NW] = tiles;
        tcast_all_k<<<tiles, 256, 0, stream>>>(tab, warena);
    }

    add_pe2_k<<<2 * NTOK / 4 / 256, 256, 0, stream>>>(src_seq, trg_seq, x, xbf, y, ybf);

    auto do_mha = [&](float* statef, ushort* statebf, const ushort* kvbf, int widx,
                      const float* g, const float* bb, const int* pad) {
        const ushort* bt;
        if (big) {
            bt = warena + woff[widx];
        } else {
            tcast_k<<<dim3(8, 8, 4), 256, 0, stream>>>(
                wsrc[widx], wsrc[widx + 1], wsrc[widx + 2], wsrc[widx + 3],
                warena, 512, 512);
            bt = warena;
        }
        if (kvbf == statebf) {
            // packed QKV: 128x128 tiles, nbx = 1536/128 = 12, grid 384
            gemm3_k<false, false, false, true><<<32 * 12, 256, 0, stream>>>(
                statebf, bt, nullptr, nullptr, qkvb, M, 1536, 512, 12);
        } else {
            // cross-attn: Q (512 cols) 128x64; K/V (1024 cols) 128x128
            gemm2_k<false, false, false, true><<<32 * 8, 256, 0, stream>>>(
                statebf, bt + 0 * WSZ, nullptr, nullptr, qkvb, M, 1536, 512, 8);
            gemm3_k<false, false, false, true><<<32 * 8, 256, 0, stream>>>(
                kvbf, bt + 1 * WSZ, nullptr, nullptr, qkvb + DD, M, 1536, 512, 8);
        }
        attn_k<<<dim3(SS / 64, HH, BB), 256, 0, stream>>>(qkvb, ob, pad);
        gemm2_k<false, true, false, false><<<32 * 8, 256, 0, stream>>>(
            ob, bt + 3 * WSZ, nullptr, statef, t0, M, 512, 512, 8);
        ln_k<<<M, 256, 0, stream>>>(t0, g, bb, statef, statebf);
    };
    auto do_ffn = [&](float* statef, ushort* statebf, int widx,
                      const float* b1, const float* b2,
                      const float* g, const float* bb, float* lnoutf) {
        const ushort* bt1;
        const ushort* bt2;
        if (big) {
            bt1 = warena + woff[widx];
            bt2 = warena + woff[widx + 1];
        } else {
            tcast_k<<<dim3(32, 8, 1), 256, 0, stream>>>(
                wsrc[widx], wsrc[widx], wsrc[widx], wsrc[widx], warena, 512, DFFv);
            bt1 = warena;
            bt2 = warena;
        }
        // FFN1: N=2048, 128x128 tiles, nbx=16, grid 512
        gemm3_k<true, false, true, true><<<32 * 16, 256, 0, stream>>>(
            statebf, bt1, b1, nullptr, hbf, M, DFFv, 512, 16);
        if (!big) {
            tcast_k<<<dim3(8, 32, 1), 256, 0, stream>>>(
                wsrc[widx + 1], wsrc[widx + 1], wsrc[widx + 1], wsrc[widx + 1],
                warena, DFFv, 512);
        }
        gemm2_k<true, true, false, false><<<32 * 8, 256, 0, stream>>>(
            hbf, bt2, b2, statef, t0, M, 512, DFFv, 8);
        ln_k<<<M, 256, 0, stream>>>(t0, g, bb, lnoutf, statebf);
    };

    for (int l = 0; l < LL; ++l) {
        do_mha(x, xbf, xbf, l * 6, e_g1 + l * DD, e_b1 + l * DD, enc_pad);
        do_ffn(x, xbf, l * 6 + 4, e_bb1 + l * DFFv, e_bb2 + l * DD,
               e_g2 + l * DD, e_b2 + l * DD, x);
    }
    for (int l = 0; l < LL; ++l) {
        do_mha(y, ybf, ybf, 12 + l * 10, d_g1 + l * DD, d_b1 + l * DD, dec_pad);
        do_mha(y, ybf, xbf, 12 + l * 10 + 4, d_g2 + l * DD, d_b2 + l * DD, enc_pad);
        const bool last = (l == LL - 1);
        do_ffn(y, ybf, 12 + l * 10 + 8, d_bb1 + l * DFFv, d_bb2 + l * DD,
               d_g3 + l * DD, d_b3 + l * DD, last ? (float*)d_out : y);
    }
}

// Round 9
// 628.395 us; speedup vs baseline: 1.0904x; 1.0823x over previous
//
#include <hip/hip_runtime.h>
#include <hip/hip_bf16.h>

// Problem constants
#define BB 8
#define SS 512
#define DD 512
#define HH 8
#define DQKv 64
#define DFFv 2048
#define LL 2

typedef __attribute__((ext_vector_type(8))) __bf16 bf16x8;
typedef __attribute__((ext_vector_type(4))) float f32x4;

// fp32 -> bf16 (RNE), bf16 -> fp32 helpers on raw ushort bits
static __device__ __forceinline__ ushort f2b(float x) {
    unsigned int u = __float_as_uint(x);
    unsigned int r = (u + 0x7FFFu + ((u >> 16) & 1u)) >> 16;
    return (ushort)r;
}
static __device__ __forceinline__ float b2f(ushort u) {
    return __uint_as_float(((unsigned int)u) << 16);
}

typedef __attribute__((address_space(1))) const unsigned int gas_u32;
typedef __attribute__((address_space(3))) unsigned int las_u32;
static __device__ __forceinline__ void gload16(const void* g, void* l) {
    __builtin_amdgcn_global_load_lds((gas_u32*)g, (las_u32*)l, 16, 0, 0);
}

// ---------------------------------------------------------------------------
// x = in + PE (PE trig computed inline); src->x and trg->y in one grid.
// ---------------------------------------------------------------------------
__global__ __launch_bounds__(256) void add_pe2_k(const float* __restrict__ src,
                                                 const float* __restrict__ trg,
                                                 float* __restrict__ xf,
                                                 ushort* __restrict__ xb,
                                                 float* __restrict__ yf,
                                                 ushort* __restrict__ yb) {
    const int NQ = BB * SS * DD / 4;
    int i = blockIdx.x * 256 + threadIdx.x;       // 0 .. 2*NQ-1
    const bool second = i >= NQ;
    const int ii = second ? i - NQ : i;
    const int rem = ii & (SS * DD / 4 - 1);
    const int d4 = rem & (DD / 4 - 1);            // 0..127
    const int s = rem >> 7;

    float4 a = ((const float4*)(second ? trg : src))[ii];
    const float c = -9.210340371976184f / 512.0f; // -ln(1e4)/D
    const float div0 = __expf((float)(4 * d4) * c);
    const float div1 = __expf((float)(4 * d4 + 2) * c);
    const float a0 = (float)s * div0, a1 = (float)s * div1;
    a.x += sinf(a0); a.y += cosf(a0);
    a.z += sinf(a1); a.w += cosf(a1);

    float* of = second ? yf : xf;
    ushort* ob = second ? yb : xb;
    ((float4*)of)[ii] = a;
    ushort4 ub;
    ub.x = f2b(a.x); ub.y = f2b(a.y); ub.z = f2b(a.z); ub.w = f2b(a.w);
    ((ushort4*)ob)[ii] = ub;
}

// ---------------------------------------------------------------------------
// Per-op weight transpose+cast (fallback when ws is small)
// ---------------------------------------------------------------------------
__global__ __launch_bounds__(256) void tcast_k(const float* __restrict__ s0,
                                               const float* __restrict__ s1,
                                               const float* __restrict__ s2,
                                               const float* __restrict__ s3,
                                               ushort* __restrict__ dst,
                                               int K, int N) {
    __shared__ ushort st[64][72];
    const float* src = (blockIdx.z == 0) ? s0 : (blockIdx.z == 1) ? s1
                     : (blockIdx.z == 2) ? s2 : s3;
    ushort* d = dst + (size_t)blockIdx.z * K * N;
    const int k0 = blockIdx.y * 64, n0 = blockIdx.x * 64;
    const int t = threadIdx.x;
    const int r = t >> 2, c4 = (t & 3) * 16;
#pragma unroll
    for (int i = 0; i < 16; i += 4) {
        float4 v = *(const float4*)&src[(size_t)(k0 + r) * N + n0 + c4 + i];
        st[c4 + i + 0][r] = f2b(v.x);
        st[c4 + i + 1][r] = f2b(v.y);
        st[c4 + i + 2][r] = f2b(v.z);
        st[c4 + i + 3][r] = f2b(v.w);
    }
    __syncthreads();
    const int n = t >> 2, seg = (t & 3) * 16;
    *(uint4*)&d[(size_t)(n0 + n) * K + k0 + seg]     = *(const uint4*)&st[n][seg];
    *(uint4*)&d[(size_t)(n0 + n) * K + k0 + seg + 8] = *(const uint4*)&st[n][seg + 8];
}

// ---------------------------------------------------------------------------
// All-weights transpose+cast in ONE launch.
// ---------------------------------------------------------------------------
#define NW 32
struct WTab {
    const float* src[NW];
    unsigned off[NW];   // dst offset in ushort elems
    int Kd[NW];         // K/64
    int Nd[NW];         // N/64
    int cum[NW + 1];    // tile prefix sums
};

__global__ __launch_bounds__(256) void tcast_all_k(WTab tab, ushort* __restrict__ dst) {
    __shared__ ushort st[64][72];
    const int t = blockIdx.x;
    int m = 0;
    while (t >= tab.cum[m + 1]) ++m;
    const int local = t - tab.cum[m];
    const int ntx = tab.Nd[m];
    const int bx = local % ntx, by = local / ntx;
    const float* src = tab.src[m];
    ushort* d = dst + tab.off[m];
    const int N = ntx * 64, K = tab.Kd[m] * 64;
    const int k0 = by * 64, n0 = bx * 64;

    const int tt = threadIdx.x;
    const int r = tt >> 2, c4 = (tt & 3) * 16;
#pragma unroll
    for (int i = 0; i < 16; i += 4) {
        float4 v = *(const float4*)&src[(size_t)(k0 + r) * N + n0 + c4 + i];
        st[c4 + i + 0][r] = f2b(v.x);
        st[c4 + i + 1][r] = f2b(v.y);
        st[c4 + i + 2][r] = f2b(v.z);
        st[c4 + i + 3][r] = f2b(v.w);
    }
    __syncthreads();
    const int n = tt >> 2, seg = (tt & 3) * 16;
    *(uint4*)&d[(size_t)(n0 + n) * K + k0 + seg]     = *(const uint4*)&st[n][seg];
    *(uint4*)&d[(size_t)(n0 + n) * K + k0 + seg + 8] = *(const uint4*)&st[n][seg + 8];
}

// ---------------------------------------------------------------------------
// bf16 MFMA GEMM, BM=128 BN=64 BK=64, 2-phase dbuf pipeline + chunk-XOR
// LDS swizzle (T2, rule #21: linear LDS dest, pre-swizzled GLOBAL source,
// swizzled read). Physical chunk p at row r holds logical chunk p^(r&7);
// frag read uses chunk (ks*4+lhi)^(llo&7) -> 2-way max -> conflict-free.
// ---------------------------------------------------------------------------
template <bool BIAS, bool RES, bool RELU, bool OUTBF>
__global__ __launch_bounds__(256) void gemm2_k(const ushort* __restrict__ A,
                                               const ushort* __restrict__ Bt,
                                               const float* __restrict__ bias,
                                               const float* __restrict__ res,
                                               void* __restrict__ Cout,
                                               int M, int N, int K, int nbx) {
    __shared__ ushort sA[2][128 * 64];
    __shared__ ushort sB[2][64 * 64];

    const int tid = threadIdx.x;
    const int nwg = gridDim.x;
    const int wg = blockIdx.x;
    const int swz = (wg & 7) * (nwg >> 3) + (wg >> 3);   // XCD-contiguous chunks
    const int bx = swz % nbx, by = swz / nbx;

    const int lane = tid & 63, w = tid >> 6;
    const int wm = w >> 1, wn = w & 1;
    const int llo = lane & 15, lhi = lane >> 4;

    const int srow = tid >> 3;           // 0..31 (row blocks step by 32 == 0 mod 8)
    const int scol = (((tid & 7) ^ (srow & 7)) * 8);  // swizzled logical chunk
    const ushort* Ab = A + (size_t)(by * 128 + srow) * K + scol;
    const ushort* Bb = Bt + (size_t)(bx * 64 + srow) * K + scol;
    const int sOff = srow * 128 + (tid & 7) * 16;   // linear LDS dest (bytes)

    f32x4 acc[4][2] = {};
    const int nt = K >> 6;

    // prologue: stage tile 0 into buf 0
#pragma unroll
    for (int i = 0; i < 4; ++i)
        gload16(Ab + (size_t)i * 32 * K, (char*)sA[0] + sOff + i * 32 * 128);
#pragma unroll
    for (int i = 0; i < 2; ++i)
        gload16(Bb + (size_t)i * 32 * K, (char*)sB[0] + sOff + i * 32 * 128);
    __syncthreads();

    int cur = 0;
    for (int t = 0; t < nt; ++t) {
        if (t + 1 < nt) {
            const int k0 = (t + 1) << 6;
#pragma unroll
            for (int i = 0; i < 4; ++i)
                gload16(Ab + (size_t)i * 32 * K + k0, (char*)sA[cur ^ 1] + sOff + i * 32 * 128);
#pragma unroll
            for (int i = 0; i < 2; ++i)
                gload16(Bb + (size_t)i * 32 * K + k0, (char*)sB[cur ^ 1] + sOff + i * 32 * 128);
        }
        const int sw = llo & 7;   // row&7 for all this lane's frag rows
#pragma unroll
        for (int ks = 0; ks < 2; ++ks) {
            bf16x8 af[4];
#pragma unroll
            for (int fa = 0; fa < 4; ++fa)
                af[fa] = *(const bf16x8*)&sA[cur][(wm * 64 + fa * 16 + llo) * 64 +
                                                  (((ks * 4 + lhi) ^ sw) * 8)];
            bf16x8 bfrag[2];
#pragma unroll
            for (int fb = 0; fb < 2; ++fb)
                bfrag[fb] = *(const bf16x8*)&sB[cur][(wn * 32 + fb * 16 + llo) * 64 +
                                                     (((ks * 4 + lhi) ^ sw) * 8)];
#pragma unroll
            for (int fa = 0; fa < 4; ++fa)
#pragma unroll
                for (int fb = 0; fb < 2; ++fb)
                    acc[fa][fb] = __builtin_amdgcn_mfma_f32_16x16x32_bf16(
                        af[fa], bfrag[fb], acc[fa][fb], 0, 0, 0);
        }
        __syncthreads();   // prefetch done (vmcnt) + all reads of buf[cur] done
        cur ^= 1;
    }

#pragma unroll
    for (int fa = 0; fa < 4; ++fa) {
#pragma unroll
        for (int fb = 0; fb < 2; ++fb) {
            const int col = bx * 64 + wn * 32 + fb * 16 + llo;
            const float bv = BIAS ? bias[col] : 0.f;
#pragma unroll
            for (int j = 0; j < 4; ++j) {
                const int row = by * 128 + wm * 64 + fa * 16 + lhi * 4 + j;
                float v = acc[fa][fb][j] + bv;
                if (RES) v += res[(size_t)row * N + col];
                if (RELU) v = fmaxf(v, 0.f);
                if (OUTBF) ((ushort*)Cout)[(size_t)row * N + col] = f2b(v);
                else       ((float*)Cout)[(size_t)row * N + col] = v;
            }
        }
    }
}

// ---------------------------------------------------------------------------
// bf16 MFMA GEMM, BM=128 BN=128 BK=64, same pipeline + same XOR swizzle.
// ---------------------------------------------------------------------------
template <bool BIAS, bool RES, bool RELU, bool OUTBF>
__global__ __launch_bounds__(256) void gemm3_k(const ushort* __restrict__ A,
                                               const ushort* __restrict__ Bt,
                                               const float* __restrict__ bias,
                                               const float* __restrict__ res,
                                               void* __restrict__ Cout,
                                               int M, int N, int K, int nbx) {
    __shared__ ushort sA[2][128 * 64];
    __shared__ ushort sB[2][128 * 64];

    const int tid = threadIdx.x;
    const int nwg = gridDim.x;
    const int wg = blockIdx.x;
    const int swz = (wg & 7) * (nwg >> 3) + (wg >> 3);
    const int bx = swz % nbx, by = swz / nbx;

    const int lane = tid & 63, w = tid >> 6;
    const int wm = w >> 1, wn = w & 1;
    const int llo = lane & 15, lhi = lane >> 4;

    const int srow = tid >> 3;           // 0..31
    const int scol = (((tid & 7) ^ (srow & 7)) * 8);
    const ushort* Ab = A + (size_t)(by * 128 + srow) * K + scol;
    const ushort* Bb = Bt + (size_t)(bx * 128 + srow) * K + scol;
    const int sOff = srow * 128 + (tid & 7) * 16;

    f32x4 acc[4][4] = {};
    const int nt = K >> 6;

#pragma unroll
    for (int i = 0; i < 4; ++i)
        gload16(Ab + (size_t)i * 32 * K, (char*)sA[0] + sOff + i * 32 * 128);
#pragma unroll
    for (int i = 0; i < 4; ++i)
        gload16(Bb + (size_t)i * 32 * K, (char*)sB[0] + sOff + i * 32 * 128);
    __syncthreads();

    int cur = 0;
    for (int t = 0; t < nt; ++t) {
        if (t + 1 < nt) {
            const int k0 = (t + 1) << 6;
#pragma unroll
            for (int i = 0; i < 4; ++i)
                gload16(Ab + (size_t)i * 32 * K + k0, (char*)sA[cur ^ 1] + sOff + i * 32 * 128);
#pragma unroll
            for (int i = 0; i < 4; ++i)
                gload16(Bb + (size_t)i * 32 * K + k0, (char*)sB[cur ^ 1] + sOff + i * 32 * 128);
        }
        const int sw = llo & 7;
#pragma unroll
        for (int ks = 0; ks < 2; ++ks) {
            bf16x8 af[4];
#pragma unroll
            for (int fa = 0; fa < 4; ++fa)
                af[fa] = *(const bf16x8*)&sA[cur][(wm * 64 + fa * 16 + llo) * 64 +
                                                  (((ks * 4 + lhi) ^ sw) * 8)];
            bf16x8 bfrag[4];
#pragma unroll
            for (int fb = 0; fb < 4; ++fb)
                bfrag[fb] = *(const bf16x8*)&sB[cur][(wn * 64 + fb * 16 + llo) * 64 +
                                                     (((ks * 4 + lhi) ^ sw) * 8)];
#pragma unroll
            for (int fa = 0; fa < 4; ++fa)
#pragma unroll
                for (int fb = 0; fb < 4; ++fb)
                    acc[fa][fb] = __builtin_amdgcn_mfma_f32_16x16x32_bf16(
                        af[fa], bfrag[fb], acc[fa][fb], 0, 0, 0);
        }
        __syncthreads();
        cur ^= 1;
    }

#pragma unroll
    for (int fa = 0; fa < 4; ++fa) {
#pragma unroll
        for (int fb = 0; fb < 4; ++fb) {
            const int col = bx * 128 + wn * 64 + fb * 16 + llo;
            const float bv = BIAS ? bias[col] : 0.f;
#pragma unroll
            for (int j = 0; j < 4; ++j) {
                const int row = by * 128 + wm * 64 + fa * 16 + lhi * 4 + j;
                float v = acc[fa][fb][j] + bv;
                if (RES) v += res[(size_t)row * N + col];
                if (RELU) v = fmaxf(v, 0.f);
                if (OUTBF) ((ushort*)Cout)[(size_t)row * N + col] = f2b(v);
                else       ((float*)Cout)[(size_t)row * N + col] = v;
            }
        }
    }
}

// ---------------------------------------------------------------------------
// MFMA flash attention on packed QKV [M][1536]. Semantics verified R2-R8.
// (LDS rows padded to 72 elems -> bank rotation already conflict-free.)
// ---------------------------------------------------------------------------
__global__ __launch_bounds__(256) void attn_k(const ushort* __restrict__ QKV,
                                              ushort* __restrict__ O,
                                              const int* __restrict__ pad) {
    __shared__ ushort sQ[64][72];
    __shared__ ushort sK[64][72];
    __shared__ ushort sVt[64][72];   // V transposed: [d][key]
    __shared__ ushort sP[64][72];    // P: [q][key-local]

    const int tid = threadIdx.x;
    const int b = blockIdx.z, h = blockIdx.y, q0 = blockIdx.x << 6;
    const int klim = SS - pad[b];
    const int lane = tid & 63, w = tid >> 6;
    const int qw0 = w << 4;
    const int lhi = lane >> 4, llo = lane & 15;
    const int ST = 3 * DD;           // 1536 row stride

    {
        const int r = tid >> 2, seg = (tid & 3) << 4;
        const ushort* src = &QKV[(size_t)(b * SS + q0 + r) * ST + h * DQKv + seg];
        *(uint4*)&sQ[r][seg]     = *(const uint4*)src;
        *(uint4*)&sQ[r][seg + 8] = *(const uint4*)(src + 8);
    }

    auto window = [&](int i, int& wlo, int& whi) {
        if (h < 6) {
            const int step = 4 << (h >> 1);
            const int s2 = step >> 1;
            const int a1 = (i < s2) ? i : s2;
            const int a2 = ((SS - 1 - i) < s2) ? (SS - 1 - i) : s2;
            const int left = (i < SS / 2) ? a1 : (step - a2);
            wlo = i - left;
            whi = wlo + step;
        } else {
            wlo = 0;
            whi = SS - 1;
        }
    };

    int lo[4], hi[4];
#pragma unroll
    for (int j = 0; j < 4; ++j) window(q0 + qw0 + lhi * 4 + j, lo[j], hi[j]);

    int kt0 = 0, kt1 = SS;
    if (h < 6) {
        int lo0, hi0, lo63, hi63;
        window(q0, lo0, hi0);
        window(q0 + 63, lo63, hi63);
        if (lo63 >= klim) {
            kt0 = 0; kt1 = SS;
        } else {
            kt0 = (lo0 >> 6) << 6;
            kt1 = ((hi63 >> 6) + 1) << 6;
            if (kt1 > SS) kt1 = SS;
        }
    }

    float mr[4] = {-1e30f, -1e30f, -1e30f, -1e30f};
    float lr[4] = {0.f, 0.f, 0.f, 0.f};
    f32x4 oacc[4] = {};

    for (int kt = kt0; kt < kt1; kt += 64) {
        __syncthreads();
        {
            const int r = tid >> 2, seg = (tid & 3) << 4;
            const ushort* ksrc = &QKV[(size_t)(b * SS + kt + r) * ST + DD + h * DQKv + seg];
            *(uint4*)&sK[r][seg]     = *(const uint4*)ksrc;
            *(uint4*)&sK[r][seg + 8] = *(const uint4*)(ksrc + 8);
            const ushort* vsrc = &QKV[(size_t)(b * SS + kt + r) * ST + 2 * DD + h * DQKv + seg];
            uint4 u0 = *(const uint4*)vsrc;
            uint4 u1 = *(const uint4*)(vsrc + 8);
            const ushort* v0 = (const ushort*)&u0;
            const ushort* v1 = (const ushort*)&u1;
#pragma unroll
            for (int i = 0; i < 8; ++i) sVt[seg + i][r] = v0[i];
#pragma unroll
            for (int i = 0; i < 8; ++i) sVt[seg + 8 + i][r] = v1[i];
        }
        __syncthreads();

        // ---- QK^T ----
        f32x4 sacc[4] = {};
#pragma unroll
        for (int ks = 0; ks < 2; ++ks) {
            bf16x8 aq = *(const bf16x8*)&sQ[qw0 + llo][ks * 32 + lhi * 8];
#pragma unroll
            for (int n = 0; n < 4; ++n) {
                bf16x8 bk = *(const bf16x8*)&sK[n * 16 + llo][ks * 32 + lhi * 8];
                sacc[n] = __builtin_amdgcn_mfma_f32_16x16x32_bf16(aq, bk, sacc[n], 0, 0, 0);
            }
        }

        // ---- mask + scale + online softmax ----
#pragma unroll
        for (int j = 0; j < 4; ++j) {
            float s[4];
#pragma unroll
            for (int n = 0; n < 4; ++n) {
                const int kidx = kt + n * 16 + llo;
                const bool ok = (kidx < klim) && (kidx >= lo[j]) && (kidx <= hi[j]);
                s[n] = ok ? (sacc[n][j] * 0.125f) : -1e9f;
            }
            float tm = fmaxf(fmaxf(s[0], s[1]), fmaxf(s[2], s[3]));
#pragma unroll
            for (int off = 8; off; off >>= 1) tm = fmaxf(tm, __shfl_xor(tm, off));
            const float mn = fmaxf(mr[j], tm);
            const float alpha = __expf(mr[j] - mn);
            mr[j] = mn;
            float ps = 0.f;
            const int prow = qw0 + lhi * 4 + j;
#pragma unroll
            for (int n = 0; n < 4; ++n) {
                const ushort pb = f2b(__expf(s[n] - mn));
                sP[prow][n * 16 + llo] = pb;
                ps += b2f(pb);
            }
#pragma unroll
            for (int off = 8; off; off >>= 1) ps += __shfl_xor(ps, off);
            lr[j] = lr[j] * alpha + ps;
            oacc[0][j] *= alpha; oacc[1][j] *= alpha;
            oacc[2][j] *= alpha; oacc[3][j] *= alpha;
        }

        // ---- PV ----
#pragma unroll
        for (int ks = 0; ks < 2; ++ks) {
            bf16x8 ap = *(const bf16x8*)&sP[qw0 + llo][ks * 32 + lhi * 8];
#pragma unroll
            for (int n = 0; n < 4; ++n) {
                bf16x8 bv = *(const bf16x8*)&sVt[n * 16 + llo][ks * 32 + lhi * 8];
                oacc[n] = __builtin_amdgcn_mfma_f32_16x16x32_bf16(ap, bv, oacc[n], 0, 0, 0);
            }
        }
    }

#pragma unroll
    for (int j = 0; j < 4; ++j) {
        const float inv = 1.f / lr[j];
        const int q = q0 + qw0 + lhi * 4 + j;
#pragma unroll
        for (int n = 0; n < 4; ++n) {
            O[(size_t)(b * SS + q) * (HH * DQKv) + h * DQKv + n * 16 + llo] =
                f2b(oacc[n][j] * inv);
        }
    }
}

// ---------------------------------------------------------------------------
// LayerNorm over rows of 512; writes fp32 state + bf16 state copy
// ---------------------------------------------------------------------------
__global__ __launch_bounds__(256) void ln_k(const float* __restrict__ in,
                                            const float* __restrict__ g,
                                            const float* __restrict__ bvec,
                                            float* __restrict__ outf,
                                            ushort* __restrict__ outb) {
    const int row = blockIdx.x;
    const int tid = threadIdx.x;
    const float2 xv = *(const float2*)&in[(size_t)row * DD + tid * 2];

    __shared__ float red[4];
    __shared__ float red2[4];
    const int wid = tid >> 6, lane = tid & 63;

    float s = xv.x + xv.y;
#pragma unroll
    for (int off = 32; off; off >>= 1) s += __shfl_xor(s, off);
    if (lane == 0) red[wid] = s;
    __syncthreads();
    const float mu = (red[0] + red[1] + red[2] + red[3]) * (1.f / 512.f);

    const float dx = xv.x - mu, dy = xv.y - mu;
    float q = dx * dx + dy * dy;
#pragma unroll
    for (int off = 32; off; off >>= 1) q += __shfl_xor(q, off);
    if (lane == 0) red2[wid] = q;
    __syncthreads();
    const float var = (red2[0] + red2[1] + red2[2] + red2[3]) * (1.f / 512.f);
    const float rs = rsqrtf(var + 1e-6f);

    float2 o;
    o.x = dx * rs * g[tid * 2] + bvec[tid * 2];
    o.y = dy * rs * g[tid * 2 + 1] + bvec[tid * 2 + 1];
    *(float2*)&outf[(size_t)row * DD + tid * 2] = o;
    ushort2 ub; ub.x = f2b(o.x); ub.y = f2b(o.y);
    *(ushort2*)&outb[(size_t)row * DD + tid * 2] = ub;
}

// ---------------------------------------------------------------------------
// Host orchestration
// ---------------------------------------------------------------------------
extern "C" void kernel_launch(void* const* d_in, const int* in_sizes, int n_in,
                              void* d_out, int out_size, void* d_ws, size_t ws_size,
                              hipStream_t stream) {
    const float* src_seq = (const float*)d_in[0];
    const float* trg_seq = (const float*)d_in[1];
    const int* enc_pad = (const int*)d_in[2];
    const int* dec_pad = (const int*)d_in[3];
    const float* e_wq = (const float*)d_in[4];
    const float* e_wk = (const float*)d_in[5];
    const float* e_wv = (const float*)d_in[6];
    const float* e_wo = (const float*)d_in[7];
    const float* e_g1 = (const float*)d_in[8];
    const float* e_b1 = (const float*)d_in[9];
    const float* e_w1 = (const float*)d_in[10];
    const float* e_bb1 = (const float*)d_in[11];
    const float* e_w2 = (const float*)d_in[12];
    const float* e_bb2 = (const float*)d_in[13];
    const float* e_g2 = (const float*)d_in[14];
    const float* e_b2 = (const float*)d_in[15];
    const float* d_swq = (const float*)d_in[16];
    const float* d_swk = (const float*)d_in[17];
    const float* d_swv = (const float*)d_in[18];
    const float* d_swo = (const float*)d_in[19];
    const float* d_g1 = (const float*)d_in[20];
    const float* d_b1 = (const float*)d_in[21];
    const float* d_cwq = (const float*)d_in[22];
    const float* d_cwk = (const float*)d_in[23];
    const float* d_cwv = (const float*)d_in[24];
    const float* d_cwo = (const float*)d_in[25];
    const float* d_g2 = (const float*)d_in[26];
    const float* d_b2 = (const float*)d_in[27];
    const float* d_w1 = (const float*)d_in[28];
    const float* d_bb1 = (const float*)d_in[29];
    const float* d_w2 = (const float*)d_in[30];
    const float* d_bb2 = (const float*)d_in[31];
    const float* d_g3 = (const float*)d_in[32];
    const float* d_b3 = (const float*)d_in[33];
    (void)in_sizes; (void)n_in; (void)out_size;

    const int M = BB * SS;          // 4096
    const int NTOK = BB * SS * DD;  // 2097152
    const size_t WSZ = (size_t)DD * 512;  // 262144 elems (one 512x512 weight)

    float* ws = (float*)d_ws;
    float* x  = ws;
    float* y  = x + NTOK;
    float* t0 = y + NTOK;
    ushort* xbf  = (ushort*)(t0 + NTOK);
    ushort* ybf  = xbf + NTOK;
    ushort* qkvb = ybf + NTOK;              // M x 1536 packed QKV
    ushort* ob   = qkvb + (size_t)M * 1536;
    ushort* hbf  = qkvb;                    // FFN hidden 4096x2048 aliases qkvb+ob
    ushort* warena = ob + NTOK;

    // ---- weight table ----
    const float* wsrc[NW]; int wK[NW], wN[NW]; size_t woff[NW];
    int wcnt = 0; size_t acc = 0;
    auto push = [&](const float* p, int K, int N) {
        wsrc[wcnt] = p; wK[wcnt] = K; wN[wcnt] = N; woff[wcnt] = acc;
        acc += (size_t)K * N; ++wcnt;
    };
    for (int l = 0; l < LL; ++l) {
        push(e_wq + (size_t)l * WSZ, 512, 512);
        push(e_wk + (size_t)l * WSZ, 512, 512);
        push(e_wv + (size_t)l * WSZ, 512, 512);
        push(e_wo + (size_t)l * WSZ, 512, 512);
        push(e_w1 + (size_t)l * DD * DFFv, 512, DFFv);
        push(e_w2 + (size_t)l * DFFv * DD, DFFv, 512);
    }
    for (int l = 0; l < LL; ++l) {
        push(d_swq + (size_t)l * WSZ, 512, 512);
        push(d_swk + (size_t)l * WSZ, 512, 512);
        push(d_swv + (size_t)l * WSZ, 512, 512);
        push(d_swo + (size_t)l * WSZ, 512, 512);
        push(d_cwq + (size_t)l * WSZ, 512, 512);
        push(d_cwk + (size_t)l * WSZ, 512, 512);
        push(d_cwv + (size_t)l * WSZ, 512, 512);
        push(d_cwo + (size_t)l * WSZ, 512, 512);
        push(d_w1 + (size_t)l * DD * DFFv, 512, DFFv);
        push(d_w2 + (size_t)l * DFFv * DD, DFFv, 512);
    }

    const size_t base_bytes = (size_t)(warena - (ushort*)d_ws) * 2;
    const bool big = ws_size >= base_bytes + acc * 2;

    if (big) {
        WTab tab;
        int tiles = 0;
        for (int i = 0; i < NW; ++i) {
            tab.src[i] = wsrc[i];
            tab.off[i] = (unsigned)woff[i];
            tab.Kd[i] = wK[i] / 64;
            tab.Nd[i] = wN[i] / 64;
            tab.cum[i] = tiles;
            tiles += (wK[i] / 64) * (wN[i] / 64);
        }
        tab.cum[NW] = tiles;
        tcast_all_k<<<tiles, 256, 0, stream>>>(tab, warena);
    }

    add_pe2_k<<<2 * NTOK / 4 / 256, 256, 0, stream>>>(src_seq, trg_seq, x, xbf, y, ybf);

    auto do_mha = [&](float* statef, ushort* statebf, const ushort* kvbf, int widx,
                      const float* g, const float* bb, const int* pad) {
        const ushort* bt;
        if (big) {
            bt = warena + woff[widx];
        } else {
            tcast_k<<<dim3(8, 8, 4), 256, 0, stream>>>(
                wsrc[widx], wsrc[widx + 1], wsrc[widx + 2], wsrc[widx + 3],
                warena, 512, 512);
            bt = warena;
        }
        if (kvbf == statebf) {
            // packed QKV: 128x128 tiles, nbx = 1536/128 = 12, grid 384
            gemm3_k<false, false, false, true><<<32 * 12, 256, 0, stream>>>(
                statebf, bt, nullptr, nullptr, qkvb, M, 1536, 512, 12);
        } else {
            // cross-attn: Q (512 cols) 128x64; K/V (1024 cols) 128x128
            gemm2_k<false, false, false, true><<<32 * 8, 256, 0, stream>>>(
                statebf, bt + 0 * WSZ, nullptr, nullptr, qkvb, M, 1536, 512, 8);
            gemm3_k<false, false, false, true><<<32 * 8, 256, 0, stream>>>(
                kvbf, bt + 1 * WSZ, nullptr, nullptr, qkvb + DD, M, 1536, 512, 8);
        }
        attn_k<<<dim3(SS / 64, HH, BB), 256, 0, stream>>>(qkvb, ob, pad);
        gemm2_k<false, true, false, false><<<32 * 8, 256, 0, stream>>>(
            ob, bt + 3 * WSZ, nullptr, statef, t0, M, 512, 512, 8);
        ln_k<<<M, 256, 0, stream>>>(t0, g, bb, statef, statebf);
    };
    auto do_ffn = [&](float* statef, ushort* statebf, int widx,
                      const float* b1, const float* b2,
                      const float* g, const float* bb, float* lnoutf) {
        const ushort* bt1;
        const ushort* bt2;
        if (big) {
            bt1 = warena + woff[widx];
            bt2 = warena + woff[widx + 1];
        } else {
            tcast_k<<<dim3(32, 8, 1), 256, 0, stream>>>(
                wsrc[widx], wsrc[widx], wsrc[widx], wsrc[widx], warena, 512, DFFv);
            bt1 = warena;
            bt2 = warena;
        }
        // FFN1: N=2048, 128x128 tiles, nbx=16, grid 512
        gemm3_k<true, false, true, true><<<32 * 16, 256, 0, stream>>>(
            statebf, bt1, b1, nullptr, hbf, M, DFFv, 512, 16);
        if (!big) {
            tcast_k<<<dim3(8, 32, 1), 256, 0, stream>>>(
                wsrc[widx + 1], wsrc[widx + 1], wsrc[widx + 1], wsrc[widx + 1],
                warena, DFFv, 512);
        }
        gemm2_k<true, true, false, false><<<32 * 8, 256, 0, stream>>>(
            hbf, bt2, b2, statef, t0, M, 512, DFFv, 8);
        ln_k<<<M, 256, 0, stream>>>(t0, g, bb, lnoutf, statebf);
    };

    for (int l = 0; l < LL; ++l) {
        do_mha(x, xbf, xbf, l * 6, e_g1 + l * DD, e_b1 + l * DD, enc_pad);
        do_ffn(x, xbf, l * 6 + 4, e_bb1 + l * DFFv, e_bb2 + l * DD,
               e_g2 + l * DD, e_b2 + l * DD, x);
    }
    for (int l = 0; l < LL; ++l) {
        do_mha(y, ybf, ybf, 12 + l * 10, d_g1 + l * DD, d_b1 + l * DD, dec_pad);
        do_mha(y, ybf, xbf, 12 + l * 10 + 4, d_g2 + l * DD, d_b2 + l * DD, enc_pad);
        const bool last = (l == LL - 1);
        do_ffn(y, ybf, 12 + l * 10 + 8, d_bb1 + l * DFFv, d_bb2 + l * DD,
               d_g3 + l * DD, d_b3 + l * DD, last ? (float*)d_out : y);
    }
}

// Round 10
// 593.740 us; speedup vs baseline: 1.1541x; 1.0584x over previous
//
#include <hip/hip_runtime.h>
#include <hip/hip_bf16.h>

// Problem constants
#define BB 8
#define SS 512
#define DD 512
#define HH 8
#define DQKv 64
#define DFFv 2048
#define LL 2

typedef __attribute__((ext_vector_type(8))) __bf16 bf16x8;
typedef __attribute__((ext_vector_type(4))) float f32x4;

// fp32 -> bf16 (RNE), bf16 -> fp32 helpers on raw ushort bits
static __device__ __forceinline__ ushort f2b(float x) {
    unsigned int u = __float_as_uint(x);
    unsigned int r = (u + 0x7FFFu + ((u >> 16) & 1u)) >> 16;
    return (ushort)r;
}
static __device__ __forceinline__ float b2f(ushort u) {
    return __uint_as_float(((unsigned int)u) << 16);
}

typedef __attribute__((address_space(1))) const unsigned int gas_u32;
typedef __attribute__((address_space(3))) unsigned int las_u32;
static __device__ __forceinline__ void gload16(const void* g, void* l) {
    __builtin_amdgcn_global_load_lds((gas_u32*)g, (las_u32*)l, 16, 0, 0);
}

// ---------------------------------------------------------------------------
// x = in + PE (PE trig computed inline); src->x and trg->y in one grid.
// ---------------------------------------------------------------------------
__global__ __launch_bounds__(256) void add_pe2_k(const float* __restrict__ src,
                                                 const float* __restrict__ trg,
                                                 float* __restrict__ xf,
                                                 ushort* __restrict__ xb,
                                                 float* __restrict__ yf,
                                                 ushort* __restrict__ yb) {
    const int NQ = BB * SS * DD / 4;
    int i = blockIdx.x * 256 + threadIdx.x;       // 0 .. 2*NQ-1
    const bool second = i >= NQ;
    const int ii = second ? i - NQ : i;
    const int rem = ii & (SS * DD / 4 - 1);
    const int d4 = rem & (DD / 4 - 1);            // 0..127
    const int s = rem >> 7;

    float4 a = ((const float4*)(second ? trg : src))[ii];
    const float c = -9.210340371976184f / 512.0f; // -ln(1e4)/D
    const float div0 = __expf((float)(4 * d4) * c);
    const float div1 = __expf((float)(4 * d4 + 2) * c);
    const float a0 = (float)s * div0, a1 = (float)s * div1;
    a.x += sinf(a0); a.y += cosf(a0);
    a.z += sinf(a1); a.w += cosf(a1);

    float* of = second ? yf : xf;
    ushort* ob = second ? yb : xb;
    ((float4*)of)[ii] = a;
    ushort4 ub;
    ub.x = f2b(a.x); ub.y = f2b(a.y); ub.z = f2b(a.z); ub.w = f2b(a.w);
    ((ushort4*)ob)[ii] = ub;
}

// ---------------------------------------------------------------------------
// Per-op weight transpose+cast (fallback when ws is small)
// ---------------------------------------------------------------------------
__global__ __launch_bounds__(256) void tcast_k(const float* __restrict__ s0,
                                               const float* __restrict__ s1,
                                               const float* __restrict__ s2,
                                               const float* __restrict__ s3,
                                               ushort* __restrict__ dst,
                                               int K, int N) {
    __shared__ ushort st[64][72];
    const float* src = (blockIdx.z == 0) ? s0 : (blockIdx.z == 1) ? s1
                     : (blockIdx.z == 2) ? s2 : s3;
    ushort* d = dst + (size_t)blockIdx.z * K * N;
    const int k0 = blockIdx.y * 64, n0 = blockIdx.x * 64;
    const int t = threadIdx.x;
    const int r = t >> 2, c4 = (t & 3) * 16;
#pragma unroll
    for (int i = 0; i < 16; i += 4) {
        float4 v = *(const float4*)&src[(size_t)(k0 + r) * N + n0 + c4 + i];
        st[c4 + i + 0][r] = f2b(v.x);
        st[c4 + i + 1][r] = f2b(v.y);
        st[c4 + i + 2][r] = f2b(v.z);
        st[c4 + i + 3][r] = f2b(v.w);
    }
    __syncthreads();
    const int n = t >> 2, seg = (t & 3) * 16;
    *(uint4*)&d[(size_t)(n0 + n) * K + k0 + seg]     = *(const uint4*)&st[n][seg];
    *(uint4*)&d[(size_t)(n0 + n) * K + k0 + seg + 8] = *(const uint4*)&st[n][seg + 8];
}

// ---------------------------------------------------------------------------
// All-weights transpose+cast in ONE launch.
// ---------------------------------------------------------------------------
#define NW 32
struct WTab {
    const float* src[NW];
    unsigned off[NW];   // dst offset in ushort elems
    int Kd[NW];         // K/64
    int Nd[NW];         // N/64
    int cum[NW + 1];    // tile prefix sums
};

__global__ __launch_bounds__(256) void tcast_all_k(WTab tab, ushort* __restrict__ dst) {
    __shared__ ushort st[64][72];
    const int t = blockIdx.x;
    int m = 0;
    while (t >= tab.cum[m + 1]) ++m;
    const int local = t - tab.cum[m];
    const int ntx = tab.Nd[m];
    const int bx = local % ntx, by = local / ntx;
    const float* src = tab.src[m];
    ushort* d = dst + tab.off[m];
    const int N = ntx * 64, K = tab.Kd[m] * 64;
    const int k0 = by * 64, n0 = bx * 64;

    const int tt = threadIdx.x;
    const int r = tt >> 2, c4 = (tt & 3) * 16;
#pragma unroll
    for (int i = 0; i < 16; i += 4) {
        float4 v = *(const float4*)&src[(size_t)(k0 + r) * N + n0 + c4 + i];
        st[c4 + i + 0][r] = f2b(v.x);
        st[c4 + i + 1][r] = f2b(v.y);
        st[c4 + i + 2][r] = f2b(v.z);
        st[c4 + i + 3][r] = f2b(v.w);
    }
    __syncthreads();
    const int n = tt >> 2, seg = (tt & 3) * 16;
    *(uint4*)&d[(size_t)(n0 + n) * K + k0 + seg]     = *(const uint4*)&st[n][seg];
    *(uint4*)&d[(size_t)(n0 + n) * K + k0 + seg + 8] = *(const uint4*)&st[n][seg + 8];
}

// ---------------------------------------------------------------------------
// bf16 MFMA GEMM, BM=64 BN=64 BK=64, 2-phase dbuf + chunk-XOR swizzle.
// 4 waves (2x2), wave = 32x32 via 2x2 16x16x32 frags. Grid = (M/64)*(N/64):
// N=512 shapes -> 512 blocks = 2 blocks/CU (TLP hides barrier drains).
// ---------------------------------------------------------------------------
template <bool BIAS, bool RES, bool RELU, bool OUTBF>
__global__ __launch_bounds__(256) void gemm2_k(const ushort* __restrict__ A,
                                               const ushort* __restrict__ Bt,
                                               const float* __restrict__ bias,
                                               const float* __restrict__ res,
                                               void* __restrict__ Cout,
                                               int M, int N, int K, int nbx) {
    __shared__ ushort sA[2][64 * 64];
    __shared__ ushort sB[2][64 * 64];

    const int tid = threadIdx.x;
    const int nwg = gridDim.x;
    const int wg = blockIdx.x;
    const int swz = (wg & 7) * (nwg >> 3) + (wg >> 3);   // XCD-contiguous chunks
    const int bx = swz % nbx, by = swz / nbx;

    const int lane = tid & 63, w = tid >> 6;
    const int wm = w >> 1, wn = w & 1;
    const int llo = lane & 15, lhi = lane >> 4;

    const int srow = tid >> 3;           // 0..31 (rows step by 32 == 0 mod 8)
    const int scol = (((tid & 7) ^ (srow & 7)) * 8);  // pre-swizzled global chunk
    const ushort* Ab = A + (size_t)(by * 64 + srow) * K + scol;
    const ushort* Bb = Bt + (size_t)(bx * 64 + srow) * K + scol;
    const int sOff = srow * 128 + (tid & 7) * 16;     // linear LDS dest (bytes)

    f32x4 acc[2][2] = {};
    const int nt = K >> 6;

    // prologue: stage tile 0 into buf 0 (2 A + 2 B gloads)
#pragma unroll
    for (int i = 0; i < 2; ++i) {
        gload16(Ab + (size_t)i * 32 * K, (char*)sA[0] + sOff + i * 32 * 128);
        gload16(Bb + (size_t)i * 32 * K, (char*)sB[0] + sOff + i * 32 * 128);
    }
    __syncthreads();

    int cur = 0;
    for (int t = 0; t < nt; ++t) {
        if (t + 1 < nt) {
            const int k0 = (t + 1) << 6;
#pragma unroll
            for (int i = 0; i < 2; ++i) {
                gload16(Ab + (size_t)i * 32 * K + k0, (char*)sA[cur ^ 1] + sOff + i * 32 * 128);
                gload16(Bb + (size_t)i * 32 * K + k0, (char*)sB[cur ^ 1] + sOff + i * 32 * 128);
            }
        }
        const int sw = llo & 7;   // row&7 for this lane's frag rows
#pragma unroll
        for (int ks = 0; ks < 2; ++ks) {
            const int pc = ((ks * 4 + lhi) ^ sw) * 8;   // physical chunk
            bf16x8 af[2];
#pragma unroll
            for (int fa = 0; fa < 2; ++fa)
                af[fa] = *(const bf16x8*)&sA[cur][(wm * 32 + fa * 16 + llo) * 64 + pc];
            bf16x8 bfrag[2];
#pragma unroll
            for (int fb = 0; fb < 2; ++fb)
                bfrag[fb] = *(const bf16x8*)&sB[cur][(wn * 32 + fb * 16 + llo) * 64 + pc];
#pragma unroll
            for (int fa = 0; fa < 2; ++fa)
#pragma unroll
                for (int fb = 0; fb < 2; ++fb)
                    acc[fa][fb] = __builtin_amdgcn_mfma_f32_16x16x32_bf16(
                        af[fa], bfrag[fb], acc[fa][fb], 0, 0, 0);
        }
        __syncthreads();   // prefetch done (vmcnt) + all reads of buf[cur] done
        cur ^= 1;
    }

#pragma unroll
    for (int fa = 0; fa < 2; ++fa) {
#pragma unroll
        for (int fb = 0; fb < 2; ++fb) {
            const int col = bx * 64 + wn * 32 + fb * 16 + llo;
            const float bv = BIAS ? bias[col] : 0.f;
#pragma unroll
            for (int j = 0; j < 4; ++j) {
                const int row = by * 64 + wm * 32 + fa * 16 + lhi * 4 + j;
                float v = acc[fa][fb][j] + bv;
                if (RES) v += res[(size_t)row * N + col];
                if (RELU) v = fmaxf(v, 0.f);
                if (OUTBF) ((ushort*)Cout)[(size_t)row * N + col] = f2b(v);
                else       ((float*)Cout)[(size_t)row * N + col] = v;
            }
        }
    }
}

// ---------------------------------------------------------------------------
// bf16 MFMA GEMM, BM=64 BN=128 BK=64, same pipeline + swizzle. 4 waves,
// wave = 32x64 via 2x4 frags. QKV grid 768 = 3/CU, FFN1 grid 1024 = 4/CU.
// ---------------------------------------------------------------------------
template <bool BIAS, bool RES, bool RELU, bool OUTBF>
__global__ __launch_bounds__(256) void gemm3_k(const ushort* __restrict__ A,
                                               const ushort* __restrict__ Bt,
                                               const float* __restrict__ bias,
                                               const float* __restrict__ res,
                                               void* __restrict__ Cout,
                                               int M, int N, int K, int nbx) {
    __shared__ ushort sA[2][64 * 64];
    __shared__ ushort sB[2][128 * 64];

    const int tid = threadIdx.x;
    const int nwg = gridDim.x;
    const int wg = blockIdx.x;
    const int swz = (wg & 7) * (nwg >> 3) + (wg >> 3);
    const int bx = swz % nbx, by = swz / nbx;

    const int lane = tid & 63, w = tid >> 6;
    const int wm = w >> 1, wn = w & 1;
    const int llo = lane & 15, lhi = lane >> 4;

    const int srow = tid >> 3;           // 0..31
    const int scol = (((tid & 7) ^ (srow & 7)) * 8);
    const ushort* Ab = A + (size_t)(by * 64 + srow) * K + scol;
    const ushort* Bb = Bt + (size_t)(bx * 128 + srow) * K + scol;
    const int sOff = srow * 128 + (tid & 7) * 16;

    f32x4 acc[2][4] = {};
    const int nt = K >> 6;

#pragma unroll
    for (int i = 0; i < 2; ++i)
        gload16(Ab + (size_t)i * 32 * K, (char*)sA[0] + sOff + i * 32 * 128);
#pragma unroll
    for (int i = 0; i < 4; ++i)
        gload16(Bb + (size_t)i * 32 * K, (char*)sB[0] + sOff + i * 32 * 128);
    __syncthreads();

    int cur = 0;
    for (int t = 0; t < nt; ++t) {
        if (t + 1 < nt) {
            const int k0 = (t + 1) << 6;
#pragma unroll
            for (int i = 0; i < 2; ++i)
                gload16(Ab + (size_t)i * 32 * K + k0, (char*)sA[cur ^ 1] + sOff + i * 32 * 128);
#pragma unroll
            for (int i = 0; i < 4; ++i)
                gload16(Bb + (size_t)i * 32 * K + k0, (char*)sB[cur ^ 1] + sOff + i * 32 * 128);
        }
        const int sw = llo & 7;
#pragma unroll
        for (int ks = 0; ks < 2; ++ks) {
            const int pc = ((ks * 4 + lhi) ^ sw) * 8;
            bf16x8 af[2];
#pragma unroll
            for (int fa = 0; fa < 2; ++fa)
                af[fa] = *(const bf16x8*)&sA[cur][(wm * 32 + fa * 16 + llo) * 64 + pc];
            bf16x8 bfrag[4];
#pragma unroll
            for (int fb = 0; fb < 4; ++fb)
                bfrag[fb] = *(const bf16x8*)&sB[cur][(wn * 64 + fb * 16 + llo) * 64 + pc];
#pragma unroll
            for (int fa = 0; fa < 2; ++fa)
#pragma unroll
                for (int fb = 0; fb < 4; ++fb)
                    acc[fa][fb] = __builtin_amdgcn_mfma_f32_16x16x32_bf16(
                        af[fa], bfrag[fb], acc[fa][fb], 0, 0, 0);
        }
        __syncthreads();
        cur ^= 1;
    }

#pragma unroll
    for (int fa = 0; fa < 2; ++fa) {
#pragma unroll
        for (int fb = 0; fb < 4; ++fb) {
            const int col = bx * 128 + wn * 64 + fb * 16 + llo;
            const float bv = BIAS ? bias[col] : 0.f;
#pragma unroll
            for (int j = 0; j < 4; ++j) {
                const int row = by * 64 + wm * 32 + fa * 16 + lhi * 4 + j;
                float v = acc[fa][fb][j] + bv;
                if (RES) v += res[(size_t)row * N + col];
                if (RELU) v = fmaxf(v, 0.f);
                if (OUTBF) ((ushort*)Cout)[(size_t)row * N + col] = f2b(v);
                else       ((float*)Cout)[(size_t)row * N + col] = v;
            }
        }
    }
}

// ---------------------------------------------------------------------------
// MFMA flash attention on packed QKV [M][1536]. Semantics verified R2-R9.
// ---------------------------------------------------------------------------
__global__ __launch_bounds__(256) void attn_k(const ushort* __restrict__ QKV,
                                              ushort* __restrict__ O,
                                              const int* __restrict__ pad) {
    __shared__ ushort sQ[64][72];
    __shared__ ushort sK[64][72];
    __shared__ ushort sVt[64][72];   // V transposed: [d][key]
    __shared__ ushort sP[64][72];    // P: [q][key-local]

    const int tid = threadIdx.x;
    const int b = blockIdx.z, h = blockIdx.y, q0 = blockIdx.x << 6;
    const int klim = SS - pad[b];
    const int lane = tid & 63, w = tid >> 6;
    const int qw0 = w << 4;
    const int lhi = lane >> 4, llo = lane & 15;
    const int ST = 3 * DD;           // 1536 row stride

    {
        const int r = tid >> 2, seg = (tid & 3) << 4;
        const ushort* src = &QKV[(size_t)(b * SS + q0 + r) * ST + h * DQKv + seg];
        *(uint4*)&sQ[r][seg]     = *(const uint4*)src;
        *(uint4*)&sQ[r][seg + 8] = *(const uint4*)(src + 8);
    }

    auto window = [&](int i, int& wlo, int& whi) {
        if (h < 6) {
            const int step = 4 << (h >> 1);
            const int s2 = step >> 1;
            const int a1 = (i < s2) ? i : s2;
            const int a2 = ((SS - 1 - i) < s2) ? (SS - 1 - i) : s2;
            const int left = (i < SS / 2) ? a1 : (step - a2);
            wlo = i - left;
            whi = wlo + step;
        } else {
            wlo = 0;
            whi = SS - 1;
        }
    };

    int lo[4], hi[4];
#pragma unroll
    for (int j = 0; j < 4; ++j) window(q0 + qw0 + lhi * 4 + j, lo[j], hi[j]);

    int kt0 = 0, kt1 = SS;
    if (h < 6) {
        int lo0, hi0, lo63, hi63;
        window(q0, lo0, hi0);
        window(q0 + 63, lo63, hi63);
        if (lo63 >= klim) {
            kt0 = 0; kt1 = SS;
        } else {
            kt0 = (lo0 >> 6) << 6;
            kt1 = ((hi63 >> 6) + 1) << 6;
            if (kt1 > SS) kt1 = SS;
        }
    }

    float mr[4] = {-1e30f, -1e30f, -1e30f, -1e30f};
    float lr[4] = {0.f, 0.f, 0.f, 0.f};
    f32x4 oacc[4] = {};

    for (int kt = kt0; kt < kt1; kt += 64) {
        __syncthreads();
        {
            const int r = tid >> 2, seg = (tid & 3) << 4;
            const ushort* ksrc = &QKV[(size_t)(b * SS + kt + r) * ST + DD + h * DQKv + seg];
            *(uint4*)&sK[r][seg]     = *(const uint4*)ksrc;
            *(uint4*)&sK[r][seg + 8] = *(const uint4*)(ksrc + 8);
            const ushort* vsrc = &QKV[(size_t)(b * SS + kt + r) * ST + 2 * DD + h * DQKv + seg];
            uint4 u0 = *(const uint4*)vsrc;
            uint4 u1 = *(const uint4*)(vsrc + 8);
            const ushort* v0 = (const ushort*)&u0;
            const ushort* v1 = (const ushort*)&u1;
#pragma unroll
            for (int i = 0; i < 8; ++i) sVt[seg + i][r] = v0[i];
#pragma unroll
            for (int i = 0; i < 8; ++i) sVt[seg + 8 + i][r] = v1[i];
        }
        __syncthreads();

        // ---- QK^T ----
        f32x4 sacc[4] = {};
#pragma unroll
        for (int ks = 0; ks < 2; ++ks) {
            bf16x8 aq = *(const bf16x8*)&sQ[qw0 + llo][ks * 32 + lhi * 8];
#pragma unroll
            for (int n = 0; n < 4; ++n) {
                bf16x8 bk = *(const bf16x8*)&sK[n * 16 + llo][ks * 32 + lhi * 8];
                sacc[n] = __builtin_amdgcn_mfma_f32_16x16x32_bf16(aq, bk, sacc[n], 0, 0, 0);
            }
        }

        // ---- mask + scale + online softmax ----
#pragma unroll
        for (int j = 0; j < 4; ++j) {
            float s[4];
#pragma unroll
            for (int n = 0; n < 4; ++n) {
                const int kidx = kt + n * 16 + llo;
                const bool ok = (kidx < klim) && (kidx >= lo[j]) && (kidx <= hi[j]);
                s[n] = ok ? (sacc[n][j] * 0.125f) : -1e9f;
            }
            float tm = fmaxf(fmaxf(s[0], s[1]), fmaxf(s[2], s[3]));
#pragma unroll
            for (int off = 8; off; off >>= 1) tm = fmaxf(tm, __shfl_xor(tm, off));
            const float mn = fmaxf(mr[j], tm);
            const float alpha = __expf(mr[j] - mn);
            mr[j] = mn;
            float ps = 0.f;
            const int prow = qw0 + lhi * 4 + j;
#pragma unroll
            for (int n = 0; n < 4; ++n) {
                const ushort pb = f2b(__expf(s[n] - mn));
                sP[prow][n * 16 + llo] = pb;
                ps += b2f(pb);
            }
#pragma unroll
            for (int off = 8; off; off >>= 1) ps += __shfl_xor(ps, off);
            lr[j] = lr[j] * alpha + ps;
            oacc[0][j] *= alpha; oacc[1][j] *= alpha;
            oacc[2][j] *= alpha; oacc[3][j] *= alpha;
        }

        // ---- PV ----
#pragma unroll
        for (int ks = 0; ks < 2; ++ks) {
            bf16x8 ap = *(const bf16x8*)&sP[qw0 + llo][ks * 32 + lhi * 8];
#pragma unroll
            for (int n = 0; n < 4; ++n) {
                bf16x8 bv = *(const bf16x8*)&sVt[n * 16 + llo][ks * 32 + lhi * 8];
                oacc[n] = __builtin_amdgcn_mfma_f32_16x16x32_bf16(ap, bv, oacc[n], 0, 0, 0);
            }
        }
    }

#pragma unroll
    for (int j = 0; j < 4; ++j) {
        const float inv = 1.f / lr[j];
        const int q = q0 + qw0 + lhi * 4 + j;
#pragma unroll
        for (int n = 0; n < 4; ++n) {
            O[(size_t)(b * SS + q) * (HH * DQKv) + h * DQKv + n * 16 + llo] =
                f2b(oacc[n][j] * inv);
        }
    }
}

// ---------------------------------------------------------------------------
// LayerNorm over rows of 512; writes fp32 state + bf16 state copy
// ---------------------------------------------------------------------------
__global__ __launch_bounds__(256) void ln_k(const float* __restrict__ in,
                                            const float* __restrict__ g,
                                            const float* __restrict__ bvec,
                                            float* __restrict__ outf,
                                            ushort* __restrict__ outb) {
    const int row = blockIdx.x;
    const int tid = threadIdx.x;
    const float2 xv = *(const float2*)&in[(size_t)row * DD + tid * 2];

    __shared__ float red[4];
    __shared__ float red2[4];
    const int wid = tid >> 6, lane = tid & 63;

    float s = xv.x + xv.y;
#pragma unroll
    for (int off = 32; off; off >>= 1) s += __shfl_xor(s, off);
    if (lane == 0) red[wid] = s;
    __syncthreads();
    const float mu = (red[0] + red[1] + red[2] + red[3]) * (1.f / 512.f);

    const float dx = xv.x - mu, dy = xv.y - mu;
    float q = dx * dx + dy * dy;
#pragma unroll
    for (int off = 32; off; off >>= 1) q += __shfl_xor(q, off);
    if (lane == 0) red2[wid] = q;
    __syncthreads();
    const float var = (red2[0] + red2[1] + red2[2] + red2[3]) * (1.f / 512.f);
    const float rs = rsqrtf(var + 1e-6f);

    float2 o;
    o.x = dx * rs * g[tid * 2] + bvec[tid * 2];
    o.y = dy * rs * g[tid * 2 + 1] + bvec[tid * 2 + 1];
    *(float2*)&outf[(size_t)row * DD + tid * 2] = o;
    ushort2 ub; ub.x = f2b(o.x); ub.y = f2b(o.y);
    *(ushort2*)&outb[(size_t)row * DD + tid * 2] = ub;
}

// ---------------------------------------------------------------------------
// Host orchestration
// ---------------------------------------------------------------------------
extern "C" void kernel_launch(void* const* d_in, const int* in_sizes, int n_in,
                              void* d_out, int out_size, void* d_ws, size_t ws_size,
                              hipStream_t stream) {
    const float* src_seq = (const float*)d_in[0];
    const float* trg_seq = (const float*)d_in[1];
    const int* enc_pad = (const int*)d_in[2];
    const int* dec_pad = (const int*)d_in[3];
    const float* e_wq = (const float*)d_in[4];
    const float* e_wk = (const float*)d_in[5];
    const float* e_wv = (const float*)d_in[6];
    const float* e_wo = (const float*)d_in[7];
    const float* e_g1 = (const float*)d_in[8];
    const float* e_b1 = (const float*)d_in[9];
    const float* e_w1 = (const float*)d_in[10];
    const float* e_bb1 = (const float*)d_in[11];
    const float* e_w2 = (const float*)d_in[12];
    const float* e_bb2 = (const float*)d_in[13];
    const float* e_g2 = (const float*)d_in[14];
    const float* e_b2 = (const float*)d_in[15];
    const float* d_swq = (const float*)d_in[16];
    const float* d_swk = (const float*)d_in[17];
    const float* d_swv = (const float*)d_in[18];
    const float* d_swo = (const float*)d_in[19];
    const float* d_g1 = (const float*)d_in[20];
    const float* d_b1 = (const float*)d_in[21];
    const float* d_cwq = (const float*)d_in[22];
    const float* d_cwk = (const float*)d_in[23];
    const float* d_cwv = (const float*)d_in[24];
    const float* d_cwo = (const float*)d_in[25];
    const float* d_g2 = (const float*)d_in[26];
    const float* d_b2 = (const float*)d_in[27];
    const float* d_w1 = (const float*)d_in[28];
    const float* d_bb1 = (const float*)d_in[29];
    const float* d_w2 = (const float*)d_in[30];
    const float* d_bb2 = (const float*)d_in[31];
    const float* d_g3 = (const float*)d_in[32];
    const float* d_b3 = (const float*)d_in[33];
    (void)in_sizes; (void)n_in; (void)out_size;

    const int M = BB * SS;          // 4096
    const int NTOK = BB * SS * DD;  // 2097152
    const size_t WSZ = (size_t)DD * 512;  // 262144 elems (one 512x512 weight)

    float* ws = (float*)d_ws;
    float* x  = ws;
    float* y  = x + NTOK;
    float* t0 = y + NTOK;
    ushort* xbf  = (ushort*)(t0 + NTOK);
    ushort* ybf  = xbf + NTOK;
    ushort* qkvb = ybf + NTOK;              // M x 1536 packed QKV
    ushort* ob   = qkvb + (size_t)M * 1536;
    ushort* hbf  = qkvb;                    // FFN hidden 4096x2048 aliases qkvb+ob
    ushort* warena = ob + NTOK;

    // ---- weight table ----
    const float* wsrc[NW]; int wK[NW], wN[NW]; size_t woff[NW];
    int wcnt = 0; size_t acc = 0;
    auto push = [&](const float* p, int K, int N) {
        wsrc[wcnt] = p; wK[wcnt] = K; wN[wcnt] = N; woff[wcnt] = acc;
        acc += (size_t)K * N; ++wcnt;
    };
    for (int l = 0; l < LL; ++l) {
        push(e_wq + (size_t)l * WSZ, 512, 512);
        push(e_wk + (size_t)l * WSZ, 512, 512);
        push(e_wv + (size_t)l * WSZ, 512, 512);
        push(e_wo + (size_t)l * WSZ, 512, 512);
        push(e_w1 + (size_t)l * DD * DFFv, 512, DFFv);
        push(e_w2 + (size_t)l * DFFv * DD, DFFv, 512);
    }
    for (int l = 0; l < LL; ++l) {
        push(d_swq + (size_t)l * WSZ, 512, 512);
        push(d_swk + (size_t)l * WSZ, 512, 512);
        push(d_swv + (size_t)l * WSZ, 512, 512);
        push(d_swo + (size_t)l * WSZ, 512, 512);
        push(d_cwq + (size_t)l * WSZ, 512, 512);
        push(d_cwk + (size_t)l * WSZ, 512, 512);
        push(d_cwv + (size_t)l * WSZ, 512, 512);
        push(d_cwo + (size_t)l * WSZ, 512, 512);
        push(d_w1 + (size_t)l * DD * DFFv, 512, DFFv);
        push(d_w2 + (size_t)l * DFFv * DD, DFFv, 512);
    }

    const size_t base_bytes = (size_t)(warena - (ushort*)d_ws) * 2;
    const bool big = ws_size >= base_bytes + acc * 2;

    if (big) {
        WTab tab;
        int tiles = 0;
        for (int i = 0; i < NW; ++i) {
            tab.src[i] = wsrc[i];
            tab.off[i] = (unsigned)woff[i];
            tab.Kd[i] = wK[i] / 64;
            tab.Nd[i] = wN[i] / 64;
            tab.cum[i] = tiles;
            tiles += (wK[i] / 64) * (wN[i] / 64);
        }
        tab.cum[NW] = tiles;
        tcast_all_k<<<tiles, 256, 0, stream>>>(tab, warena);
    }

    add_pe2_k<<<2 * NTOK / 4 / 256, 256, 0, stream>>>(src_seq, trg_seq, x, xbf, y, ybf);

    auto do_mha = [&](float* statef, ushort* statebf, const ushort* kvbf, int widx,
                      const float* g, const float* bb, const int* pad) {
        const ushort* bt;
        if (big) {
            bt = warena + woff[widx];
        } else {
            tcast_k<<<dim3(8, 8, 4), 256, 0, stream>>>(
                wsrc[widx], wsrc[widx + 1], wsrc[widx + 2], wsrc[widx + 3],
                warena, 512, 512);
            bt = warena;
        }
        if (kvbf == statebf) {
            // packed QKV: BM=64 x BN=128, nbx = 12, grid 768 = 3/CU
            gemm3_k<false, false, false, true><<<64 * 12, 256, 0, stream>>>(
                statebf, bt, nullptr, nullptr, qkvb, M, 1536, 512, 12);
        } else {
            // cross-attn: Q (512 cols) 64x64 grid 512; K/V (1024 cols) 64x128 grid 512
            gemm2_k<false, false, false, true><<<64 * 8, 256, 0, stream>>>(
                statebf, bt + 0 * WSZ, nullptr, nullptr, qkvb, M, 1536, 512, 8);
            gemm3_k<false, false, false, true><<<64 * 8, 256, 0, stream>>>(
                kvbf, bt + 1 * WSZ, nullptr, nullptr, qkvb + DD, M, 1536, 512, 8);
        }
        attn_k<<<dim3(SS / 64, HH, BB), 256, 0, stream>>>(qkvb, ob, pad);
        gemm2_k<false, true, false, false><<<64 * 8, 256, 0, stream>>>(
            ob, bt + 3 * WSZ, nullptr, statef, t0, M, 512, 512, 8);
        ln_k<<<M, 256, 0, stream>>>(t0, g, bb, statef, statebf);
    };
    auto do_ffn = [&](float* statef, ushort* statebf, int widx,
                      const float* b1, const float* b2,
                      const float* g, const float* bb, float* lnoutf) {
        const ushort* bt1;
        const ushort* bt2;
        if (big) {
            bt1 = warena + woff[widx];
            bt2 = warena + woff[widx + 1];
        } else {
            tcast_k<<<dim3(32, 8, 1), 256, 0, stream>>>(
                wsrc[widx], wsrc[widx], wsrc[widx], wsrc[widx], warena, 512, DFFv);
            bt1 = warena;
            bt2 = warena;
        }
        // FFN1: N=2048, 64x128 tiles, nbx=16, grid 1024 = 4/CU
        gemm3_k<true, false, true, true><<<64 * 16, 256, 0, stream>>>(
            statebf, bt1, b1, nullptr, hbf, M, DFFv, 512, 16);
        if (!big) {
            tcast_k<<<dim3(8, 32, 1), 256, 0, stream>>>(
                wsrc[widx + 1], wsrc[widx + 1], wsrc[widx + 1], wsrc[widx + 1],
                warena, DFFv, 512);
        }
        gemm2_k<true, true, false, false><<<64 * 8, 256, 0, stream>>>(
            hbf, bt2, b2, statef, t0, M, 512, DFFv, 8);
        ln_k<<<M, 256, 0, stream>>>(t0, g, bb, lnoutf, statebf);
    };

    for (int l = 0; l < LL; ++l) {
        do_mha(x, xbf, xbf, l * 6, e_g1 + l * DD, e_b1 + l * DD, enc_pad);
        do_ffn(x, xbf, l * 6 + 4, e_bb1 + l * DFFv, e_bb2 + l * DD,
               e_g2 + l * DD, e_b2 + l * DD, x);
    }
    for (int l = 0; l < LL; ++l) {
        do_mha(y, ybf, ybf, 12 + l * 10, d_g1 + l * DD, d_b1 + l * DD, dec_pad);
        do_mha(y, ybf, xbf, 12 + l * 10 + 4, d_g2 + l * DD, d_b2 + l * DD, enc_pad);
        const bool last = (l == LL - 1);
        do_ffn(y, ybf, 12 + l * 10 + 8, d_bb1 + l * DFFv, d_bb2 + l * DD,
               d_g3 + l * DD, d_b3 + l * DD, last ? (float*)d_out : y);
    }
}

// Round 11
// 588.186 us; speedup vs baseline: 1.1650x; 1.0094x over previous
//
#include <hip/hip_runtime.h>
#include <hip/hip_bf16.h>

// Problem constants
#define BB 8
#define SS 512
#define DD 512
#define HH 8
#define DQKv 64
#define DFFv 2048
#define LL 2

typedef __attribute__((ext_vector_type(8))) __bf16 bf16x8;
typedef __attribute__((ext_vector_type(4))) float f32x4;

// fp32 -> bf16 (RNE), bf16 -> fp32 helpers on raw ushort bits
static __device__ __forceinline__ ushort f2b(float x) {
    unsigned int u = __float_as_uint(x);
    unsigned int r = (u + 0x7FFFu + ((u >> 16) & 1u)) >> 16;
    return (ushort)r;
}
static __device__ __forceinline__ float b2f(ushort u) {
    return __uint_as_float(((unsigned int)u) << 16);
}

typedef __attribute__((address_space(1))) const unsigned int gas_u32;
typedef __attribute__((address_space(3))) unsigned int las_u32;
static __device__ __forceinline__ void gload16(const void* g, void* l) {
    __builtin_amdgcn_global_load_lds((gas_u32*)g, (las_u32*)l, 16, 0, 0);
}

#define VMCNT4 asm volatile("s_waitcnt vmcnt(4)" ::: "memory")
#define VMCNT6 asm volatile("s_waitcnt vmcnt(6)" ::: "memory")
#define VMCNT0 asm volatile("s_waitcnt vmcnt(0)" ::: "memory")
#define LGKM0  asm volatile("s_waitcnt lgkmcnt(0)" ::: "memory")
#define SCHEDB __builtin_amdgcn_sched_barrier(0)
#define SBAR   __builtin_amdgcn_s_barrier()

// ---------------------------------------------------------------------------
// x = in + PE (PE trig computed inline); src->x and trg->y in one grid.
// ---------------------------------------------------------------------------
__global__ __launch_bounds__(256) void add_pe2_k(const float* __restrict__ src,
                                                 const float* __restrict__ trg,
                                                 float* __restrict__ xf,
                                                 ushort* __restrict__ xb,
                                                 float* __restrict__ yf,
                                                 ushort* __restrict__ yb) {
    const int NQ = BB * SS * DD / 4;
    int i = blockIdx.x * 256 + threadIdx.x;       // 0 .. 2*NQ-1
    const bool second = i >= NQ;
    const int ii = second ? i - NQ : i;
    const int rem = ii & (SS * DD / 4 - 1);
    const int d4 = rem & (DD / 4 - 1);            // 0..127
    const int s = rem >> 7;

    float4 a = ((const float4*)(second ? trg : src))[ii];
    const float c = -9.210340371976184f / 512.0f; // -ln(1e4)/D
    const float div0 = __expf((float)(4 * d4) * c);
    const float div1 = __expf((float)(4 * d4 + 2) * c);
    const float a0 = (float)s * div0, a1 = (float)s * div1;
    a.x += sinf(a0); a.y += cosf(a0);
    a.z += sinf(a1); a.w += cosf(a1);

    float* of = second ? yf : xf;
    ushort* ob = second ? yb : xb;
    ((float4*)of)[ii] = a;
    ushort4 ub;
    ub.x = f2b(a.x); ub.y = f2b(a.y); ub.z = f2b(a.z); ub.w = f2b(a.w);
    ((ushort4*)ob)[ii] = ub;
}

// ---------------------------------------------------------------------------
// Per-op weight transpose+cast (fallback when ws is small)
// ---------------------------------------------------------------------------
__global__ __launch_bounds__(256) void tcast_k(const float* __restrict__ s0,
                                               const float* __restrict__ s1,
                                               const float* __restrict__ s2,
                                               const float* __restrict__ s3,
                                               ushort* __restrict__ dst,
                                               int K, int N) {
    __shared__ ushort st[64][72];
    const float* src = (blockIdx.z == 0) ? s0 : (blockIdx.z == 1) ? s1
                     : (blockIdx.z == 2) ? s2 : s3;
    ushort* d = dst + (size_t)blockIdx.z * K * N;
    const int k0 = blockIdx.y * 64, n0 = blockIdx.x * 64;
    const int t = threadIdx.x;
    const int r = t >> 2, c4 = (t & 3) * 16;
#pragma unroll
    for (int i = 0; i < 16; i += 4) {
        float4 v = *(const float4*)&src[(size_t)(k0 + r) * N + n0 + c4 + i];
        st[c4 + i + 0][r] = f2b(v.x);
        st[c4 + i + 1][r] = f2b(v.y);
        st[c4 + i + 2][r] = f2b(v.z);
        st[c4 + i + 3][r] = f2b(v.w);
    }
    __syncthreads();
    const int n = t >> 2, seg = (t & 3) * 16;
    *(uint4*)&d[(size_t)(n0 + n) * K + k0 + seg]     = *(const uint4*)&st[n][seg];
    *(uint4*)&d[(size_t)(n0 + n) * K + k0 + seg + 8] = *(const uint4*)&st[n][seg + 8];
}

// ---------------------------------------------------------------------------
// All-weights transpose+cast in ONE launch.
// ---------------------------------------------------------------------------
#define NW 32
struct WTab {
    const float* src[NW];
    unsigned off[NW];   // dst offset in ushort elems
    int Kd[NW];         // K/64
    int Nd[NW];         // N/64
    int cum[NW + 1];    // tile prefix sums
};

__global__ __launch_bounds__(256) void tcast_all_k(WTab tab, ushort* __restrict__ dst) {
    __shared__ ushort st[64][72];
    const int t = blockIdx.x;
    int m = 0;
    while (t >= tab.cum[m + 1]) ++m;
    const int local = t - tab.cum[m];
    const int ntx = tab.Nd[m];
    const int bx = local % ntx, by = local / ntx;
    const float* src = tab.src[m];
    ushort* d = dst + tab.off[m];
    const int N = ntx * 64, K = tab.Kd[m] * 64;
    const int k0 = by * 64, n0 = bx * 64;

    const int tt = threadIdx.x;
    const int r = tt >> 2, c4 = (tt & 3) * 16;
#pragma unroll
    for (int i = 0; i < 16; i += 4) {
        float4 v = *(const float4*)&src[(size_t)(k0 + r) * N + n0 + c4 + i];
        st[c4 + i + 0][r] = f2b(v.x);
        st[c4 + i + 1][r] = f2b(v.y);
        st[c4 + i + 2][r] = f2b(v.z);
        st[c4 + i + 3][r] = f2b(v.w);
    }
    __syncthreads();
    const int n = tt >> 2, seg = (tt & 3) * 16;
    *(uint4*)&d[(size_t)(n0 + n) * K + k0 + seg]     = *(const uint4*)&st[n][seg];
    *(uint4*)&d[(size_t)(n0 + n) * K + k0 + seg + 8] = *(const uint4*)&st[n][seg + 8];
}

// ---------------------------------------------------------------------------
// bf16 MFMA GEMM, BM=64 BN=64 BK=64. 3-buffer depth-2 prefetch with COUNTED
// vmcnt (T4): per K-step wait only the oldest tile's 4 loads (vmcnt(4)),
// lgkmcnt(0) + ONE raw s_barrier, then issue tile t+2 and compute tile t.
// Prefetch loads stay in flight across the barrier. XOR swizzle as R9/R10.
// ---------------------------------------------------------------------------
template <bool BIAS, bool RES, bool RELU, bool OUTBF>
__global__ __launch_bounds__(256) void gemm2_k(const ushort* __restrict__ A,
                                               const ushort* __restrict__ Bt,
                                               const float* __restrict__ bias,
                                               const float* __restrict__ res,
                                               void* __restrict__ Cout,
                                               int M, int N, int K, int nbx) {
    __shared__ ushort sA[3][64 * 64];
    __shared__ ushort sB[3][64 * 64];

    const int tid = threadIdx.x;
    const int nwg = gridDim.x;
    const int wg = blockIdx.x;
    const int swz = (wg & 7) * (nwg >> 3) + (wg >> 3);   // XCD-contiguous chunks
    const int bx = swz % nbx, by = swz / nbx;

    const int lane = tid & 63, w = tid >> 6;
    const int wm = w >> 1, wn = w & 1;
    const int llo = lane & 15, lhi = lane >> 4;

    const int srow = tid >> 3;           // 0..31 (rows step by 32 == 0 mod 8)
    const int scol = (((tid & 7) ^ (srow & 7)) * 8);  // pre-swizzled global chunk
    const ushort* Ab = A + (size_t)(by * 64 + srow) * K + scol;
    const ushort* Bb = Bt + (size_t)(bx * 64 + srow) * K + scol;
    const int sOff = srow * 128 + (tid & 7) * 16;     // linear LDS dest (bytes)

    f32x4 acc[2][2] = {};
    const int nt = K >> 6;

    // prologue: tiles 0 and 1 into bufs 0,1
#pragma unroll
    for (int i = 0; i < 2; ++i) {
        gload16(Ab + (size_t)i * 32 * K, (char*)sA[0] + sOff + i * 32 * 128);
        gload16(Bb + (size_t)i * 32 * K, (char*)sB[0] + sOff + i * 32 * 128);
    }
    if (nt > 1) {
#pragma unroll
        for (int i = 0; i < 2; ++i) {
            gload16(Ab + (size_t)i * 32 * K + 64, (char*)sA[1] + sOff + i * 32 * 128);
            gload16(Bb + (size_t)i * 32 * K + 64, (char*)sB[1] + sOff + i * 32 * 128);
        }
    }
    SCHEDB;

    for (int t = 0; t < nt; ++t) {
        if (t + 1 < nt) { VMCNT4; } else { VMCNT0; }  // oldest tile (t) done
        LGKM0;                                         // prev iter's ds_reads landed
        SCHEDB;
        SBAR;                                          // all waves: tile t staged
        SCHEDB;
        if (t + 2 < nt) {                              // overwrites buf (t-1)%3: safe
            const int k0 = (t + 2) << 6;
            char* dA = (char*)sA[(t + 2) % 3] + sOff;
            char* dB = (char*)sB[(t + 2) % 3] + sOff;
#pragma unroll
            for (int i = 0; i < 2; ++i) {
                gload16(Ab + (size_t)i * 32 * K + k0, dA + i * 32 * 128);
                gload16(Bb + (size_t)i * 32 * K + k0, dB + i * 32 * 128);
            }
        }
        SCHEDB;
        const ushort* cA = sA[t % 3];
        const ushort* cB = sB[t % 3];
        const int sw = llo & 7;
#pragma unroll
        for (int ks = 0; ks < 2; ++ks) {
            const int pc = ((ks * 4 + lhi) ^ sw) * 8;   // physical chunk
            bf16x8 af[2];
#pragma unroll
            for (int fa = 0; fa < 2; ++fa)
                af[fa] = *(const bf16x8*)&cA[(wm * 32 + fa * 16 + llo) * 64 + pc];
            bf16x8 bfrag[2];
#pragma unroll
            for (int fb = 0; fb < 2; ++fb)
                bfrag[fb] = *(const bf16x8*)&cB[(wn * 32 + fb * 16 + llo) * 64 + pc];
#pragma unroll
            for (int fa = 0; fa < 2; ++fa)
#pragma unroll
                for (int fb = 0; fb < 2; ++fb)
                    acc[fa][fb] = __builtin_amdgcn_mfma_f32_16x16x32_bf16(
                        af[fa], bfrag[fb], acc[fa][fb], 0, 0, 0);
        }
    }

#pragma unroll
    for (int fa = 0; fa < 2; ++fa) {
#pragma unroll
        for (int fb = 0; fb < 2; ++fb) {
            const int col = bx * 64 + wn * 32 + fb * 16 + llo;
            const float bv = BIAS ? bias[col] : 0.f;
#pragma unroll
            for (int j = 0; j < 4; ++j) {
                const int row = by * 64 + wm * 32 + fa * 16 + lhi * 4 + j;
                float v = acc[fa][fb][j] + bv;
                if (RES) v += res[(size_t)row * N + col];
                if (RELU) v = fmaxf(v, 0.f);
                if (OUTBF) ((ushort*)Cout)[(size_t)row * N + col] = f2b(v);
                else       ((float*)Cout)[(size_t)row * N + col] = v;
            }
        }
    }
}

// ---------------------------------------------------------------------------
// bf16 MFMA GEMM, BM=64 BN=128 BK=64. 2-buffer counted-vmcnt variant:
// issue t+1, wait vmcnt(6) (only tile t's loads), barrier, MFMA, lgkm+barrier.
// Keeps LDS at 48 KB (3 blocks/CU). XOR swizzle as R9/R10.
// ---------------------------------------------------------------------------
template <bool BIAS, bool RES, bool RELU, bool OUTBF>
__global__ __launch_bounds__(256) void gemm3_k(const ushort* __restrict__ A,
                                               const ushort* __restrict__ Bt,
                                               const float* __restrict__ bias,
                                               const float* __restrict__ res,
                                               void* __restrict__ Cout,
                                               int M, int N, int K, int nbx) {
    __shared__ ushort sA[2][64 * 64];
    __shared__ ushort sB[2][128 * 64];

    const int tid = threadIdx.x;
    const int nwg = gridDim.x;
    const int wg = blockIdx.x;
    const int swz = (wg & 7) * (nwg >> 3) + (wg >> 3);
    const int bx = swz % nbx, by = swz / nbx;

    const int lane = tid & 63, w = tid >> 6;
    const int wm = w >> 1, wn = w & 1;
    const int llo = lane & 15, lhi = lane >> 4;

    const int srow = tid >> 3;           // 0..31
    const int scol = (((tid & 7) ^ (srow & 7)) * 8);
    const ushort* Ab = A + (size_t)(by * 64 + srow) * K + scol;
    const ushort* Bb = Bt + (size_t)(bx * 128 + srow) * K + scol;
    const int sOff = srow * 128 + (tid & 7) * 16;

    f32x4 acc[2][4] = {};
    const int nt = K >> 6;

    // prologue: tile 0 -> buf 0
#pragma unroll
    for (int i = 0; i < 2; ++i)
        gload16(Ab + (size_t)i * 32 * K, (char*)sA[0] + sOff + i * 32 * 128);
#pragma unroll
    for (int i = 0; i < 4; ++i)
        gload16(Bb + (size_t)i * 32 * K, (char*)sB[0] + sOff + i * 32 * 128);
    SCHEDB;

    for (int t = 0; t < nt; ++t) {
        if (t + 1 < nt) {
            const int k0 = (t + 1) << 6;
            char* dA = (char*)sA[(t + 1) & 1] + sOff;   // last read iter t-1, released
            char* dB = (char*)sB[(t + 1) & 1] + sOff;
#pragma unroll
            for (int i = 0; i < 2; ++i)
                gload16(Ab + (size_t)i * 32 * K + k0, dA + i * 32 * 128);
#pragma unroll
            for (int i = 0; i < 4; ++i)
                gload16(Bb + (size_t)i * 32 * K + k0, dB + i * 32 * 128);
            SCHEDB;
            VMCNT6;                                     // tile t done; t+1 in flight
        } else {
            VMCNT0;
        }
        SCHEDB;
        SBAR;                                           // all waves: tile t staged
        SCHEDB;
        const ushort* cA = sA[t & 1];
        const ushort* cB = sB[t & 1];
        const int sw = llo & 7;
#pragma unroll
        for (int ks = 0; ks < 2; ++ks) {
            const int pc = ((ks * 4 + lhi) ^ sw) * 8;
            bf16x8 af[2];
#pragma unroll
            for (int fa = 0; fa < 2; ++fa)
                af[fa] = *(const bf16x8*)&cA[(wm * 32 + fa * 16 + llo) * 64 + pc];
            bf16x8 bfrag[4];
#pragma unroll
            for (int fb = 0; fb < 4; ++fb)
                bfrag[fb] = *(const bf16x8*)&cB[(wn * 64 + fb * 16 + llo) * 64 + pc];
#pragma unroll
            for (int fa = 0; fa < 2; ++fa)
#pragma unroll
                for (int fb = 0; fb < 4; ++fb)
                    acc[fa][fb] = __builtin_amdgcn_mfma_f32_16x16x32_bf16(
                        af[fa], bfrag[fb], acc[fa][fb], 0, 0, 0);
        }
        LGKM0;                                          // this iter's ds_reads landed
        SCHEDB;
        SBAR;                                           // release buf for overwrite
    }

#pragma unroll
    for (int fa = 0; fa < 2; ++fa) {
#pragma unroll
        for (int fb = 0; fb < 4; ++fb) {
            const int col = bx * 128 + wn * 64 + fb * 16 + llo;
            const float bv = BIAS ? bias[col] : 0.f;
#pragma unroll
            for (int j = 0; j < 4; ++j) {
                const int row = by * 64 + wm * 32 + fa * 16 + lhi * 4 + j;
                float v = acc[fa][fb][j] + bv;
                if (RES) v += res[(size_t)row * N + col];
                if (RELU) v = fmaxf(v, 0.f);
                if (OUTBF) ((ushort*)Cout)[(size_t)row * N + col] = f2b(v);
                else       ((float*)Cout)[(size_t)row * N + col] = v;
            }
        }
    }
}

// ---------------------------------------------------------------------------
// MFMA flash attention on packed QKV [M][1536]. Semantics verified R2-R10.
// ---------------------------------------------------------------------------
__global__ __launch_bounds__(256) void attn_k(const ushort* __restrict__ QKV,
                                              ushort* __restrict__ O,
                                              const int* __restrict__ pad) {
    __shared__ ushort sQ[64][72];
    __shared__ ushort sK[64][72];
    __shared__ ushort sVt[64][72];   // V transposed: [d][key]
    __shared__ ushort sP[64][72];    // P: [q][key-local]

    const int tid = threadIdx.x;
    const int b = blockIdx.z, h = blockIdx.y, q0 = blockIdx.x << 6;
    const int klim = SS - pad[b];
    const int lane = tid & 63, w = tid >> 6;
    const int qw0 = w << 4;
    const int lhi = lane >> 4, llo = lane & 15;
    const int ST = 3 * DD;           // 1536 row stride

    {
        const int r = tid >> 2, seg = (tid & 3) << 4;
        const ushort* src = &QKV[(size_t)(b * SS + q0 + r) * ST + h * DQKv + seg];
        *(uint4*)&sQ[r][seg]     = *(const uint4*)src;
        *(uint4*)&sQ[r][seg + 8] = *(const uint4*)(src + 8);
    }

    auto window = [&](int i, int& wlo, int& whi) {
        if (h < 6) {
            const int step = 4 << (h >> 1);
            const int s2 = step >> 1;
            const int a1 = (i < s2) ? i : s2;
            const int a2 = ((SS - 1 - i) < s2) ? (SS - 1 - i) : s2;
            const int left = (i < SS / 2) ? a1 : (step - a2);
            wlo = i - left;
            whi = wlo + step;
        } else {
            wlo = 0;
            whi = SS - 1;
        }
    };

    int lo[4], hi[4];
#pragma unroll
    for (int j = 0; j < 4; ++j) window(q0 + qw0 + lhi * 4 + j, lo[j], hi[j]);

    int kt0 = 0, kt1 = SS;
    if (h < 6) {
        int lo0, hi0, lo63, hi63;
        window(q0, lo0, hi0);
        window(q0 + 63, lo63, hi63);
        if (lo63 >= klim) {
            kt0 = 0; kt1 = SS;
        } else {
            kt0 = (lo0 >> 6) << 6;
            kt1 = ((hi63 >> 6) + 1) << 6;
            if (kt1 > SS) kt1 = SS;
        }
    }

    float mr[4] = {-1e30f, -1e30f, -1e30f, -1e30f};
    float lr[4] = {0.f, 0.f, 0.f, 0.f};
    f32x4 oacc[4] = {};

    for (int kt = kt0; kt < kt1; kt += 64) {
        __syncthreads();
        {
            const int r = tid >> 2, seg = (tid & 3) << 4;
            const ushort* ksrc = &QKV[(size_t)(b * SS + kt + r) * ST + DD + h * DQKv + seg];
            *(uint4*)&sK[r][seg]     = *(const uint4*)ksrc;
            *(uint4*)&sK[r][seg + 8] = *(const uint4*)(ksrc + 8);
            const ushort* vsrc = &QKV[(size_t)(b * SS + kt + r) * ST + 2 * DD + h * DQKv + seg];
            uint4 u0 = *(const uint4*)vsrc;
            uint4 u1 = *(const uint4*)(vsrc + 8);
            const ushort* v0 = (const ushort*)&u0;
            const ushort* v1 = (const ushort*)&u1;
#pragma unroll
            for (int i = 0; i < 8; ++i) sVt[seg + i][r] = v0[i];
#pragma unroll
            for (int i = 0; i < 8; ++i) sVt[seg + 8 + i][r] = v1[i];
        }
        __syncthreads();

        // ---- QK^T ----
        f32x4 sacc[4] = {};
#pragma unroll
        for (int ks = 0; ks < 2; ++ks) {
            bf16x8 aq = *(const bf16x8*)&sQ[qw0 + llo][ks * 32 + lhi * 8];
#pragma unroll
            for (int n = 0; n < 4; ++n) {
                bf16x8 bk = *(const bf16x8*)&sK[n * 16 + llo][ks * 32 + lhi * 8];
                sacc[n] = __builtin_amdgcn_mfma_f32_16x16x32_bf16(aq, bk, sacc[n], 0, 0, 0);
            }
        }

        // ---- mask + scale + online softmax ----
#pragma unroll
        for (int j = 0; j < 4; ++j) {
            float s[4];
#pragma unroll
            for (int n = 0; n < 4; ++n) {
                const int kidx = kt + n * 16 + llo;
                const bool ok = (kidx < klim) && (kidx >= lo[j]) && (kidx <= hi[j]);
                s[n] = ok ? (sacc[n][j] * 0.125f) : -1e9f;
            }
            float tm = fmaxf(fmaxf(s[0], s[1]), fmaxf(s[2], s[3]));
#pragma unroll
            for (int off = 8; off; off >>= 1) tm = fmaxf(tm, __shfl_xor(tm, off));
            const float mn = fmaxf(mr[j], tm);
            const float alpha = __expf(mr[j] - mn);
            mr[j] = mn;
            float ps = 0.f;
            const int prow = qw0 + lhi * 4 + j;
#pragma unroll
            for (int n = 0; n < 4; ++n) {
                const ushort pb = f2b(__expf(s[n] - mn));
                sP[prow][n * 16 + llo] = pb;
                ps += b2f(pb);
            }
#pragma unroll
            for (int off = 8; off; off >>= 1) ps += __shfl_xor(ps, off);
            lr[j] = lr[j] * alpha + ps;
            oacc[0][j] *= alpha; oacc[1][j] *= alpha;
            oacc[2][j] *= alpha; oacc[3][j] *= alpha;
        }

        // ---- PV ----
#pragma unroll
        for (int ks = 0; ks < 2; ++ks) {
            bf16x8 ap = *(const bf16x8*)&sP[qw0 + llo][ks * 32 + lhi * 8];
#pragma unroll
            for (int n = 0; n < 4; ++n) {
                bf16x8 bv = *(const bf16x8*)&sVt[n * 16 + llo][ks * 32 + lhi * 8];
                oacc[n] = __builtin_amdgcn_mfma_f32_16x16x32_bf16(ap, bv, oacc[n], 0, 0, 0);
            }
        }
    }

#pragma unroll
    for (int j = 0; j < 4; ++j) {
        const float inv = 1.f / lr[j];
        const int q = q0 + qw0 + lhi * 4 + j;
#pragma unroll
        for (int n = 0; n < 4; ++n) {
            O[(size_t)(b * SS + q) * (HH * DQKv) + h * DQKv + n * 16 + llo] =
                f2b(oacc[n][j] * inv);
        }
    }
}

// ---------------------------------------------------------------------------
// LayerNorm over rows of 512; writes fp32 state + bf16 state copy
// ---------------------------------------------------------------------------
__global__ __launch_bounds__(256) void ln_k(const float* __restrict__ in,
                                            const float* __restrict__ g,
                                            const float* __restrict__ bvec,
                                            float* __restrict__ outf,
                                            ushort* __restrict__ outb) {
    const int row = blockIdx.x;
    const int tid = threadIdx.x;
    const float2 xv = *(const float2*)&in[(size_t)row * DD + tid * 2];

    __shared__ float red[4];
    __shared__ float red2[4];
    const int wid = tid >> 6, lane = tid & 63;

    float s = xv.x + xv.y;
#pragma unroll
    for (int off = 32; off; off >>= 1) s += __shfl_xor(s, off);
    if (lane == 0) red[wid] = s;
    __syncthreads();
    const float mu = (red[0] + red[1] + red[2] + red[3]) * (1.f / 512.f);

    const float dx = xv.x - mu, dy = xv.y - mu;
    float q = dx * dx + dy * dy;
#pragma unroll
    for (int off = 32; off; off >>= 1) q += __shfl_xor(q, off);
    if (lane == 0) red2[wid] = q;
    __syncthreads();
    const float var = (red2[0] + red2[1] + red2[2] + red2[3]) * (1.f / 512.f);
    const float rs = rsqrtf(var + 1e-6f);

    float2 o;
    o.x = dx * rs * g[tid * 2] + bvec[tid * 2];
    o.y = dy * rs * g[tid * 2 + 1] + bvec[tid * 2 + 1];
    *(float2*)&outf[(size_t)row * DD + tid * 2] = o;
    ushort2 ub; ub.x = f2b(o.x); ub.y = f2b(o.y);
    *(ushort2*)&outb[(size_t)row * DD + tid * 2] = ub;
}

// ---------------------------------------------------------------------------
// Host orchestration
// ---------------------------------------------------------------------------
extern "C" void kernel_launch(void* const* d_in, const int* in_sizes, int n_in,
                              void* d_out, int out_size, void* d_ws, size_t ws_size,
                              hipStream_t stream) {
    const float* src_seq = (const float*)d_in[0];
    const float* trg_seq = (const float*)d_in[1];
    const int* enc_pad = (const int*)d_in[2];
    const int* dec_pad = (const int*)d_in[3];
    const float* e_wq = (const float*)d_in[4];
    const float* e_wk = (const float*)d_in[5];
    const float* e_wv = (const float*)d_in[6];
    const float* e_wo = (const float*)d_in[7];
    const float* e_g1 = (const float*)d_in[8];
    const float* e_b1 = (const float*)d_in[9];
    const float* e_w1 = (const float*)d_in[10];
    const float* e_bb1 = (const float*)d_in[11];
    const float* e_w2 = (const float*)d_in[12];
    const float* e_bb2 = (const float*)d_in[13];
    const float* e_g2 = (const float*)d_in[14];
    const float* e_b2 = (const float*)d_in[15];
    const float* d_swq = (const float*)d_in[16];
    const float* d_swk = (const float*)d_in[17];
    const float* d_swv = (const float*)d_in[18];
    const float* d_swo = (const float*)d_in[19];
    const float* d_g1 = (const float*)d_in[20];
    const float* d_b1 = (const float*)d_in[21];
    const float* d_cwq = (const float*)d_in[22];
    const float* d_cwk = (const float*)d_in[23];
    const float* d_cwv = (const float*)d_in[24];
    const float* d_cwo = (const float*)d_in[25];
    const float* d_g2 = (const float*)d_in[26];
    const float* d_b2 = (const float*)d_in[27];
    const float* d_w1 = (const float*)d_in[28];
    const float* d_bb1 = (const float*)d_in[29];
    const float* d_w2 = (const float*)d_in[30];
    const float* d_bb2 = (const float*)d_in[31];
    const float* d_g3 = (const float*)d_in[32];
    const float* d_b3 = (const float*)d_in[33];
    (void)in_sizes; (void)n_in; (void)out_size;

    const int M = BB * SS;          // 4096
    const int NTOK = BB * SS * DD;  // 2097152
    const size_t WSZ = (size_t)DD * 512;  // 262144 elems (one 512x512 weight)

    float* ws = (float*)d_ws;
    float* x  = ws;
    float* y  = x + NTOK;
    float* t0 = y + NTOK;
    ushort* xbf  = (ushort*)(t0 + NTOK);
    ushort* ybf  = xbf + NTOK;
    ushort* qkvb = ybf + NTOK;              // M x 1536 packed QKV
    ushort* ob   = qkvb + (size_t)M * 1536;
    ushort* hbf  = qkvb;                    // FFN hidden 4096x2048 aliases qkvb+ob
    ushort* warena = ob + NTOK;

    // ---- weight table ----
    const float* wsrc[NW]; int wK[NW], wN[NW]; size_t woff[NW];
    int wcnt = 0; size_t acc = 0;
    auto push = [&](const float* p, int K, int N) {
        wsrc[wcnt] = p; wK[wcnt] = K; wN[wcnt] = N; woff[wcnt] = acc;
        acc += (size_t)K * N; ++wcnt;
    };
    for (int l = 0; l < LL; ++l) {
        push(e_wq + (size_t)l * WSZ, 512, 512);
        push(e_wk + (size_t)l * WSZ, 512, 512);
        push(e_wv + (size_t)l * WSZ, 512, 512);
        push(e_wo + (size_t)l * WSZ, 512, 512);
        push(e_w1 + (size_t)l * DD * DFFv, 512, DFFv);
        push(e_w2 + (size_t)l * DFFv * DD, DFFv, 512);
    }
    for (int l = 0; l < LL; ++l) {
        push(d_swq + (size_t)l * WSZ, 512, 512);
        push(d_swk + (size_t)l * WSZ, 512, 512);
        push(d_swv + (size_t)l * WSZ, 512, 512);
        push(d_swo + (size_t)l * WSZ, 512, 512);
        push(d_cwq + (size_t)l * WSZ, 512, 512);
        push(d_cwk + (size_t)l * WSZ, 512, 512);
        push(d_cwv + (size_t)l * WSZ, 512, 512);
        push(d_cwo + (size_t)l * WSZ, 512, 512);
        push(d_w1 + (size_t)l * DD * DFFv, 512, DFFv);
        push(d_w2 + (size_t)l * DFFv * DD, DFFv, 512);
    }

    const size_t base_bytes = (size_t)(warena - (ushort*)d_ws) * 2;
    const bool big = ws_size >= base_bytes + acc * 2;

    if (big) {
        WTab tab;
        int tiles = 0;
        for (int i = 0; i < NW; ++i) {
            tab.src[i] = wsrc[i];
            tab.off[i] = (unsigned)woff[i];
            tab.Kd[i] = wK[i] / 64;
            tab.Nd[i] = wN[i] / 64;
            tab.cum[i] = tiles;
            tiles += (wK[i] / 64) * (wN[i] / 64);
        }
        tab.cum[NW] = tiles;
        tcast_all_k<<<tiles, 256, 0, stream>>>(tab, warena);
    }

    add_pe2_k<<<2 * NTOK / 4 / 256, 256, 0, stream>>>(src_seq, trg_seq, x, xbf, y, ybf);

    auto do_mha = [&](float* statef, ushort* statebf, const ushort* kvbf, int widx,
                      const float* g, const float* bb, const int* pad) {
        const ushort* bt;
        if (big) {
            bt = warena + woff[widx];
        } else {
            tcast_k<<<dim3(8, 8, 4), 256, 0, stream>>>(
                wsrc[widx], wsrc[widx + 1], wsrc[widx + 2], wsrc[widx + 3],
                warena, 512, 512);
            bt = warena;
        }
        if (kvbf == statebf) {
            // packed QKV: BM=64 x BN=128, nbx = 12, grid 768 = 3/CU
            gemm3_k<false, false, false, true><<<64 * 12, 256, 0, stream>>>(
                statebf, bt, nullptr, nullptr, qkvb, M, 1536, 512, 12);
        } else {
            // cross-attn: Q (512 cols) 64x64 grid 512; K/V (1024 cols) 64x128 grid 512
            gemm2_k<false, false, false, true><<<64 * 8, 256, 0, stream>>>(
                statebf, bt + 0 * WSZ, nullptr, nullptr, qkvb, M, 1536, 512, 8);
            gemm3_k<false, false, false, true><<<64 * 8, 256, 0, stream>>>(
                kvbf, bt + 1 * WSZ, nullptr, nullptr, qkvb + DD, M, 1536, 512, 8);
        }
        attn_k<<<dim3(SS / 64, HH, BB), 256, 0, stream>>>(qkvb, ob, pad);
        gemm2_k<false, true, false, false><<<64 * 8, 256, 0, stream>>>(
            ob, bt + 3 * WSZ, nullptr, statef, t0, M, 512, 512, 8);
        ln_k<<<M, 256, 0, stream>>>(t0, g, bb, statef, statebf);
    };
    auto do_ffn = [&](float* statef, ushort* statebf, int widx,
                      const float* b1, const float* b2,
                      const float* g, const float* bb, float* lnoutf) {
        const ushort* bt1;
        const ushort* bt2;
        if (big) {
            bt1 = warena + woff[widx];
            bt2 = warena + woff[widx + 1];
        } else {
            tcast_k<<<dim3(32, 8, 1), 256, 0, stream>>>(
                wsrc[widx], wsrc[widx], wsrc[widx], wsrc[widx], warena, 512, DFFv);
            bt1 = warena;
            bt2 = warena;
        }
        // FFN1: N=2048, 64x128 tiles, nbx=16, grid 1024 = 4/CU
        gemm3_k<true, false, true, true><<<64 * 16, 256, 0, stream>>>(
            statebf, bt1, b1, nullptr, hbf, M, DFFv, 512, 16);
        if (!big) {
            tcast_k<<<dim3(8, 32, 1), 256, 0, stream>>>(
                wsrc[widx + 1], wsrc[widx + 1], wsrc[widx + 1], wsrc[widx + 1],
                warena, DFFv, 512);
        }
        gemm2_k<true, true, false, false><<<64 * 8, 256, 0, stream>>>(
            hbf, bt2, b2, statef, t0, M, 512, DFFv, 8);
        ln_k<<<M, 256, 0, stream>>>(t0, g, bb, lnoutf, statebf);
    };

    for (int l = 0; l < LL; ++l) {
        do_mha(x, xbf, xbf, l * 6, e_g1 + l * DD, e_b1 + l * DD, enc_pad);
        do_ffn(x, xbf, l * 6 + 4, e_bb1 + l * DFFv, e_bb2 + l * DD,
               e_g2 + l * DD, e_b2 + l * DD, x);
    }
    for (int l = 0; l < LL; ++l) {
        do_mha(y, ybf, ybf, 12 + l * 10, d_g1 + l * DD, d_b1 + l * DD, dec_pad);
        do_mha(y, ybf, xbf, 12 + l * 10 + 4, d_g2 + l * DD, d_b2 + l * DD, enc_pad);
        const bool last = (l == LL - 1);
        do_ffn(y, ybf, 12 + l * 10 + 8, d_bb1 + l * DFFv, d_bb2 + l * DD,
               d_g3 + l * DD, d_b3 + l * DD, last ? (float*)d_out : y);
    }
}

// Round 12
// 550.783 us; speedup vs baseline: 1.2441x; 1.0679x over previous
//
#include <hip/hip_runtime.h>
#include <hip/hip_bf16.h>

// Problem constants
#define BB 8
#define SS 512
#define DD 512
#define HH 8
#define DQKv 64
#define DFFv 2048
#define LL 2

typedef __attribute__((ext_vector_type(8))) __bf16 bf16x8;
typedef __attribute__((ext_vector_type(4))) float f32x4;

// fp32 -> bf16 (RNE), bf16 -> fp32 helpers on raw ushort bits
static __device__ __forceinline__ ushort f2b(float x) {
    unsigned int u = __float_as_uint(x);
    unsigned int r = (u + 0x7FFFu + ((u >> 16) & 1u)) >> 16;
    return (ushort)r;
}
static __device__ __forceinline__ float b2f(ushort u) {
    return __uint_as_float(((unsigned int)u) << 16);
}

typedef __attribute__((address_space(1))) const unsigned int gas_u32;
typedef __attribute__((address_space(3))) unsigned int las_u32;
static __device__ __forceinline__ void gload16(const void* g, void* l) {
    __builtin_amdgcn_global_load_lds((gas_u32*)g, (las_u32*)l, 16, 0, 0);
}

#define VMCNT4 asm volatile("s_waitcnt vmcnt(4)" ::: "memory")
#define VMCNT6 asm volatile("s_waitcnt vmcnt(6)" ::: "memory")
#define VMCNT0 asm volatile("s_waitcnt vmcnt(0)" ::: "memory")
#define LGKM0  asm volatile("s_waitcnt lgkmcnt(0)" ::: "memory")
#define SCHEDB __builtin_amdgcn_sched_barrier(0)
#define SBAR   __builtin_amdgcn_s_barrier()

// ---------------------------------------------------------------------------
// x = in + PE (inline trig); src->xb and trg->yb (bf16 state only).
// ---------------------------------------------------------------------------
__global__ __launch_bounds__(256) void add_pe2_k(const float* __restrict__ src,
                                                 const float* __restrict__ trg,
                                                 ushort* __restrict__ xb,
                                                 ushort* __restrict__ yb) {
    const int NQ = BB * SS * DD / 4;
    int i = blockIdx.x * 256 + threadIdx.x;       // 0 .. 2*NQ-1
    const bool second = i >= NQ;
    const int ii = second ? i - NQ : i;
    const int rem = ii & (SS * DD / 4 - 1);
    const int d4 = rem & (DD / 4 - 1);            // 0..127
    const int s = rem >> 7;

    float4 a = ((const float4*)(second ? trg : src))[ii];
    const float c = -9.210340371976184f / 512.0f; // -ln(1e4)/D
    const float div0 = __expf((float)(4 * d4) * c);
    const float div1 = __expf((float)(4 * d4 + 2) * c);
    const float a0 = (float)s * div0, a1 = (float)s * div1;
    a.x += sinf(a0); a.y += cosf(a0);
    a.z += sinf(a1); a.w += cosf(a1);

    ushort* ob = second ? yb : xb;
    ushort4 ub;
    ub.x = f2b(a.x); ub.y = f2b(a.y); ub.z = f2b(a.z); ub.w = f2b(a.w);
    ((ushort4*)ob)[ii] = ub;
}

// ---------------------------------------------------------------------------
// Per-op weight transpose+cast (fallback when ws is small)
// ---------------------------------------------------------------------------
__global__ __launch_bounds__(256) void tcast_k(const float* __restrict__ s0,
                                               const float* __restrict__ s1,
                                               const float* __restrict__ s2,
                                               const float* __restrict__ s3,
                                               ushort* __restrict__ dst,
                                               int K, int N) {
    __shared__ ushort st[64][72];
    const float* src = (blockIdx.z == 0) ? s0 : (blockIdx.z == 1) ? s1
                     : (blockIdx.z == 2) ? s2 : s3;
    ushort* d = dst + (size_t)blockIdx.z * K * N;
    const int k0 = blockIdx.y * 64, n0 = blockIdx.x * 64;
    const int t = threadIdx.x;
    const int r = t >> 2, c4 = (t & 3) * 16;
#pragma unroll
    for (int i = 0; i < 16; i += 4) {
        float4 v = *(const float4*)&src[(size_t)(k0 + r) * N + n0 + c4 + i];
        st[c4 + i + 0][r] = f2b(v.x);
        st[c4 + i + 1][r] = f2b(v.y);
        st[c4 + i + 2][r] = f2b(v.z);
        st[c4 + i + 3][r] = f2b(v.w);
    }
    __syncthreads();
    const int n = t >> 2, seg = (t & 3) * 16;
    *(uint4*)&d[(size_t)(n0 + n) * K + k0 + seg]     = *(const uint4*)&st[n][seg];
    *(uint4*)&d[(size_t)(n0 + n) * K + k0 + seg + 8] = *(const uint4*)&st[n][seg + 8];
}

// ---------------------------------------------------------------------------
// All-weights transpose+cast in ONE launch.
// ---------------------------------------------------------------------------
#define NW 32
struct WTab {
    const float* src[NW];
    unsigned off[NW];   // dst offset in ushort elems
    int Kd[NW];         // K/64
    int Nd[NW];         // N/64
    int cum[NW + 1];    // tile prefix sums
};

__global__ __launch_bounds__(256) void tcast_all_k(WTab tab, ushort* __restrict__ dst) {
    __shared__ ushort st[64][72];
    const int t = blockIdx.x;
    int m = 0;
    while (t >= tab.cum[m + 1]) ++m;
    const int local = t - tab.cum[m];
    const int ntx = tab.Nd[m];
    const int bx = local % ntx, by = local / ntx;
    const float* src = tab.src[m];
    ushort* d = dst + tab.off[m];
    const int N = ntx * 64, K = tab.Kd[m] * 64;
    const int k0 = by * 64, n0 = bx * 64;

    const int tt = threadIdx.x;
    const int r = tt >> 2, c4 = (tt & 3) * 16;
#pragma unroll
    for (int i = 0; i < 16; i += 4) {
        float4 v = *(const float4*)&src[(size_t)(k0 + r) * N + n0 + c4 + i];
        st[c4 + i + 0][r] = f2b(v.x);
        st[c4 + i + 1][r] = f2b(v.y);
        st[c4 + i + 2][r] = f2b(v.z);
        st[c4 + i + 3][r] = f2b(v.w);
    }
    __syncthreads();
    const int n = tt >> 2, seg = (tt & 3) * 16;
    *(uint4*)&d[(size_t)(n0 + n) * K + k0 + seg]     = *(const uint4*)&st[n][seg];
    *(uint4*)&d[(size_t)(n0 + n) * K + k0 + seg + 8] = *(const uint4*)&st[n][seg + 8];
}

// ---------------------------------------------------------------------------
// bf16 MFMA GEMM, BM=64 BN=64 BK=64. 3-buffer depth-2 counted-vmcnt pipeline,
// XOR swizzle (R9-R11 structure, verified). RES input is bf16.
// ---------------------------------------------------------------------------
template <bool BIAS, bool RES, bool RELU, bool OUTBF>
__global__ __launch_bounds__(256) void gemm2_k(const ushort* __restrict__ A,
                                               const ushort* __restrict__ Bt,
                                               const float* __restrict__ bias,
                                               const ushort* __restrict__ res,
                                               void* __restrict__ Cout,
                                               int M, int N, int K, int nbx) {
    __shared__ ushort sA[3][64 * 64];
    __shared__ ushort sB[3][64 * 64];

    const int tid = threadIdx.x;
    const int nwg = gridDim.x;
    const int wg = blockIdx.x;
    const int swz = (wg & 7) * (nwg >> 3) + (wg >> 3);   // XCD-contiguous chunks
    const int bx = swz % nbx, by = swz / nbx;

    const int lane = tid & 63, w = tid >> 6;
    const int wm = w >> 1, wn = w & 1;
    const int llo = lane & 15, lhi = lane >> 4;

    const int srow = tid >> 3;
    const int scol = (((tid & 7) ^ (srow & 7)) * 8);  // pre-swizzled global chunk
    const ushort* Ab = A + (size_t)(by * 64 + srow) * K + scol;
    const ushort* Bb = Bt + (size_t)(bx * 64 + srow) * K + scol;
    const int sOff = srow * 128 + (tid & 7) * 16;

    f32x4 acc[2][2] = {};
    const int nt = K >> 6;

#pragma unroll
    for (int i = 0; i < 2; ++i) {
        gload16(Ab + (size_t)i * 32 * K, (char*)sA[0] + sOff + i * 32 * 128);
        gload16(Bb + (size_t)i * 32 * K, (char*)sB[0] + sOff + i * 32 * 128);
    }
    if (nt > 1) {
#pragma unroll
        for (int i = 0; i < 2; ++i) {
            gload16(Ab + (size_t)i * 32 * K + 64, (char*)sA[1] + sOff + i * 32 * 128);
            gload16(Bb + (size_t)i * 32 * K + 64, (char*)sB[1] + sOff + i * 32 * 128);
        }
    }
    SCHEDB;

    for (int t = 0; t < nt; ++t) {
        if (t + 1 < nt) { VMCNT4; } else { VMCNT0; }
        LGKM0;
        SCHEDB;
        SBAR;
        SCHEDB;
        if (t + 2 < nt) {
            const int k0 = (t + 2) << 6;
            char* dA = (char*)sA[(t + 2) % 3] + sOff;
            char* dB = (char*)sB[(t + 2) % 3] + sOff;
#pragma unroll
            for (int i = 0; i < 2; ++i) {
                gload16(Ab + (size_t)i * 32 * K + k0, dA + i * 32 * 128);
                gload16(Bb + (size_t)i * 32 * K + k0, dB + i * 32 * 128);
            }
        }
        SCHEDB;
        const ushort* cA = sA[t % 3];
        const ushort* cB = sB[t % 3];
        const int sw = llo & 7;
#pragma unroll
        for (int ks = 0; ks < 2; ++ks) {
            const int pc = ((ks * 4 + lhi) ^ sw) * 8;
            bf16x8 af[2];
#pragma unroll
            for (int fa = 0; fa < 2; ++fa)
                af[fa] = *(const bf16x8*)&cA[(wm * 32 + fa * 16 + llo) * 64 + pc];
            bf16x8 bfrag[2];
#pragma unroll
            for (int fb = 0; fb < 2; ++fb)
                bfrag[fb] = *(const bf16x8*)&cB[(wn * 32 + fb * 16 + llo) * 64 + pc];
#pragma unroll
            for (int fa = 0; fa < 2; ++fa)
#pragma unroll
                for (int fb = 0; fb < 2; ++fb)
                    acc[fa][fb] = __builtin_amdgcn_mfma_f32_16x16x32_bf16(
                        af[fa], bfrag[fb], acc[fa][fb], 0, 0, 0);
        }
    }

#pragma unroll
    for (int fa = 0; fa < 2; ++fa) {
#pragma unroll
        for (int fb = 0; fb < 2; ++fb) {
            const int col = bx * 64 + wn * 32 + fb * 16 + llo;
            const float bv = BIAS ? bias[col] : 0.f;
#pragma unroll
            for (int j = 0; j < 4; ++j) {
                const int row = by * 64 + wm * 32 + fa * 16 + lhi * 4 + j;
                float v = acc[fa][fb][j] + bv;
                if (RES) v += b2f(res[(size_t)row * N + col]);
                if (RELU) v = fmaxf(v, 0.f);
                if (OUTBF) ((ushort*)Cout)[(size_t)row * N + col] = f2b(v);
                else       ((float*)Cout)[(size_t)row * N + col] = v;
            }
        }
    }
}

// ---------------------------------------------------------------------------
// Split-K=2 GEMM for FFN2 (M=4096, N=512, K=2048): grid 1024 = 4 blocks/CU.
// Block (bx, by, kh): kh selects K-half; raw fp32 partial to P[kh].
// Same 3-buffer counted-vmcnt pipeline + XOR swizzle.
// ---------------------------------------------------------------------------
__global__ __launch_bounds__(256) void gemm2s_k(const ushort* __restrict__ A,
                                                const ushort* __restrict__ Bt,
                                                float* __restrict__ P0,
                                                float* __restrict__ P1,
                                                int M, int N, int K) {
    __shared__ ushort sA[3][64 * 64];
    __shared__ ushort sB[3][64 * 64];

    const int tid = threadIdx.x;
    const int nwg = gridDim.x;          // 1024
    const int wg = blockIdx.x;
    const int swz = (wg & 7) * (nwg >> 3) + (wg >> 3);
    const int bx = swz & 7;             // N/64 = 8
    const int r2 = swz >> 3;            // 0..127
    const int by = r2 & 63;             // M/64 = 64
    const int kh = r2 >> 6;             // 0,1
    const int Kh = K >> 1;              // 1024
    const int kbase = kh * Kh;

    const int lane = tid & 63, w = tid >> 6;
    const int wm = w >> 1, wn = w & 1;
    const int llo = lane & 15, lhi = lane >> 4;

    const int srow = tid >> 3;
    const int scol = (((tid & 7) ^ (srow & 7)) * 8);
    const ushort* Ab = A + (size_t)(by * 64 + srow) * K + kbase + scol;
    const ushort* Bb = Bt + (size_t)(bx * 64 + srow) * K + kbase + scol;
    const int sOff = srow * 128 + (tid & 7) * 16;

    f32x4 acc[2][2] = {};
    const int nt = Kh >> 6;             // 16

#pragma unroll
    for (int i = 0; i < 2; ++i) {
        gload16(Ab + (size_t)i * 32 * K, (char*)sA[0] + sOff + i * 32 * 128);
        gload16(Bb + (size_t)i * 32 * K, (char*)sB[0] + sOff + i * 32 * 128);
    }
#pragma unroll
    for (int i = 0; i < 2; ++i) {
        gload16(Ab + (size_t)i * 32 * K + 64, (char*)sA[1] + sOff + i * 32 * 128);
        gload16(Bb + (size_t)i * 32 * K + 64, (char*)sB[1] + sOff + i * 32 * 128);
    }
    SCHEDB;

    for (int t = 0; t < nt; ++t) {
        if (t + 1 < nt) { VMCNT4; } else { VMCNT0; }
        LGKM0;
        SCHEDB;
        SBAR;
        SCHEDB;
        if (t + 2 < nt) {
            const int k0 = (t + 2) << 6;
            char* dA = (char*)sA[(t + 2) % 3] + sOff;
            char* dB = (char*)sB[(t + 2) % 3] + sOff;
#pragma unroll
            for (int i = 0; i < 2; ++i) {
                gload16(Ab + (size_t)i * 32 * K + k0, dA + i * 32 * 128);
                gload16(Bb + (size_t)i * 32 * K + k0, dB + i * 32 * 128);
            }
        }
        SCHEDB;
        const ushort* cA = sA[t % 3];
        const ushort* cB = sB[t % 3];
        const int sw = llo & 7;
#pragma unroll
        for (int ks = 0; ks < 2; ++ks) {
            const int pc = ((ks * 4 + lhi) ^ sw) * 8;
            bf16x8 af[2];
#pragma unroll
            for (int fa = 0; fa < 2; ++fa)
                af[fa] = *(const bf16x8*)&cA[(wm * 32 + fa * 16 + llo) * 64 + pc];
            bf16x8 bfrag[2];
#pragma unroll
            for (int fb = 0; fb < 2; ++fb)
                bfrag[fb] = *(const bf16x8*)&cB[(wn * 32 + fb * 16 + llo) * 64 + pc];
#pragma unroll
            for (int fa = 0; fa < 2; ++fa)
#pragma unroll
                for (int fb = 0; fb < 2; ++fb)
                    acc[fa][fb] = __builtin_amdgcn_mfma_f32_16x16x32_bf16(
                        af[fa], bfrag[fb], acc[fa][fb], 0, 0, 0);
        }
    }

    float* P = kh ? P1 : P0;
#pragma unroll
    for (int fa = 0; fa < 2; ++fa) {
#pragma unroll
        for (int fb = 0; fb < 2; ++fb) {
            const int col = bx * 64 + wn * 32 + fb * 16 + llo;
#pragma unroll
            for (int j = 0; j < 4; ++j) {
                const int row = by * 64 + wm * 32 + fa * 16 + lhi * 4 + j;
                P[(size_t)row * N + col] = acc[fa][fb][j];
            }
        }
    }
}

// ---------------------------------------------------------------------------
// bf16 MFMA GEMM, BM=64 BN=128 BK=64. 2-buffer counted-vmcnt (R11 verified).
// ---------------------------------------------------------------------------
template <bool BIAS, bool RES, bool RELU, bool OUTBF>
__global__ __launch_bounds__(256) void gemm3_k(const ushort* __restrict__ A,
                                               const ushort* __restrict__ Bt,
                                               const float* __restrict__ bias,
                                               const ushort* __restrict__ res,
                                               void* __restrict__ Cout,
                                               int M, int N, int K, int nbx) {
    __shared__ ushort sA[2][64 * 64];
    __shared__ ushort sB[2][128 * 64];

    const int tid = threadIdx.x;
    const int nwg = gridDim.x;
    const int wg = blockIdx.x;
    const int swz = (wg & 7) * (nwg >> 3) + (wg >> 3);
    const int bx = swz % nbx, by = swz / nbx;

    const int lane = tid & 63, w = tid >> 6;
    const int wm = w >> 1, wn = w & 1;
    const int llo = lane & 15, lhi = lane >> 4;

    const int srow = tid >> 3;
    const int scol = (((tid & 7) ^ (srow & 7)) * 8);
    const ushort* Ab = A + (size_t)(by * 64 + srow) * K + scol;
    const ushort* Bb = Bt + (size_t)(bx * 128 + srow) * K + scol;
    const int sOff = srow * 128 + (tid & 7) * 16;

    f32x4 acc[2][4] = {};
    const int nt = K >> 6;

#pragma unroll
    for (int i = 0; i < 2; ++i)
        gload16(Ab + (size_t)i * 32 * K, (char*)sA[0] + sOff + i * 32 * 128);
#pragma unroll
    for (int i = 0; i < 4; ++i)
        gload16(Bb + (size_t)i * 32 * K, (char*)sB[0] + sOff + i * 32 * 128);
    SCHEDB;

    for (int t = 0; t < nt; ++t) {
        if (t + 1 < nt) {
            const int k0 = (t + 1) << 6;
            char* dA = (char*)sA[(t + 1) & 1] + sOff;
            char* dB = (char*)sB[(t + 1) & 1] + sOff;
#pragma unroll
            for (int i = 0; i < 2; ++i)
                gload16(Ab + (size_t)i * 32 * K + k0, dA + i * 32 * 128);
#pragma unroll
            for (int i = 0; i < 4; ++i)
                gload16(Bb + (size_t)i * 32 * K + k0, dB + i * 32 * 128);
            SCHEDB;
            VMCNT6;
        } else {
            VMCNT0;
        }
        SCHEDB;
        SBAR;
        SCHEDB;
        const ushort* cA = sA[t & 1];
        const ushort* cB = sB[t & 1];
        const int sw = llo & 7;
#pragma unroll
        for (int ks = 0; ks < 2; ++ks) {
            const int pc = ((ks * 4 + lhi) ^ sw) * 8;
            bf16x8 af[2];
#pragma unroll
            for (int fa = 0; fa < 2; ++fa)
                af[fa] = *(const bf16x8*)&cA[(wm * 32 + fa * 16 + llo) * 64 + pc];
            bf16x8 bfrag[4];
#pragma unroll
            for (int fb = 0; fb < 4; ++fb)
                bfrag[fb] = *(const bf16x8*)&cB[(wn * 64 + fb * 16 + llo) * 64 + pc];
#pragma unroll
            for (int fa = 0; fa < 2; ++fa)
#pragma unroll
                for (int fb = 0; fb < 4; ++fb)
                    acc[fa][fb] = __builtin_amdgcn_mfma_f32_16x16x32_bf16(
                        af[fa], bfrag[fb], acc[fa][fb], 0, 0, 0);
        }
        LGKM0;
        SCHEDB;
        SBAR;
    }

#pragma unroll
    for (int fa = 0; fa < 2; ++fa) {
#pragma unroll
        for (int fb = 0; fb < 4; ++fb) {
            const int col = bx * 128 + wn * 64 + fb * 16 + llo;
            const float bv = BIAS ? bias[col] : 0.f;
#pragma unroll
            for (int j = 0; j < 4; ++j) {
                const int row = by * 64 + wm * 32 + fa * 16 + lhi * 4 + j;
                float v = acc[fa][fb][j] + bv;
                if (RES) v += b2f(res[(size_t)row * N + col]);
                if (RELU) v = fmaxf(v, 0.f);
                if (OUTBF) ((ushort*)Cout)[(size_t)row * N + col] = f2b(v);
                else       ((float*)Cout)[(size_t)row * N + col] = v;
            }
        }
    }
}

// ---------------------------------------------------------------------------
// MFMA flash attention on packed QKV [M][1536]. Semantics verified R2-R11.
// ---------------------------------------------------------------------------
__global__ __launch_bounds__(256) void attn_k(const ushort* __restrict__ QKV,
                                              ushort* __restrict__ O,
                                              const int* __restrict__ pad) {
    __shared__ ushort sQ[64][72];
    __shared__ ushort sK[64][72];
    __shared__ ushort sVt[64][72];   // V transposed: [d][key]
    __shared__ ushort sP[64][72];    // P: [q][key-local]

    const int tid = threadIdx.x;
    const int b = blockIdx.z, h = blockIdx.y, q0 = blockIdx.x << 6;
    const int klim = SS - pad[b];
    const int lane = tid & 63, w = tid >> 6;
    const int qw0 = w << 4;
    const int lhi = lane >> 4, llo = lane & 15;
    const int ST = 3 * DD;           // 1536 row stride

    {
        const int r = tid >> 2, seg = (tid & 3) << 4;
        const ushort* src = &QKV[(size_t)(b * SS + q0 + r) * ST + h * DQKv + seg];
        *(uint4*)&sQ[r][seg]     = *(const uint4*)src;
        *(uint4*)&sQ[r][seg + 8] = *(const uint4*)(src + 8);
    }

    auto window = [&](int i, int& wlo, int& whi) {
        if (h < 6) {
            const int step = 4 << (h >> 1);
            const int s2 = step >> 1;
            const int a1 = (i < s2) ? i : s2;
            const int a2 = ((SS - 1 - i) < s2) ? (SS - 1 - i) : s2;
            const int left = (i < SS / 2) ? a1 : (step - a2);
            wlo = i - left;
            whi = wlo + step;
        } else {
            wlo = 0;
            whi = SS - 1;
        }
    };

    int lo[4], hi[4];
#pragma unroll
    for (int j = 0; j < 4; ++j) window(q0 + qw0 + lhi * 4 + j, lo[j], hi[j]);

    int kt0 = 0, kt1 = SS;
    if (h < 6) {
        int lo0, hi0, lo63, hi63;
        window(q0, lo0, hi0);
        window(q0 + 63, lo63, hi63);
        if (lo63 >= klim) {
            kt0 = 0; kt1 = SS;
        } else {
            kt0 = (lo0 >> 6) << 6;
            kt1 = ((hi63 >> 6) + 1) << 6;
            if (kt1 > SS) kt1 = SS;
        }
    }

    float mr[4] = {-1e30f, -1e30f, -1e30f, -1e30f};
    float lr[4] = {0.f, 0.f, 0.f, 0.f};
    f32x4 oacc[4] = {};

    for (int kt = kt0; kt < kt1; kt += 64) {
        __syncthreads();
        {
            const int r = tid >> 2, seg = (tid & 3) << 4;
            const ushort* ksrc = &QKV[(size_t)(b * SS + kt + r) * ST + DD + h * DQKv + seg];
            *(uint4*)&sK[r][seg]     = *(const uint4*)ksrc;
            *(uint4*)&sK[r][seg + 8] = *(const uint4*)(ksrc + 8);
            const ushort* vsrc = &QKV[(size_t)(b * SS + kt + r) * ST + 2 * DD + h * DQKv + seg];
            uint4 u0 = *(const uint4*)vsrc;
            uint4 u1 = *(const uint4*)(vsrc + 8);
            const ushort* v0 = (const ushort*)&u0;
            const ushort* v1 = (const ushort*)&u1;
#pragma unroll
            for (int i = 0; i < 8; ++i) sVt[seg + i][r] = v0[i];
#pragma unroll
            for (int i = 0; i < 8; ++i) sVt[seg + 8 + i][r] = v1[i];
        }
        __syncthreads();

        // ---- QK^T ----
        f32x4 sacc[4] = {};
#pragma unroll
        for (int ks = 0; ks < 2; ++ks) {
            bf16x8 aq = *(const bf16x8*)&sQ[qw0 + llo][ks * 32 + lhi * 8];
#pragma unroll
            for (int n = 0; n < 4; ++n) {
                bf16x8 bk = *(const bf16x8*)&sK[n * 16 + llo][ks * 32 + lhi * 8];
                sacc[n] = __builtin_amdgcn_mfma_f32_16x16x32_bf16(aq, bk, sacc[n], 0, 0, 0);
            }
        }

        // ---- mask + scale + online softmax ----
#pragma unroll
        for (int j = 0; j < 4; ++j) {
            float s[4];
#pragma unroll
            for (int n = 0; n < 4; ++n) {
                const int kidx = kt + n * 16 + llo;
                const bool ok = (kidx < klim) && (kidx >= lo[j]) && (kidx <= hi[j]);
                s[n] = ok ? (sacc[n][j] * 0.125f) : -1e9f;
            }
            float tm = fmaxf(fmaxf(s[0], s[1]), fmaxf(s[2], s[3]));
#pragma unroll
            for (int off = 8; off; off >>= 1) tm = fmaxf(tm, __shfl_xor(tm, off));
            const float mn = fmaxf(mr[j], tm);
            const float alpha = __expf(mr[j] - mn);
            mr[j] = mn;
            float ps = 0.f;
            const int prow = qw0 + lhi * 4 + j;
#pragma unroll
            for (int n = 0; n < 4; ++n) {
                const ushort pb = f2b(__expf(s[n] - mn));
                sP[prow][n * 16 + llo] = pb;
                ps += b2f(pb);
            }
#pragma unroll
            for (int off = 8; off; off >>= 1) ps += __shfl_xor(ps, off);
            lr[j] = lr[j] * alpha + ps;
            oacc[0][j] *= alpha; oacc[1][j] *= alpha;
            oacc[2][j] *= alpha; oacc[3][j] *= alpha;
        }

        // ---- PV ----
#pragma unroll
        for (int ks = 0; ks < 2; ++ks) {
            bf16x8 ap = *(const bf16x8*)&sP[qw0 + llo][ks * 32 + lhi * 8];
#pragma unroll
            for (int n = 0; n < 4; ++n) {
                bf16x8 bv = *(const bf16x8*)&sVt[n * 16 + llo][ks * 32 + lhi * 8];
                oacc[n] = __builtin_amdgcn_mfma_f32_16x16x32_bf16(ap, bv, oacc[n], 0, 0, 0);
            }
        }
    }

#pragma unroll
    for (int j = 0; j < 4; ++j) {
        const float inv = 1.f / lr[j];
        const int q = q0 + qw0 + lhi * 4 + j;
#pragma unroll
        for (int n = 0; n < 4; ++n) {
            O[(size_t)(b * SS + q) * (HH * DQKv) + h * DQKv + n * 16 + llo] =
                f2b(oacc[n][j] * inv);
        }
    }
}

// ---------------------------------------------------------------------------
// LayerNorm over rows of 512 from fp32 input; writes bf16 state (+ optional
// fp32 out for the final layer).
// ---------------------------------------------------------------------------
__global__ __launch_bounds__(256) void ln_k(const float* __restrict__ in,
                                            const float* __restrict__ g,
                                            const float* __restrict__ bvec,
                                            ushort* __restrict__ outb,
                                            float* __restrict__ outf) {
    const int row = blockIdx.x;
    const int tid = threadIdx.x;
    const float2 xv = *(const float2*)&in[(size_t)row * DD + tid * 2];

    __shared__ float red[4];
    __shared__ float red2[4];
    const int wid = tid >> 6, lane = tid & 63;

    float s = xv.x + xv.y;
#pragma unroll
    for (int off = 32; off; off >>= 1) s += __shfl_xor(s, off);
    if (lane == 0) red[wid] = s;
    __syncthreads();
    const float mu = (red[0] + red[1] + red[2] + red[3]) * (1.f / 512.f);

    const float dx = xv.x - mu, dy = xv.y - mu;
    float q = dx * dx + dy * dy;
#pragma unroll
    for (int off = 32; off; off >>= 1) q += __shfl_xor(q, off);
    if (lane == 0) red2[wid] = q;
    __syncthreads();
    const float var = (red2[0] + red2[1] + red2[2] + red2[3]) * (1.f / 512.f);
    const float rs = rsqrtf(var + 1e-6f);

    float2 o;
    o.x = dx * rs * g[tid * 2] + bvec[tid * 2];
    o.y = dy * rs * g[tid * 2 + 1] + bvec[tid * 2 + 1];
    ushort2 ub; ub.x = f2b(o.x); ub.y = f2b(o.y);
    *(ushort2*)&outb[(size_t)row * DD + tid * 2] = ub;
    if (outf) *(float2*)&outf[(size_t)row * DD + tid * 2] = o;
}

// ---------------------------------------------------------------------------
// LayerNorm for split-K FFN2: v = p0 + p1 + bias + res(bf16), then LN.
// ---------------------------------------------------------------------------
__global__ __launch_bounds__(256) void ln2_k(const float* __restrict__ p0,
                                             const float* __restrict__ p1,
                                             const float* __restrict__ bias,
                                             const ushort* __restrict__ res,
                                             const float* __restrict__ g,
                                             const float* __restrict__ bvec,
                                             ushort* __restrict__ outb,
                                             float* __restrict__ outf) {
    const int row = blockIdx.x;
    const int tid = threadIdx.x;
    const size_t base = (size_t)row * DD + tid * 2;
    const float2 a0 = *(const float2*)&p0[base];
    const float2 a1 = *(const float2*)&p1[base];
    const ushort2 rv = *(const ushort2*)&res[base];
    float2 xv;
    xv.x = a0.x + a1.x + bias[tid * 2]     + b2f(rv.x);
    xv.y = a0.y + a1.y + bias[tid * 2 + 1] + b2f(rv.y);

    __shared__ float red[4];
    __shared__ float red2[4];
    const int wid = tid >> 6, lane = tid & 63;

    float s = xv.x + xv.y;
#pragma unroll
    for (int off = 32; off; off >>= 1) s += __shfl_xor(s, off);
    if (lane == 0) red[wid] = s;
    __syncthreads();
    const float mu = (red[0] + red[1] + red[2] + red[3]) * (1.f / 512.f);

    const float dx = xv.x - mu, dy = xv.y - mu;
    float q = dx * dx + dy * dy;
#pragma unroll
    for (int off = 32; off; off >>= 1) q += __shfl_xor(q, off);
    if (lane == 0) red2[wid] = q;
    __syncthreads();
    const float var = (red2[0] + red2[1] + red2[2] + red2[3]) * (1.f / 512.f);
    const float rs = rsqrtf(var + 1e-6f);

    float2 o;
    o.x = dx * rs * g[tid * 2] + bvec[tid * 2];
    o.y = dy * rs * g[tid * 2 + 1] + bvec[tid * 2 + 1];
    ushort2 ub; ub.x = f2b(o.x); ub.y = f2b(o.y);
    *(ushort2*)&outb[base] = ub;
    if (outf) *(float2*)&outf[base] = o;
}

// ---------------------------------------------------------------------------
// Host orchestration
// ---------------------------------------------------------------------------
extern "C" void kernel_launch(void* const* d_in, const int* in_sizes, int n_in,
                              void* d_out, int out_size, void* d_ws, size_t ws_size,
                              hipStream_t stream) {
    const float* src_seq = (const float*)d_in[0];
    const float* trg_seq = (const float*)d_in[1];
    const int* enc_pad = (const int*)d_in[2];
    const int* dec_pad = (const int*)d_in[3];
    const float* e_wq = (const float*)d_in[4];
    const float* e_wk = (const float*)d_in[5];
    const float* e_wv = (const float*)d_in[6];
    const float* e_wo = (const float*)d_in[7];
    const float* e_g1 = (const float*)d_in[8];
    const float* e_b1 = (const float*)d_in[9];
    const float* e_w1 = (const float*)d_in[10];
    const float* e_bb1 = (const float*)d_in[11];
    const float* e_w2 = (const float*)d_in[12];
    const float* e_bb2 = (const float*)d_in[13];
    const float* e_g2 = (const float*)d_in[14];
    const float* e_b2 = (const float*)d_in[15];
    const float* d_swq = (const float*)d_in[16];
    const float* d_swk = (const float*)d_in[17];
    const float* d_swv = (const float*)d_in[18];
    const float* d_swo = (const float*)d_in[19];
    const float* d_g1 = (const float*)d_in[20];
    const float* d_b1 = (const float*)d_in[21];
    const float* d_cwq = (const float*)d_in[22];
    const float* d_cwk = (const float*)d_in[23];
    const float* d_cwv = (const float*)d_in[24];
    const float* d_cwo = (const float*)d_in[25];
    const float* d_g2 = (const float*)d_in[26];
    const float* d_b2 = (const float*)d_in[27];
    const float* d_w1 = (const float*)d_in[28];
    const float* d_bb1 = (const float*)d_in[29];
    const float* d_w2 = (const float*)d_in[30];
    const float* d_bb2 = (const float*)d_in[31];
    const float* d_g3 = (const float*)d_in[32];
    const float* d_b3 = (const float*)d_in[33];
    (void)in_sizes; (void)n_in; (void)out_size;

    const int M = BB * SS;          // 4096
    const int NTOK = BB * SS * DD;  // 2097152
    const size_t WSZ = (size_t)DD * 512;  // 262144 elems (one 512x512 weight)

    float* ws = (float*)d_ws;
    float* t0 = ws;
    float* p0 = t0 + NTOK;
    float* p1 = p0 + NTOK;
    ushort* xbf  = (ushort*)(p1 + NTOK);
    ushort* ybf  = xbf + NTOK;
    ushort* qkvb = ybf + NTOK;              // M x 1536 packed QKV
    ushort* ob   = qkvb + (size_t)M * 1536;
    ushort* hbf  = qkvb;                    // FFN hidden 4096x2048 aliases qkvb+ob
    ushort* warena = ob + NTOK;

    // ---- weight table ----
    const float* wsrc[NW]; int wK[NW], wN[NW]; size_t woff[NW];
    int wcnt = 0; size_t acc = 0;
    auto push = [&](const float* p, int K, int N) {
        wsrc[wcnt] = p; wK[wcnt] = K; wN[wcnt] = N; woff[wcnt] = acc;
        acc += (size_t)K * N; ++wcnt;
    };
    for (int l = 0; l < LL; ++l) {
        push(e_wq + (size_t)l * WSZ, 512, 512);
        push(e_wk + (size_t)l * WSZ, 512, 512);
        push(e_wv + (size_t)l * WSZ, 512, 512);
        push(e_wo + (size_t)l * WSZ, 512, 512);
        push(e_w1 + (size_t)l * DD * DFFv, 512, DFFv);
        push(e_w2 + (size_t)l * DFFv * DD, DFFv, 512);
    }
    for (int l = 0; l < LL; ++l) {
        push(d_swq + (size_t)l * WSZ, 512, 512);
        push(d_swk + (size_t)l * WSZ, 512, 512);
        push(d_swv + (size_t)l * WSZ, 512, 512);
        push(d_swo + (size_t)l * WSZ, 512, 512);
        push(d_cwq + (size_t)l * WSZ, 512, 512);
        push(d_cwk + (size_t)l * WSZ, 512, 512);
        push(d_cwv + (size_t)l * WSZ, 512, 512);
        push(d_cwo + (size_t)l * WSZ, 512, 512);
        push(d_w1 + (size_t)l * DD * DFFv, 512, DFFv);
        push(d_w2 + (size_t)l * DFFv * DD, DFFv, 512);
    }

    const size_t base_bytes = (size_t)((char*)warena - (char*)d_ws);
    const bool big = ws_size >= base_bytes + acc * 2;

    if (big) {
        WTab tab;
        int tiles = 0;
        for (int i = 0; i < NW; ++i) {
            tab.src[i] = wsrc[i];
            tab.off[i] = (unsigned)woff[i];
            tab.Kd[i] = wK[i] / 64;
            tab.Nd[i] = wN[i] / 64;
            tab.cum[i] = tiles;
            tiles += (wK[i] / 64) * (wN[i] / 64);
        }
        tab.cum[NW] = tiles;
        tcast_all_k<<<tiles, 256, 0, stream>>>(tab, warena);
    }

    add_pe2_k<<<2 * NTOK / 4 / 256, 256, 0, stream>>>(src_seq, trg_seq, xbf, ybf);

    auto do_mha = [&](ushort* statebf, const ushort* kvbf, int widx,
                      const float* g, const float* bb, const int* pad) {
        const ushort* bt;
        if (big) {
            bt = warena + woff[widx];
        } else {
            tcast_k<<<dim3(8, 8, 4), 256, 0, stream>>>(
                wsrc[widx], wsrc[widx + 1], wsrc[widx + 2], wsrc[widx + 3],
                warena, 512, 512);
            bt = warena;
        }
        if (kvbf == statebf) {
            gemm3_k<false, false, false, true><<<64 * 12, 256, 0, stream>>>(
                statebf, bt, nullptr, nullptr, qkvb, M, 1536, 512, 12);
        } else {
            gemm2_k<false, false, false, true><<<64 * 8, 256, 0, stream>>>(
                statebf, bt + 0 * WSZ, nullptr, nullptr, qkvb, M, 1536, 512, 8);
            gemm3_k<false, false, false, true><<<64 * 8, 256, 0, stream>>>(
                kvbf, bt + 1 * WSZ, nullptr, nullptr, qkvb + DD, M, 1536, 512, 8);
        }
        attn_k<<<dim3(SS / 64, HH, BB), 256, 0, stream>>>(qkvb, ob, pad);
        gemm2_k<false, true, false, false><<<64 * 8, 256, 0, stream>>>(
            ob, bt + 3 * WSZ, nullptr, statebf, t0, M, 512, 512, 8);
        ln_k<<<M, 256, 0, stream>>>(t0, g, bb, statebf, nullptr);
    };
    auto do_ffn = [&](ushort* statebf, int widx,
                      const float* b1, const float* b2,
                      const float* g, const float* bb, float* lnoutf) {
        const ushort* bt1;
        const ushort* bt2;
        if (big) {
            bt1 = warena + woff[widx];
            bt2 = warena + woff[widx + 1];
        } else {
            tcast_k<<<dim3(32, 8, 1), 256, 0, stream>>>(
                wsrc[widx], wsrc[widx], wsrc[widx], wsrc[widx], warena, 512, DFFv);
            bt1 = warena;
            bt2 = warena;
        }
        // FFN1: N=2048, 64x128 tiles, grid 1024 = 4/CU
        gemm3_k<true, false, true, true><<<64 * 16, 256, 0, stream>>>(
            statebf, bt1, b1, nullptr, hbf, M, DFFv, 512, 16);
        if (!big) {
            tcast_k<<<dim3(8, 32, 1), 256, 0, stream>>>(
                wsrc[widx + 1], wsrc[widx + 1], wsrc[widx + 1], wsrc[widx + 1],
                warena, DFFv, 512);
        }
        // FFN2: split-K=2, grid 1024 = 4/CU, raw fp32 partials
        gemm2s_k<<<1024, 256, 0, stream>>>(hbf, bt2, p0, p1, M, 512, DFFv);
        ln2_k<<<M, 256, 0, stream>>>(p0, p1, b2, statebf, g, bb, statebf, lnoutf);
    };

    for (int l = 0; l < LL; ++l) {
        do_mha(xbf, xbf, l * 6, e_g1 + l * DD, e_b1 + l * DD, enc_pad);
        do_ffn(xbf, l * 6 + 4, e_bb1 + l * DFFv, e_bb2 + l * DD,
               e_g2 + l * DD, e_b2 + l * DD, nullptr);
    }
    for (int l = 0; l < LL; ++l) {
        do_mha(ybf, ybf, 12 + l * 10, d_g1 + l * DD, d_b1 + l * DD, dec_pad);
        do_mha(ybf, xbf, 12 + l * 10 + 4, d_g2 + l * DD, d_b2 + l * DD, enc_pad);
        const bool last = (l == LL - 1);
        do_ffn(ybf, 12 + l * 10 + 8, d_bb1 + l * DFFv, d_bb2 + l * DD,
               d_g3 + l * DD, d_b3 + l * DD, last ? (float*)d_out : nullptr);
    }
}